// Round 1
// baseline (3629.999 us; speedup 1.0000x reference)
//
#include <hip/hip_runtime.h>
#include <math.h>

#define NNODES 32768
#define NEDGES 524288
#define KDIM 32
#define NSHD 16
#define NB 8
#define NHID 64
#define NGRAPH 16
#define NELEM 10
#define RMAXF 5.0f
#define PI_F 3.14159265358979f
#define CBES 0.632455532033676f   /* sqrt(2/R_MAX) = sqrt(0.4) */

__device__ __forceinline__ void compute_sh(float x, float y, float z, float* sh){
  float x2=x*x, y2=y*y, z2=z*z;
  sh[0]=0.28209479f;
  sh[1]=0.48860251f*y;
  sh[2]=0.48860251f*z;
  sh[3]=0.48860251f*x;
  sh[4]=1.09254843f*x*y;
  sh[5]=1.09254843f*y*z;
  sh[6]=0.31539157f*(3.0f*z2-1.0f);
  sh[7]=1.09254843f*x*z;
  sh[8]=0.54627422f*(x2-y2);
  sh[9]=0.59004359f*y*(3.0f*x2-y2);
  sh[10]=2.89061144f*x*y*z;
  sh[11]=0.45704579f*y*(5.0f*z2-1.0f);
  sh[12]=0.37317633f*z*(5.0f*z2-3.0f);
  sh[13]=0.45704579f*x*(5.0f*z2-1.0f);
  sh[14]=1.44530572f*z*(x2-y2);
  sh[15]=0.59004359f*x*(x2-3.0f*y2);
}

// ---------------------------------------------------------------- prep
// G3[i][j][l] = U3[ijl]+U3[jil]+U3[jli]  (grad tensor; B3 = a.g3/3)
// U2s = U2 + U2^T ; c{1,2,3}[k] = (Wp{1,2,3} @ W_read)[k]
__global__ void prep_kernel(const float* __restrict__ U2, const float* __restrict__ U3,
                            const float* __restrict__ Wp1, const float* __restrict__ Wp2,
                            const float* __restrict__ Wp3, const float* __restrict__ Wread,
                            float* __restrict__ G3, float* __restrict__ U2s,
                            float* __restrict__ c123){
  int t = threadIdx.x;
  for (int v = t; v < 4096; v += 256){
    int i = v >> 8, j = (v >> 4) & 15, l = v & 15;
    G3[v] = U3[i*256 + j*16 + l] + U3[j*256 + i*16 + l] + U3[j*256 + l*16 + i];
  }
  {
    int i = t >> 4, j = t & 15;
    U2s[t] = U2[i*16+j] + U2[j*16+i];
  }
  if (t < 96){
    int which = t >> 5, k = t & 31;
    const float* Wp = (which==0)?Wp1:((which==1)?Wp2:Wp3);
    float s = 0.f;
    for (int q=0;q<KDIM;q++) s += Wp[k*KDIM+q]*Wread[q];
    c123[t] = s;
  }
}

// ---------------------------------------------------------------- node embed
// one wave per node: x = attrs@W_embed, y = x@W_up, e0 atomic per node
__global__ void node_embed_kernel(const float* __restrict__ attrs,
                                  const float* __restrict__ W_embed,
                                  const float* __restrict__ W_up,
                                  const float* __restrict__ ae,
                                  const int* __restrict__ batch,
                                  float* __restrict__ xbuf, float* __restrict__ ybuf,
                                  float* __restrict__ out_e){
  int gtid = blockIdx.x*256 + threadIdx.x;
  int n = gtid >> 6;
  int lane = threadIdx.x & 63;
  int k = lane & 31;
  float xv = 0.f;
  #pragma unroll
  for (int e=0;e<NELEM;e++) xv += attrs[n*NELEM+e]*W_embed[e*KDIM+k];
  float yv = 0.f;
  #pragma unroll 8
  for (int k2=0;k2<KDIM;k2++) yv += __shfl(xv, k2, 64) * W_up[k2*KDIM+k];
  if (lane < 32){
    xbuf[n*KDIM+k]=xv;
    ybuf[n*KDIM+k]=yv;
  }
  if (lane == 0){
    float s=0.f;
    #pragma unroll
    for (int e=0;e<NELEM;e++) s += attrs[n*NELEM+e]*ae[e];
    atomicAdd(&out_e[batch[n]], s);
  }
}

// ---------------------------------------------------------------- edge forward
// one wave per edge: radial MLP + sh, scatter msg into A[receiver] (atomics)
__global__ void edge_fwd_kernel(const float* __restrict__ pos, const int* __restrict__ eidx,
                                const float* __restrict__ shifts, const float* __restrict__ ybuf,
                                const float* __restrict__ W_r1, const float* __restrict__ b_r1,
                                const float* __restrict__ W_r2, float* __restrict__ A){
  __shared__ float s_sh[4][NHID];
  __shared__ float xs_sh[4][KDIM];
  __shared__ float sh_sh[4][NSHD];
  int wl = threadIdx.x >> 6, lane = threadIdx.x & 63;
  int e = blockIdx.x*4 + wl;
  int snd = eidx[e], rcv = eidx[NEDGES + e];
  float vx = pos[rcv*3+0] - pos[snd*3+0] + shifts[e*3+0];
  float vy = pos[rcv*3+1] - pos[snd*3+1] + shifts[e*3+1];
  float vz = pos[rcv*3+2] - pos[snd*3+2] + shifts[e*3+2];
  float r2 = vx*vx+vy*vy+vz*vz + 1e-18f;
  float r = sqrtf(r2);
  float invr = 1.0f/r;
  float ux=vx*invr, uy=vy*invr, uz=vz*invr;
  float u = r*(1.0f/RMAXF);
  float cut = 0.f;
  if (u < 1.0f){
    float u2=u*u, u3=u2*u, u6=u3*u3;
    cut = 1.0f - 28.0f*u6 + 48.0f*u6*u - 21.0f*u6*u2;
  }
  float b[NB];
  #pragma unroll
  for (int q=0;q<NB;q++)
    b[q] = CBES * sinf(PI_F*(float)(q+1)*u) * invr * cut;
  int m = lane;
  float h = b_r1[m];
  #pragma unroll
  for (int q=0;q<NB;q++) h += b[q]*W_r1[q*NHID+m];
  float sig = 1.0f/(1.0f+expf(-h));
  s_sh[wl][m] = h*sig;
  if (lane == 0){
    float sh[16];
    compute_sh(ux,uy,uz,sh);
    #pragma unroll
    for (int i=0;i<16;i++) sh_sh[wl][i]=sh[i];
  }
  __syncthreads();
  if (lane < 32){
    int k = lane;
    float Rw = 0.f;
    #pragma unroll 8
    for (int mm=0;mm<NHID;mm++) Rw += s_sh[wl][mm]*W_r2[mm*KDIM+k];
    xs_sh[wl][k] = ybuf[snd*KDIM+k]*Rw;
  }
  __syncthreads();
  float* Arow = A + (size_t)rcv*(KDIM*NSHD);
  #pragma unroll
  for (int j=0;j<8;j++){
    int v = lane + 64*j;
    atomicAdd(&Arow[v], xs_sh[wl][v>>4]*sh_sh[wl][v&15]);
  }
}

// ---------------------------------------------------------------- node B-ops
// thread = (node,k). g2 = U2s.a, g3_i = a^T G3_i a; B2 = a.g2/2, B3 = a.g3/3.
// energy via c1,c2,c3; store gA = dE/dA / AVG_NEIGH.
__global__ void node_b_kernel(const float* __restrict__ A, const float* __restrict__ xbuf,
                              const int* __restrict__ batch, const float* __restrict__ G3g,
                              const float* __restrict__ U2sg, const float* __restrict__ c123,
                              const float* __restrict__ Wread, float* __restrict__ gA,
                              float* __restrict__ out_e){
  __shared__ float G3s[4096];
  __shared__ float U2ss[256];
  for (int v=threadIdx.x; v<4096; v+=256) G3s[v]=G3g[v];
  U2ss[threadIdx.x]=U2sg[threadIdx.x];
  __syncthreads();
  int n = blockIdx.x*8 + (threadIdx.x>>5);
  int k = threadIdx.x & 31;
  float a[16];
  {
    const float4* Arow = (const float4*)(A + ((size_t)n*KDIM + k)*NSHD);
    const float inv_avg = 1.0f/16.0f;
    #pragma unroll
    for (int q=0;q<4;q++){
      float4 t = Arow[q];
      a[q*4+0]=t.x*inv_avg; a[q*4+1]=t.y*inv_avg;
      a[q*4+2]=t.z*inv_avg; a[q*4+3]=t.w*inv_avg;
    }
  }
  float g2[16], g3[16];
  #pragma unroll
  for (int i=0;i<16;i++){
    float s=0.f;
    #pragma unroll
    for (int j=0;j<16;j++) s += U2ss[i*16+j]*a[j];
    g2[i]=s;
  }
  #pragma unroll
  for (int i=0;i<16;i++){
    float s=0.f;
    #pragma unroll
    for (int j=0;j<16;j++){
      const float4* row = (const float4*)(G3s + (i*16+j)*16);
      float aj = a[j];
      #pragma unroll
      for (int lq=0;lq<4;lq++){
        float4 t = row[lq];
        s += aj*(t.x*a[lq*4+0]+t.y*a[lq*4+1]+t.z*a[lq*4+2]+t.w*a[lq*4+3]);
      }
    }
    g3[i]=s;
  }
  float B2=0.f, B3=0.f;
  #pragma unroll
  for (int i=0;i<16;i++){ B2 += a[i]*g2[i]; B3 += a[i]*g3[i]; }
  B2 *= 0.5f; B3 *= (1.0f/3.0f);
  float c1k=c123[k], c2k=c123[KDIM+k], c3k=c123[2*KDIM+k];
  float contrib = a[0]*c1k + B2*c2k + B3*c3k + xbuf[n*KDIM+k]*Wread[k];
  {
    float4* gRow = (float4*)(gA + ((size_t)n*KDIM + k)*NSHD);
    const float s16 = 1.0f/16.0f;
    #pragma unroll
    for (int q=0;q<4;q++){
      float4 t;
      t.x = (c2k*g2[q*4+0]+c3k*g3[q*4+0])*s16;
      t.y = (c2k*g2[q*4+1]+c3k*g3[q*4+1])*s16;
      t.z = (c2k*g2[q*4+2]+c3k*g3[q*4+2])*s16;
      t.w = (c2k*g2[q*4+3]+c3k*g3[q*4+3])*s16;
      if (q==0) t.x += c1k*s16;
      gRow[q]=t;
    }
  }
  #pragma unroll
  for (int off=1; off<32; off<<=1) contrib += __shfl_xor(contrib, off, 64);
  if (k==0) atomicAdd(&out_e[batch[n]], contrib);
}

// ---------------------------------------------------------------- edge backward
// one wave per edge: gather gA[receiver], chain rule to positions.
__global__ void edge_bwd_kernel(const float* __restrict__ pos, const int* __restrict__ eidx,
                                const float* __restrict__ shifts, const float* __restrict__ ybuf,
                                const float* __restrict__ W_r1, const float* __restrict__ b_r1,
                                const float* __restrict__ W_r2, const float* __restrict__ gA,
                                float* __restrict__ F){
  __shared__ float ga_sh[4][KDIM*NSHD];
  __shared__ float s_sh[4][NHID];
  __shared__ float xs_sh[4][KDIM];
  __shared__ float gRw_sh[4][KDIM];
  __shared__ float gh_sh[4][NHID];
  __shared__ float gsh_sh[4][NSHD];
  int wl = threadIdx.x >> 6, lane = threadIdx.x & 63;
  int e = blockIdx.x*4 + wl;
  int snd = eidx[e], rcv = eidx[NEDGES + e];
  float vx = pos[rcv*3+0] - pos[snd*3+0] + shifts[e*3+0];
  float vy = pos[rcv*3+1] - pos[snd*3+1] + shifts[e*3+1];
  float vz = pos[rcv*3+2] - pos[snd*3+2] + shifts[e*3+2];
  float r2 = vx*vx+vy*vy+vz*vz + 1e-18f;
  float r = sqrtf(r2);
  float invr = 1.0f/r;
  float ux=vx*invr, uy=vy*invr, uz=vz*invr;
  float u = r*(1.0f/RMAXF);
  float cut = 0.f;
  if (u < 1.0f){
    float u2=u*u, u3=u2*u, u6=u3*u3;
    cut = 1.0f - 28.0f*u6 + 48.0f*u6*u - 21.0f*u6*u2;
  }
  float sh[16];
  compute_sh(ux,uy,uz,sh);
  float b[NB];
  #pragma unroll
  for (int q=0;q<NB;q++)
    b[q] = CBES * sinf(PI_F*(float)(q+1)*u) * invr * cut;
  int m = lane;
  float h = b_r1[m];
  #pragma unroll
  for (int q=0;q<NB;q++) h += b[q]*W_r1[q*NHID+m];
  float sig = 1.0f/(1.0f+expf(-h));
  float sp = sig*(1.0f + h*(1.0f-sig));   // silu'(h)
  s_sh[wl][m] = h*sig;
  const float* gRow = gA + (size_t)rcv*(KDIM*NSHD);
  #pragma unroll
  for (int j=0;j<8;j++){
    int v = lane + 64*j;
    ga_sh[wl][v] = gRow[v];
  }
  __syncthreads();
  if (lane < 32){
    int k = lane;
    float Rw = 0.f;
    #pragma unroll 8
    for (int mm=0;mm<NHID;mm++) Rw += s_sh[wl][mm]*W_r2[mm*KDIM+k];
    float ysk = ybuf[snd*KDIM+k];
    xs_sh[wl][k] = ysk*Rw;
    float gxs = 0.f;
    #pragma unroll
    for (int i=0;i<16;i++) gxs += ga_sh[wl][k*16+i]*sh[i];
    gRw_sh[wl][k] = gxs*ysk;
  }
  __syncthreads();
  {
    float gs = 0.f;
    #pragma unroll 8
    for (int kk=0;kk<KDIM;kk++) gs += gRw_sh[wl][kk]*W_r2[m*KDIM+kk];
    gh_sh[wl][m] = gs*sp;
  }
  if (lane < 16){
    int i = lane;
    float gshv = 0.f;
    #pragma unroll 8
    for (int kk=0;kk<KDIM;kk++) gshv += ga_sh[wl][kk*16+i]*xs_sh[wl][kk];
    gsh_sh[wl][i] = gshv;
  }
  __syncthreads();
  float grad_r = 0.f;
  if (lane < 8){
    int q = lane;
    float gb = 0.f;
    #pragma unroll 8
    for (int mm=0;mm<NHID;mm++) gb += gh_sh[wl][mm]*W_r1[q*NHID+mm];
    float nn = (float)(q+1);
    float ang = PI_F*nn*u;
    float sn = sinf(ang), cs = cosf(ang);
    float dcutdr = 0.f;
    if (u < 1.0f){
      float u2=u*u, u4=u2*u2, omu=1.0f-u;
      dcutdr = -168.0f*u4*u*omu*omu*(1.0f/RMAXF);
    }
    float db = CBES*invr*((PI_F*nn*(1.0f/RMAXF))*cs - sn*invr)*cut
             + CBES*sn*invr*dcutdr;
    grad_r = gb*db;
  }
  grad_r += __shfl_xor(grad_r,1,64);
  grad_r += __shfl_xor(grad_r,2,64);
  grad_r += __shfl_xor(grad_r,4,64);
  if (lane == 0){
    float g[16];
    #pragma unroll
    for (int i=0;i<16;i++) g[i]=gsh_sh[wl][i];
    float x_=ux, y_=uy, z_=uz;
    float x2=x_*x_, y2=y_*y_, z2=z_*z_;
    float gux = 0.48860251f*g[3]
              + 1.09254843f*(y_*g[4] + z_*g[7])
              + 1.09254844f*x_*g[8]
              + 3.54026154f*x_*y_*g[9]
              + 2.89061144f*y_*z_*g[10]
              + 0.45704579f*(5.0f*z2-1.0f)*g[13]
              + 2.89061144f*x_*z_*g[14]
              + 1.77013077f*(x2-y2)*g[15];
    float guy = 0.48860251f*g[1]
              + 1.09254843f*(x_*g[4] + z_*g[5])
              - 1.09254844f*y_*g[8]
              + 1.77013077f*(x2-y2)*g[9]
              + 2.89061144f*x_*z_*g[10]
              + 0.45704579f*(5.0f*z2-1.0f)*g[11]
              - 2.89061144f*y_*z_*g[14]
              - 3.54026154f*x_*y_*g[15];
    float guz = 0.48860251f*g[2]
              + 1.09254843f*(y_*g[5] + x_*g[7])
              + 1.89234942f*z_*g[6]
              + 2.89061144f*x_*y_*g[10]
              + 4.5704579f*y_*z_*g[11]
              + 0.37317633f*(15.0f*z2-3.0f)*g[12]
              + 4.5704579f*x_*z_*g[13]
              + 1.44530572f*(x2-y2)*g[14];
    float dotg = gux*x_ + guy*y_ + guz*z_;
    float gvx = grad_r*x_ + (gux - dotg*x_)*invr;
    float gvy = grad_r*y_ + (guy - dotg*y_)*invr;
    float gvz = grad_r*z_ + (guz - dotg*z_)*invr;
    // F = -dE/dpos: vec = pos[rcv]-pos[snd]  => F[snd] += gvec, F[rcv] -= gvec
    atomicAdd(&F[snd*3+0],  gvx);
    atomicAdd(&F[snd*3+1],  gvy);
    atomicAdd(&F[snd*3+2],  gvz);
    atomicAdd(&F[rcv*3+0], -gvx);
    atomicAdd(&F[rcv*3+1], -gvy);
    atomicAdd(&F[rcv*3+2], -gvz);
  }
}

extern "C" void kernel_launch(void* const* d_in, const int* in_sizes, int n_in,
                              void* d_out, int out_size, void* d_ws, size_t ws_size,
                              hipStream_t stream){
  const float* positions       = (const float*)d_in[0];
  const float* node_attrs      = (const float*)d_in[1];
  const int*   edge_index      = (const int*)  d_in[2];
  const float* shifts          = (const float*)d_in[3];
  const int*   batch           = (const int*)  d_in[4];
  /* d_in[5] = num_graphs (hardcoded 16) */
  const float* atomic_energies = (const float*)d_in[6];
  const float* W_embed         = (const float*)d_in[7];
  const float* W_up            = (const float*)d_in[8];
  const float* W_r1            = (const float*)d_in[9];
  const float* b_r1            = (const float*)d_in[10];
  const float* W_r2            = (const float*)d_in[11];
  const float* U2              = (const float*)d_in[12];
  const float* U3              = (const float*)d_in[13];
  const float* Wp1             = (const float*)d_in[14];
  const float* Wp2             = (const float*)d_in[15];
  const float* Wp3             = (const float*)d_in[16];
  const float* W_read          = (const float*)d_in[17];
  float* out = (float*)d_out;

  float* A    = (float*)d_ws;                         // N*512  (64 MB)
  float* gA   = A    + (size_t)NNODES*KDIM*NSHD;      // N*512  (64 MB)
  float* xbuf = gA   + (size_t)NNODES*KDIM*NSHD;      // N*32
  float* ybuf = xbuf + (size_t)NNODES*KDIM;           // N*32
  float* G3   = ybuf + (size_t)NNODES*KDIM;           // 4096
  float* U2s  = G3   + 4096;                          // 256
  float* c123 = U2s  + 256;                           // 96

  hipMemsetAsync(d_out, 0, sizeof(float)*(NGRAPH + (size_t)NNODES*3), stream);
  hipMemsetAsync(A, 0, sizeof(float)*(size_t)NNODES*KDIM*NSHD, stream);

  prep_kernel<<<1,256,0,stream>>>(U2,U3,Wp1,Wp2,Wp3,W_read,G3,U2s,c123);
  node_embed_kernel<<<NNODES/4,256,0,stream>>>(node_attrs,W_embed,W_up,atomic_energies,
                                               batch,xbuf,ybuf,out);
  edge_fwd_kernel<<<NEDGES/4,256,0,stream>>>(positions,edge_index,shifts,ybuf,
                                             W_r1,b_r1,W_r2,A);
  node_b_kernel<<<NNODES/8,256,0,stream>>>(A,xbuf,batch,G3,U2s,c123,W_read,gA,out);
  edge_bwd_kernel<<<NEDGES/4,256,0,stream>>>(positions,edge_index,shifts,ybuf,
                                             W_r1,b_r1,W_r2,gA,out+NGRAPH);
}

// Round 2
// 3236.290 us; speedup vs baseline: 1.1217x; 1.1217x over previous
//
#include <hip/hip_runtime.h>
#include <math.h>

#define NNODES 32768
#define NEDGES 524288
#define KDIM 32
#define NSHD 16
#define NB 8
#define NHID 64
#define NGRAPH 16
#define NELEM 10
#define RMAXF 5.0f
#define INVR_MAX 0.2f
#define PI_F 3.14159265358979f
#define CBES 0.632455532033676f   /* sqrt(2/R_MAX) */

__device__ __forceinline__ void compute_sh(float x, float y, float z, float* sh){
  float x2=x*x, y2=y*y, z2=z*z;
  sh[0]=0.28209479f;
  sh[1]=0.48860251f*y;
  sh[2]=0.48860251f*z;
  sh[3]=0.48860251f*x;
  sh[4]=1.09254843f*x*y;
  sh[5]=1.09254843f*y*z;
  sh[6]=0.31539157f*(3.0f*z2-1.0f);
  sh[7]=1.09254843f*x*z;
  sh[8]=0.54627422f*(x2-y2);
  sh[9]=0.59004359f*y*(3.0f*x2-y2);
  sh[10]=2.89061144f*x*y*z;
  sh[11]=0.45704579f*y*(5.0f*z2-1.0f);
  sh[12]=0.37317633f*z*(5.0f*z2-3.0f);
  sh[13]=0.45704579f*x*(5.0f*z2-1.0f);
  sh[14]=1.44530572f*z*(x2-y2);
  sh[15]=0.59004359f*x*(x2-3.0f*y2);
}

// ---------------------------------------------------------------- prep
__global__ void prep_kernel(const float* __restrict__ U2, const float* __restrict__ U3,
                            const float* __restrict__ Wp1, const float* __restrict__ Wp2,
                            const float* __restrict__ Wp3, const float* __restrict__ Wread,
                            float* __restrict__ G3, float* __restrict__ U2s,
                            float* __restrict__ c123){
  int t = threadIdx.x;
  for (int v = t; v < 4096; v += 256){
    int i = v >> 8, j = (v >> 4) & 15, l = v & 15;
    G3[v] = U3[i*256 + j*16 + l] + U3[j*256 + i*16 + l] + U3[j*256 + l*16 + i];
  }
  {
    int i = t >> 4, j = t & 15;
    U2s[t] = U2[i*16+j] + U2[j*16+i];
  }
  if (t < 96){
    int which = t >> 5, k = t & 31;
    const float* Wp = (which==0)?Wp1:((which==1)?Wp2:Wp3);
    float s = 0.f;
    for (int q=0;q<KDIM;q++) s += Wp[k*KDIM+q]*Wread[q];
    c123[t] = s;
  }
}

// ---------------------------------------------------------------- CSR build
__global__ void csr_count_kernel(const int* __restrict__ eidx, int* __restrict__ cnt){
  int e = blockIdx.x*256 + threadIdx.x;
  if (e < NEDGES) atomicAdd(&cnt[eidx[NEDGES + e]], 1);
}

__global__ void csr_scan_kernel(const int* __restrict__ cnt, int* __restrict__ row_start,
                                int* __restrict__ woff){
  __shared__ int part[1024];
  int t = threadIdx.x;
  int base_idx = t*32;
  int local[32];
  int s = 0;
  #pragma unroll
  for (int j=0;j<32;j++){
    int c = cnt[base_idx+j];
    local[j] = s;          // exclusive within chunk
    s += c;
  }
  part[t] = s;
  __syncthreads();
  for (int off=1; off<1024; off<<=1){
    int v = (t>=off) ? part[t-off] : 0;
    __syncthreads();
    part[t] += v;
    __syncthreads();
  }
  int base = (t==0) ? 0 : part[t-1];
  #pragma unroll
  for (int j=0;j<32;j++){
    int v = base + local[j];
    row_start[base_idx+j] = v;
    woff[base_idx+j] = v;
  }
  if (t==1023) row_start[NNODES] = part[1023];
}

__global__ void csr_scatter_kernel(const int* __restrict__ eidx, int* __restrict__ woff,
                                   int* __restrict__ elist){
  int e = blockIdx.x*256 + threadIdx.x;
  if (e < NEDGES){
    int rcv = eidx[NEDGES + e];
    int p = atomicAdd(&woff[rcv], 1);
    elist[p] = e;
  }
}

// ---------------------------------------------------------------- node embed
__global__ void node_embed_kernel(const float* __restrict__ attrs,
                                  const float* __restrict__ W_embed,
                                  const float* __restrict__ W_up,
                                  const float* __restrict__ ae,
                                  const int* __restrict__ batch,
                                  float* __restrict__ xbuf, float* __restrict__ ybuf,
                                  float* __restrict__ out_e){
  int gtid = blockIdx.x*256 + threadIdx.x;
  int n = gtid >> 6;
  int lane = threadIdx.x & 63;
  int k = lane & 31;
  float xv = 0.f;
  #pragma unroll
  for (int e=0;e<NELEM;e++) xv += attrs[n*NELEM+e]*W_embed[e*KDIM+k];
  float yv = 0.f;
  #pragma unroll 8
  for (int k2=0;k2<KDIM;k2++) yv += __shfl(xv, k2, 64) * W_up[k2*KDIM+k];
  if (lane < 32){
    xbuf[n*KDIM+k]=xv;
    ybuf[n*KDIM+k]=yv;
  }
  if (lane == 0){
    float s=0.f;
    #pragma unroll
    for (int e=0;e<NELEM;e++) s += attrs[n*NELEM+e]*ae[e];
    atomicAdd(&out_e[batch[n]], s);
  }
}

// ---------------------------------------------------------------- node-centric forward
// one wave per node; lane roles: m=lane (radial hidden), (k2=lane>>1, ihalf=lane&1)
// for the A fragment (8 floats/lane, register resident). No atomics.
__global__ void __launch_bounds__(256) node_fwd_kernel(
    const int* __restrict__ elist, const int* __restrict__ row_start,
    const int* __restrict__ eidx, const float* __restrict__ shifts,
    const float* __restrict__ pos, const float* __restrict__ ybuf,
    const float* __restrict__ W_r1, const float* __restrict__ b_r1,
    const float* __restrict__ W_r2, float* __restrict__ A){
  __shared__ float Wr1s[576];     // [q*64+m], + b_r1 at 512
  __shared__ float Wr2s[2048];    // [m*32+k]
  __shared__ float sbuf[4][64];
  int tid = threadIdx.x;
  for (int v=tid; v<512; v+=256) Wr1s[v]=W_r1[v];
  if (tid<64) Wr1s[512+tid]=b_r1[tid];
  for (int v=tid; v<2048; v+=256) Wr2s[v]=W_r2[v];
  __syncthreads();
  int wl = tid>>6, lane = tid&63;
  int n = blockIdx.x*4 + wl;
  int kk = lane&31, mb = (lane>>5)*32;
  int k2 = lane>>1, ihalf = lane&1;
  float Areg[8];
  #pragma unroll
  for (int j=0;j<8;j++) Areg[j]=0.f;
  float px=pos[n*3+0], py=pos[n*3+1], pz=pos[n*3+2];
  int rs=row_start[n], re=row_start[n+1];
  for (int p=rs; p<re; ++p){
    int e = elist[p];
    int snd = eidx[e];
    float vx = px - pos[snd*3+0] + shifts[e*3+0];
    float vy = py - pos[snd*3+1] + shifts[e*3+1];
    float vz = pz - pos[snd*3+2] + shifts[e*3+2];
    float r2 = vx*vx+vy*vy+vz*vz + 1e-18f;
    float r = sqrtf(r2);
    float invr = 1.0f/r;
    float ux=vx*invr, uy=vy*invr, uz=vz*invr;
    float u = r*INVR_MAX;
    float cut = 0.f;
    if (u < 1.0f){
      float u2=u*u, u3=u2*u, u6=u3*u3;
      cut = 1.0f - 28.0f*u6 + 48.0f*u6*u - 21.0f*u6*u2;
    }
    float th = PI_F*u;
    float s1=__sinf(th), c1=__cosf(th);
    float cb = CBES*invr*cut;
    float b[NB];
    float Sp=0.f, Sc=s1;
    b[0]=Sc*cb;
    #pragma unroll
    for (int q=1;q<NB;q++){ float Sn=2.f*c1*Sc-Sp; Sp=Sc; Sc=Sn; b[q]=Sc*cb; }
    float sh[16];
    compute_sh(ux,uy,uz,sh);
    // radial hidden: m = lane
    float h = Wr1s[512+lane];
    #pragma unroll
    for (int q=0;q<NB;q++) h += b[q]*Wr1s[q*64+lane];
    float sg = 1.0f/(1.0f+__expf(-h));
    sbuf[wl][lane] = h*sg;
    // Rw[kk]: half-split m-sum (in-wave LDS exchange, no barrier needed)
    float rwp = 0.f;
    #pragma unroll
    for (int j=0;j<32;j++) rwp += sbuf[wl][mb+j]*Wr2s[(mb+j)*32+kk];
    float rw = rwp + __shfl_xor(rwp, 32);
    float y = ybuf[snd*KDIM+kk];
    float xs = y*rw;                    // valid per lane for k=kk
    float xsb = __shfl(xs, k2);         // xs[k2] broadcast to lane pair
    #pragma unroll
    for (int j=0;j<8;j++) Areg[j] += xsb*sh[ihalf*8+j];
  }
  // lane L covers A[n][k2][ihalf*8 + j]  => offset = n*512 + lane*8 (contiguous)
  float4* Ao = (float4*)(A + (size_t)n*512 + lane*8);
  Ao[0] = make_float4(Areg[0],Areg[1],Areg[2],Areg[3]);
  Ao[1] = make_float4(Areg[4],Areg[5],Areg[6],Areg[7]);
}

// ---------------------------------------------------------------- node B-ops (unchanged)
__global__ void node_b_kernel(const float* __restrict__ A, const float* __restrict__ xbuf,
                              const int* __restrict__ batch, const float* __restrict__ G3g,
                              const float* __restrict__ U2sg, const float* __restrict__ c123,
                              const float* __restrict__ Wread, float* __restrict__ gA,
                              float* __restrict__ out_e){
  __shared__ float G3s[4096];
  __shared__ float U2ss[256];
  for (int v=threadIdx.x; v<4096; v+=256) G3s[v]=G3g[v];
  U2ss[threadIdx.x]=U2sg[threadIdx.x];
  __syncthreads();
  int n = blockIdx.x*8 + (threadIdx.x>>5);
  int k = threadIdx.x & 31;
  float a[16];
  {
    const float4* Arow = (const float4*)(A + ((size_t)n*KDIM + k)*NSHD);
    const float inv_avg = 1.0f/16.0f;
    #pragma unroll
    for (int q=0;q<4;q++){
      float4 t = Arow[q];
      a[q*4+0]=t.x*inv_avg; a[q*4+1]=t.y*inv_avg;
      a[q*4+2]=t.z*inv_avg; a[q*4+3]=t.w*inv_avg;
    }
  }
  float g2[16], g3[16];
  #pragma unroll
  for (int i=0;i<16;i++){
    float s=0.f;
    #pragma unroll
    for (int j=0;j<16;j++) s += U2ss[i*16+j]*a[j];
    g2[i]=s;
  }
  #pragma unroll
  for (int i=0;i<16;i++){
    float s=0.f;
    #pragma unroll
    for (int j=0;j<16;j++){
      const float4* row = (const float4*)(G3s + (i*16+j)*16);
      float aj = a[j];
      #pragma unroll
      for (int lq=0;lq<4;lq++){
        float4 t = row[lq];
        s += aj*(t.x*a[lq*4+0]+t.y*a[lq*4+1]+t.z*a[lq*4+2]+t.w*a[lq*4+3]);
      }
    }
    g3[i]=s;
  }
  float B2=0.f, B3=0.f;
  #pragma unroll
  for (int i=0;i<16;i++){ B2 += a[i]*g2[i]; B3 += a[i]*g3[i]; }
  B2 *= 0.5f; B3 *= (1.0f/3.0f);
  float c1k=c123[k], c2k=c123[KDIM+k], c3k=c123[2*KDIM+k];
  float contrib = a[0]*c1k + B2*c2k + B3*c3k + xbuf[n*KDIM+k]*Wread[k];
  {
    float4* gRow = (float4*)(gA + ((size_t)n*KDIM + k)*NSHD);
    const float s16 = 1.0f/16.0f;
    #pragma unroll
    for (int q=0;q<4;q++){
      float4 t;
      t.x = (c2k*g2[q*4+0]+c3k*g3[q*4+0])*s16;
      t.y = (c2k*g2[q*4+1]+c3k*g3[q*4+1])*s16;
      t.z = (c2k*g2[q*4+2]+c3k*g3[q*4+2])*s16;
      t.w = (c2k*g2[q*4+3]+c3k*g3[q*4+3])*s16;
      if (q==0) t.x += c1k*s16;
      gRow[q]=t;
    }
  }
  #pragma unroll
  for (int off=1; off<32; off<<=1) contrib += __shfl_xor(contrib, off, 64);
  if (k==0) atomicAdd(&out_e[batch[n]], contrib);
}

// ---------------------------------------------------------------- node-centric backward
// one wave per node; gA row register-resident (loaded once). 3 atomics/edge.
__global__ void __launch_bounds__(256) node_bwd_kernel(
    const int* __restrict__ elist, const int* __restrict__ row_start,
    const int* __restrict__ eidx, const float* __restrict__ shifts,
    const float* __restrict__ pos, const float* __restrict__ ybuf,
    const float* __restrict__ W_r1, const float* __restrict__ b_r1,
    const float* __restrict__ W_r2, const float* __restrict__ gA,
    float* __restrict__ F){
  __shared__ float Wr1s[576];
  __shared__ float Wr2s[2048];    // [m*32+k]
  __shared__ float W2Ts[2048];    // transposed: [k*64+m]  (avoids 64-way bank conflict)
  __shared__ float sbuf[4][64];
  __shared__ float grwbuf[4][32];
  __shared__ float gshbuf[4][16];
  int tid = threadIdx.x;
  for (int v=tid; v<512; v+=256) Wr1s[v]=W_r1[v];
  if (tid<64) Wr1s[512+tid]=b_r1[tid];
  for (int v=tid; v<2048; v+=256){
    Wr2s[v]=W_r2[v];
    int k=v>>6, m=v&63;
    W2Ts[v]=W_r2[m*32+k];
  }
  __syncthreads();
  int wl = tid>>6, lane = tid&63;
  int n = blockIdx.x*4 + wl;
  int kk = lane&31, mb = (lane>>5)*32;
  int k2 = lane>>1, ihalf = lane&1;
  float ga[8];
  {
    const float4* gi = (const float4*)(gA + (size_t)n*512 + lane*8);
    float4 t0=gi[0], t1=gi[1];
    ga[0]=t0.x; ga[1]=t0.y; ga[2]=t0.z; ga[3]=t0.w;
    ga[4]=t1.x; ga[5]=t1.y; ga[6]=t1.z; ga[7]=t1.w;
  }
  float px=pos[n*3+0], py=pos[n*3+1], pz=pos[n*3+2];
  float Fnx=0.f, Fny=0.f, Fnz=0.f;
  int rs=row_start[n], re=row_start[n+1];
  for (int p=rs; p<re; ++p){
    int e = elist[p];
    int snd = eidx[e];
    float vx = px - pos[snd*3+0] + shifts[e*3+0];
    float vy = py - pos[snd*3+1] + shifts[e*3+1];
    float vz = pz - pos[snd*3+2] + shifts[e*3+2];
    float r2 = vx*vx+vy*vy+vz*vz + 1e-18f;
    float r = sqrtf(r2);
    float invr = 1.0f/r;
    float ux=vx*invr, uy=vy*invr, uz=vz*invr;
    float u = r*INVR_MAX;
    float cut = 0.f, dcdr = 0.f;
    if (u < 1.0f){
      float u2=u*u, u3=u2*u, u6=u3*u3;
      cut = 1.0f - 28.0f*u6 + 48.0f*u6*u - 21.0f*u6*u2;
      float u4=u2*u2, om=1.0f-u;
      dcdr = -168.0f*u4*u*om*om*INVR_MAX;
    }
    float th = PI_F*u;
    float s1=__sinf(th), c1=__cosf(th);
    float cb = CBES*invr*cut;
    float b[NB], db[NB];
    {
      float Sp=0.f, Sc=s1, Cp=1.0f, Cc=c1;
      b[0]=Sc*cb;
      db[0]=CBES*invr*((PI_F*1.0f*INVR_MAX)*Cc - Sc*invr)*cut + CBES*Sc*invr*dcdr;
      #pragma unroll
      for (int q=1;q<NB;q++){
        float Sn=2.f*c1*Sc-Sp; Sp=Sc; Sc=Sn;
        float Cn=2.f*c1*Cc-Cp; Cp=Cc; Cc=Cn;
        b[q]=Sc*cb;
        db[q]=CBES*invr*((PI_F*(float)(q+1)*INVR_MAX)*Cc - Sc*invr)*cut + CBES*Sc*invr*dcdr;
      }
    }
    float sh[16];
    compute_sh(ux,uy,uz,sh);
    // forward radial recompute: m = lane
    float h = Wr1s[512+lane];
    #pragma unroll
    for (int q=0;q<NB;q++) h += b[q]*Wr1s[q*64+lane];
    float sg = 1.0f/(1.0f+__expf(-h));
    float sp_ = sg*(1.0f + h*(1.0f-sg));
    sbuf[wl][lane] = h*sg;
    float rwp = 0.f;
    #pragma unroll
    for (int j=0;j<32;j++) rwp += sbuf[wl][mb+j]*Wr2s[(mb+j)*32+kk];
    float rw = rwp + __shfl_xor(rwp, 32);
    float y = ybuf[snd*KDIM+kk];
    float xs = y*rw;
    // gxs[k2] = sum_i ga[k2][i]*sh[i] via lane-pair
    float pgx = 0.f;
    #pragma unroll
    for (int j=0;j<8;j++) pgx += ga[j]*sh[ihalf*8+j];
    float gxs = pgx + __shfl_xor(pgx, 1);
    float yk2 = __shfl(y, k2);
    float grw = gxs*yk2;
    if (ihalf==0) grwbuf[wl][k2] = grw;
    // gsh[i] = sum_k ga[k][i]*xs[k]: parity-preserving butterfly
    float xsb = __shfl(xs, k2);
    float pg[8];
    #pragma unroll
    for (int j=0;j<8;j++) pg[j] = ga[j]*xsb;
    #pragma unroll
    for (int mask=2; mask<64; mask<<=1){
      #pragma unroll
      for (int j=0;j<8;j++) pg[j] += __shfl_xor(pg[j], mask);
    }
    if (lane < 2){
      #pragma unroll
      for (int j=0;j<8;j++) gshbuf[wl][lane*8+j] = pg[j];
    }
    // gh_m = (sum_k gRw[k] W_r2[m][k]) * silu'(h_m)
    float gs = 0.f;
    #pragma unroll
    for (int q=0;q<32;q++) gs += grwbuf[wl][q]*W2Ts[q*64+lane];
    float gh = gs*sp_;
    // grad_r = sum_m gh_m * (sum_q W_r1[q][m] db[q])
    float dbw = 0.f;
    #pragma unroll
    for (int q=0;q<NB;q++) dbw += db[q]*Wr1s[q*64+lane];
    float pr = gh*dbw;
    #pragma unroll
    for (int mask=1; mask<64; mask<<=1) pr += __shfl_xor(pr, mask);
    float grad_r = pr;
    float g[16];
    #pragma unroll
    for (int i=0;i<16;i++) g[i] = gshbuf[wl][i];
    // angular gradient (uniform on all lanes)
    float x_=ux, y_=uy, z_=uz;
    float x2=x_*x_, y2=y_*y_, z2=z_*z_;
    float gux = 0.48860251f*g[3]
              + 1.09254843f*(y_*g[4] + z_*g[7])
              + 1.09254844f*x_*g[8]
              + 3.54026154f*x_*y_*g[9]
              + 2.89061144f*y_*z_*g[10]
              + 0.45704579f*(5.0f*z2-1.0f)*g[13]
              + 2.89061144f*x_*z_*g[14]
              + 1.77013077f*(x2-y2)*g[15];
    float guy = 0.48860251f*g[1]
              + 1.09254843f*(x_*g[4] + z_*g[5])
              - 1.09254844f*y_*g[8]
              + 1.77013077f*(x2-y2)*g[9]
              + 2.89061144f*x_*z_*g[10]
              + 0.45704579f*(5.0f*z2-1.0f)*g[11]
              - 2.89061144f*y_*z_*g[14]
              - 3.54026154f*x_*y_*g[15];
    float guz = 0.48860251f*g[2]
              + 1.09254843f*(y_*g[5] + x_*g[7])
              + 1.89234942f*z_*g[6]
              + 2.89061144f*x_*y_*g[10]
              + 4.5704579f*y_*z_*g[11]
              + 0.37317633f*(15.0f*z2-3.0f)*g[12]
              + 4.5704579f*x_*z_*g[13]
              + 1.44530572f*(x2-y2)*g[14];
    float dotg = gux*x_ + guy*y_ + guz*z_;
    float gvx = grad_r*x_ + (gux - dotg*x_)*invr;
    float gvy = grad_r*y_ + (guy - dotg*y_)*invr;
    float gvz = grad_r*z_ + (guz - dotg*z_)*invr;
    // vec = pos[rcv]-pos[snd]; F = -dE/dp => F[snd] += gvec, F[rcv=n] -= gvec
    if (lane == 0){
      atomicAdd(&F[snd*3+0], gvx);
      atomicAdd(&F[snd*3+1], gvy);
      atomicAdd(&F[snd*3+2], gvz);
    }
    Fnx -= gvx; Fny -= gvy; Fnz -= gvz;
  }
  if (lane == 0){
    atomicAdd(&F[n*3+0], Fnx);
    atomicAdd(&F[n*3+1], Fny);
    atomicAdd(&F[n*3+2], Fnz);
  }
}

extern "C" void kernel_launch(void* const* d_in, const int* in_sizes, int n_in,
                              void* d_out, int out_size, void* d_ws, size_t ws_size,
                              hipStream_t stream){
  const float* positions       = (const float*)d_in[0];
  const float* node_attrs      = (const float*)d_in[1];
  const int*   edge_index      = (const int*)  d_in[2];
  const float* shifts          = (const float*)d_in[3];
  const int*   batch           = (const int*)  d_in[4];
  const float* atomic_energies = (const float*)d_in[6];
  const float* W_embed         = (const float*)d_in[7];
  const float* W_up            = (const float*)d_in[8];
  const float* W_r1            = (const float*)d_in[9];
  const float* b_r1            = (const float*)d_in[10];
  const float* W_r2            = (const float*)d_in[11];
  const float* U2              = (const float*)d_in[12];
  const float* U3              = (const float*)d_in[13];
  const float* Wp1             = (const float*)d_in[14];
  const float* Wp2             = (const float*)d_in[15];
  const float* Wp3             = (const float*)d_in[16];
  const float* W_read          = (const float*)d_in[17];
  float* out = (float*)d_out;

  float* A    = (float*)d_ws;                         // 32768*512 = 64 MB
  float* gA   = A    + (size_t)NNODES*KDIM*NSHD;      // 64 MB
  float* xbuf = gA   + (size_t)NNODES*KDIM*NSHD;      // 4 MB
  float* ybuf = xbuf + (size_t)NNODES*KDIM;           // 4 MB
  float* G3   = ybuf + (size_t)NNODES*KDIM;           // 16 KB
  float* U2s  = G3   + 4096;
  float* c123 = U2s  + 256;
  int* cnt       = (int*)(c123 + 128);
  int* row_start = cnt + NNODES;
  int* woff      = row_start + NNODES + 1;
  int* elist     = woff + NNODES;                     // 2 MB

  hipMemsetAsync(d_out, 0, sizeof(float)*(NGRAPH + (size_t)NNODES*3), stream);
  hipMemsetAsync(cnt, 0, sizeof(int)*NNODES, stream);

  prep_kernel<<<1,256,0,stream>>>(U2,U3,Wp1,Wp2,Wp3,W_read,G3,U2s,c123);
  csr_count_kernel<<<NEDGES/256,256,0,stream>>>(edge_index, cnt);
  csr_scan_kernel<<<1,1024,0,stream>>>(cnt, row_start, woff);
  csr_scatter_kernel<<<NEDGES/256,256,0,stream>>>(edge_index, woff, elist);
  node_embed_kernel<<<NNODES/4,256,0,stream>>>(node_attrs,W_embed,W_up,atomic_energies,
                                               batch,xbuf,ybuf,out);
  node_fwd_kernel<<<NNODES/4,256,0,stream>>>(elist,row_start,edge_index,shifts,
                                             positions,ybuf,W_r1,b_r1,W_r2,A);
  node_b_kernel<<<NNODES/8,256,0,stream>>>(A,xbuf,batch,G3,U2s,c123,W_read,gA,out);
  node_bwd_kernel<<<NNODES/4,256,0,stream>>>(elist,row_start,edge_index,shifts,
                                             positions,ybuf,W_r1,b_r1,W_r2,gA,out+NGRAPH);
}

// Round 3
// 2704.237 us; speedup vs baseline: 1.3423x; 1.1967x over previous
//
#include <hip/hip_runtime.h>
#include <math.h>

#define NNODES 32768
#define NEDGES 524288
#define KDIM 32
#define NSHD 16
#define NB 8
#define NHID 64
#define NGRAPH 16
#define NELEM 10
#define RMAXF 5.0f
#define INVR_MAX 0.2f
#define PI_F 3.14159265358979f
#define CBES 0.632455532033676f   /* sqrt(2/R_MAX) */

__device__ __forceinline__ void compute_sh(float x, float y, float z, float* sh){
  float x2=x*x, y2=y*y, z2=z*z;
  sh[0]=0.28209479f;
  sh[1]=0.48860251f*y;
  sh[2]=0.48860251f*z;
  sh[3]=0.48860251f*x;
  sh[4]=1.09254843f*x*y;
  sh[5]=1.09254843f*y*z;
  sh[6]=0.31539157f*(3.0f*z2-1.0f);
  sh[7]=1.09254843f*x*z;
  sh[8]=0.54627422f*(x2-y2);
  sh[9]=0.59004359f*y*(3.0f*x2-y2);
  sh[10]=2.89061144f*x*y*z;
  sh[11]=0.45704579f*y*(5.0f*z2-1.0f);
  sh[12]=0.37317633f*z*(5.0f*z2-3.0f);
  sh[13]=0.45704579f*x*(5.0f*z2-1.0f);
  sh[14]=1.44530572f*z*(x2-y2);
  sh[15]=0.59004359f*x*(x2-3.0f*y2);
}

// ---------------------------------------------------------------- prep
__global__ void prep_kernel(const float* __restrict__ U2, const float* __restrict__ U3,
                            const float* __restrict__ Wp1, const float* __restrict__ Wp2,
                            const float* __restrict__ Wp3, const float* __restrict__ Wread,
                            float* __restrict__ G3, float* __restrict__ U2s,
                            float* __restrict__ c123){
  int t = threadIdx.x;
  for (int v = t; v < 4096; v += 256){
    int i = v >> 8, j = (v >> 4) & 15, l = v & 15;
    G3[v] = U3[i*256 + j*16 + l] + U3[j*256 + i*16 + l] + U3[j*256 + l*16 + i];
  }
  {
    int i = t >> 4, j = t & 15;
    U2s[t] = U2[i*16+j] + U2[j*16+i];
  }
  if (t < 96){
    int which = t >> 5, k = t & 31;
    const float* Wp = (which==0)?Wp1:((which==1)?Wp2:Wp3);
    float s = 0.f;
    for (int q=0;q<KDIM;q++) s += Wp[k*KDIM+q]*Wread[q];
    c123[t] = s;
  }
}

// ---------------------------------------------------------------- CSR build
__global__ void csr_count_kernel(const int* __restrict__ eidx, int* __restrict__ cnt){
  int e = blockIdx.x*256 + threadIdx.x;
  if (e < NEDGES) atomicAdd(&cnt[eidx[NEDGES + e]], 1);
}

__global__ void csr_scan_kernel(const int* __restrict__ cnt, int* __restrict__ row_start,
                                int* __restrict__ woff){
  __shared__ int part[1024];
  int t = threadIdx.x;
  int base_idx = t*32;
  int local[32];
  int s = 0;
  #pragma unroll
  for (int j=0;j<32;j++){
    int c = cnt[base_idx+j];
    local[j] = s;
    s += c;
  }
  part[t] = s;
  __syncthreads();
  for (int off=1; off<1024; off<<=1){
    int v = (t>=off) ? part[t-off] : 0;
    __syncthreads();
    part[t] += v;
    __syncthreads();
  }
  int base = (t==0) ? 0 : part[t-1];
  #pragma unroll
  for (int j=0;j<32;j++){
    int v = base + local[j];
    row_start[base_idx+j] = v;
    woff[base_idx+j] = v;
  }
  if (t==1023) row_start[NNODES] = part[1023];
}

__global__ void csr_scatter_kernel(const int* __restrict__ eidx, int* __restrict__ woff,
                                   int* __restrict__ elist){
  int e = blockIdx.x*256 + threadIdx.x;
  if (e < NEDGES){
    int rcv = eidx[NEDGES + e];
    int p = atomicAdd(&woff[rcv], 1);
    elist[p] = e;
  }
}

// ---------------------------------------------------------------- node embed
__global__ void node_embed_kernel(const float* __restrict__ attrs,
                                  const float* __restrict__ W_embed,
                                  const float* __restrict__ W_up,
                                  const float* __restrict__ ae,
                                  const int* __restrict__ batch,
                                  float* __restrict__ xbuf, float* __restrict__ ybuf,
                                  float* __restrict__ out_e){
  int gtid = blockIdx.x*256 + threadIdx.x;
  int n = gtid >> 6;
  int lane = threadIdx.x & 63;
  int k = lane & 31;
  float xv = 0.f;
  #pragma unroll
  for (int e=0;e<NELEM;e++) xv += attrs[n*NELEM+e]*W_embed[e*KDIM+k];
  float yv = 0.f;
  #pragma unroll 8
  for (int k2=0;k2<KDIM;k2++) yv += __shfl(xv, k2, 64) * W_up[k2*KDIM+k];
  if (lane < 32){
    xbuf[n*KDIM+k]=xv;
    ybuf[n*KDIM+k]=yv;
  }
  if (lane == 0){
    float s=0.f;
    #pragma unroll
    for (int e=0;e<NELEM;e++) s += attrs[n*NELEM+e]*ae[e];
    atomicAdd(&out_e[batch[n]], s);
  }
}

// ---------------------------------------------------------------- edge forward (thread-per-edge)
// thread p processes edge elist[p] (CSR position order). No cross-lane ops.
// Stores xs[k*E+p] (coalesced), v[c*E+p], snd[p], rcv[p].
__global__ void __launch_bounds__(256) edge_fwd_kernel(
    const int* __restrict__ elist, const int* __restrict__ eidx,
    const float* __restrict__ shifts, const float* __restrict__ pos,
    const float* __restrict__ ybuf,
    const float* __restrict__ W_r1, const float* __restrict__ b_r1,
    const float* __restrict__ W_r2,
    float* __restrict__ xsbuf, float* __restrict__ vbuf,
    int* __restrict__ sndbuf, int* __restrict__ rcvbuf){
  int p = blockIdx.x*256 + threadIdx.x;
  int e = elist[p];
  int snd = eidx[e], rcv = eidx[NEDGES + e];
  float vx = pos[rcv*3+0] - pos[snd*3+0] + shifts[e*3+0];
  float vy = pos[rcv*3+1] - pos[snd*3+1] + shifts[e*3+1];
  float vz = pos[rcv*3+2] - pos[snd*3+2] + shifts[e*3+2];
  float r2 = vx*vx+vy*vy+vz*vz + 1e-18f;
  float r = sqrtf(r2);
  float invr = 1.0f/r;
  float u = r*INVR_MAX;
  float u2=u*u, u3=u2*u, u6=u3*u3;
  float cutp = 1.0f - 28.0f*u6 + 48.0f*u6*u - 21.0f*u6*u2;
  float cut = (u < 1.0f) ? cutp : 0.f;
  float th = PI_F*u;
  float s1=__sinf(th), c1=__cosf(th);
  float cb = CBES*invr*cut;
  float b[NB];
  {
    float Sp=0.f, Sc=s1;
    b[0]=Sc*cb;
    #pragma unroll
    for (int q=1;q<NB;q++){ float Sn=2.f*c1*Sc-Sp; Sp=Sc; Sc=Sn; b[q]=Sc*cb; }
  }
  float Rw[KDIM];
  #pragma unroll
  for (int k=0;k<KDIM;k++) Rw[k]=0.f;
  #pragma unroll 4
  for (int m=0;m<NHID;m++){
    float h = b_r1[m];
    #pragma unroll
    for (int q=0;q<NB;q++) h += b[q]*W_r1[q*NHID+m];
    float s = h/(1.0f+__expf(-h));
    #pragma unroll
    for (int k=0;k<KDIM;k++) Rw[k] += s*W_r2[m*KDIM+k];
  }
  const float4* y4 = (const float4*)(ybuf + (size_t)snd*KDIM);
  #pragma unroll
  for (int t=0;t<8;t++){
    float4 yv = y4[t];
    xsbuf[(size_t)(4*t+0)*NEDGES + p] = yv.x*Rw[4*t+0];
    xsbuf[(size_t)(4*t+1)*NEDGES + p] = yv.y*Rw[4*t+1];
    xsbuf[(size_t)(4*t+2)*NEDGES + p] = yv.z*Rw[4*t+2];
    xsbuf[(size_t)(4*t+3)*NEDGES + p] = yv.w*Rw[4*t+3];
  }
  vbuf[p] = vx;
  vbuf[NEDGES + p] = vy;
  vbuf[2*NEDGES + p] = vz;
  sndbuf[p] = snd;
  rcvbuf[p] = rcv;
}

// ---------------------------------------------------------------- A accumulation
// wave per node; lane = (k2=lane>>1, ihalf=lane&1) holds A[n][k2][ihalf*8+j].
__global__ void __launch_bounds__(256) node_accA_kernel(
    const int* __restrict__ row_start, const float* __restrict__ xsbuf,
    const float* __restrict__ vbuf, float* __restrict__ A){
  int tid = threadIdx.x;
  int wl = tid>>6, lane = tid&63;
  int n = blockIdx.x*4 + wl;
  int k2 = lane>>1, ihalf = lane&1;
  float acc[8];
  #pragma unroll
  for (int j=0;j<8;j++) acc[j]=0.f;
  int rs=row_start[n], re=row_start[n+1];
  for (int p=rs; p<re; ++p){
    float vx=vbuf[p], vy=vbuf[NEDGES+p], vz=vbuf[2*NEDGES+p];
    float r2 = vx*vx+vy*vy+vz*vz + 1e-18f;
    float invr = 1.0f/sqrtf(r2);
    float sh[16];
    compute_sh(vx*invr, vy*invr, vz*invr, sh);
    float shh[8];
    #pragma unroll
    for (int j=0;j<8;j++) shh[j] = ihalf ? sh[8+j] : sh[j];
    float xsv = xsbuf[(size_t)k2*NEDGES + p];
    #pragma unroll
    for (int j=0;j<8;j++) acc[j] += xsv*shh[j];
  }
  float4* Ao = (float4*)(A + (size_t)n*512 + lane*8);
  Ao[0] = make_float4(acc[0],acc[1],acc[2],acc[3]);
  Ao[1] = make_float4(acc[4],acc[5],acc[6],acc[7]);
}

// ---------------------------------------------------------------- node B-ops
// thread = (node,k). Reads its A row, writes gA IN PLACE (thread owns the 64B).
__global__ void node_b_kernel(float* Abuf, const float* __restrict__ xbuf,
                              const int* __restrict__ batch, const float* __restrict__ G3g,
                              const float* __restrict__ U2sg, const float* __restrict__ c123,
                              const float* __restrict__ Wread,
                              float* __restrict__ out_e){
  __shared__ float G3s[4096];
  __shared__ float U2ss[256];
  for (int v=threadIdx.x; v<4096; v+=256) G3s[v]=G3g[v];
  U2ss[threadIdx.x]=U2sg[threadIdx.x];
  __syncthreads();
  int n = blockIdx.x*8 + (threadIdx.x>>5);
  int k = threadIdx.x & 31;
  float a[16];
  {
    const float4* Arow = (const float4*)(Abuf + ((size_t)n*KDIM + k)*NSHD);
    const float inv_avg = 1.0f/16.0f;
    #pragma unroll
    for (int q=0;q<4;q++){
      float4 t = Arow[q];
      a[q*4+0]=t.x*inv_avg; a[q*4+1]=t.y*inv_avg;
      a[q*4+2]=t.z*inv_avg; a[q*4+3]=t.w*inv_avg;
    }
  }
  float g2[16], g3[16];
  #pragma unroll
  for (int i=0;i<16;i++){
    float s=0.f;
    #pragma unroll
    for (int j=0;j<16;j++) s += U2ss[i*16+j]*a[j];
    g2[i]=s;
  }
  #pragma unroll
  for (int i=0;i<16;i++){
    float s=0.f;
    #pragma unroll
    for (int j=0;j<16;j++){
      const float4* row = (const float4*)(G3s + (i*16+j)*16);
      float aj = a[j];
      #pragma unroll
      for (int lq=0;lq<4;lq++){
        float4 t = row[lq];
        s += aj*(t.x*a[lq*4+0]+t.y*a[lq*4+1]+t.z*a[lq*4+2]+t.w*a[lq*4+3]);
      }
    }
    g3[i]=s;
  }
  float B2=0.f, B3=0.f;
  #pragma unroll
  for (int i=0;i<16;i++){ B2 += a[i]*g2[i]; B3 += a[i]*g3[i]; }
  B2 *= 0.5f; B3 *= (1.0f/3.0f);
  float c1k=c123[k], c2k=c123[KDIM+k], c3k=c123[2*KDIM+k];
  float contrib = a[0]*c1k + B2*c2k + B3*c3k + xbuf[n*KDIM+k]*Wread[k];
  {
    float4* gRow = (float4*)(Abuf + ((size_t)n*KDIM + k)*NSHD);
    const float s16 = 1.0f/16.0f;
    #pragma unroll
    for (int q=0;q<4;q++){
      float4 t;
      t.x = (c2k*g2[q*4+0]+c3k*g3[q*4+0])*s16;
      t.y = (c2k*g2[q*4+1]+c3k*g3[q*4+1])*s16;
      t.z = (c2k*g2[q*4+2]+c3k*g3[q*4+2])*s16;
      t.w = (c2k*g2[q*4+3]+c3k*g3[q*4+3])*s16;
      if (q==0) t.x += c1k*s16;
      gRow[q]=t;
    }
  }
  #pragma unroll
  for (int off=1; off<32; off<<=1) contrib += __shfl_xor(contrib, off, 64);
  if (k==0) atomicAdd(&out_e[batch[n]], contrib);
}

// ---------------------------------------------------------------- edge backward (thread-per-edge)
// No shuffles/LDS. xs reloaded from edge_fwd; gA row streamed via L1 (CSR runs share rows).
__global__ void __launch_bounds__(256) edge_bwd_kernel(
    const int* __restrict__ sndbuf, const int* __restrict__ rcvbuf,
    const float* __restrict__ vbuf, const float* __restrict__ xsbuf,
    const float* __restrict__ ybuf,
    const float* __restrict__ W_r1, const float* __restrict__ b_r1,
    const float* __restrict__ W_r2, const float* __restrict__ gA,
    float* __restrict__ F){
  int p = blockIdx.x*256 + threadIdx.x;
  int snd = sndbuf[p], rcv = rcvbuf[p];
  float vx=vbuf[p], vy=vbuf[NEDGES+p], vz=vbuf[2*NEDGES+p];
  float r2 = vx*vx+vy*vy+vz*vz + 1e-18f;
  float r = sqrtf(r2);
  float invr = 1.0f/r;
  float ux=vx*invr, uy=vy*invr, uz=vz*invr;
  float u = r*INVR_MAX;
  float u2=u*u, u3=u2*u, u6=u3*u3;
  float cutp = 1.0f - 28.0f*u6 + 48.0f*u6*u - 21.0f*u6*u2;
  float cut = (u<1.0f) ? cutp : 0.f;
  float u4=u2*u2, om=1.0f-u;
  float dcdrp = -168.0f*u4*u*om*om*INVR_MAX;
  float dcdr = (u<1.0f) ? dcdrp : 0.f;
  float th = PI_F*u;
  float s1=__sinf(th), c1=__cosf(th);
  float cb = CBES*invr*cut;
  float b[NB], db[NB];
  {
    float Sp=0.f, Sc=s1, Cp=1.0f, Cc=c1;
    b[0]=Sc*cb;
    db[0]=CBES*invr*((PI_F*INVR_MAX)*Cc - Sc*invr)*cut + CBES*Sc*invr*dcdr;
    #pragma unroll
    for (int q=1;q<NB;q++){
      float Sn=2.f*c1*Sc-Sp; Sp=Sc; Sc=Sn;
      float Cn=2.f*c1*Cc-Cp; Cp=Cc; Cc=Cn;
      b[q]=Sc*cb;
      db[q]=CBES*invr*((PI_F*(float)(q+1)*INVR_MAX)*Cc - Sc*invr)*cut + CBES*Sc*invr*dcdr;
    }
  }
  float sh[16];
  compute_sh(ux,uy,uz,sh);
  // load y[snd][:]
  float yreg[KDIM];
  {
    const float4* y4 = (const float4*)(ybuf + (size_t)snd*KDIM);
    #pragma unroll
    for (int t=0;t<8;t++){
      float4 yv = y4[t];
      yreg[4*t+0]=yv.x; yreg[4*t+1]=yv.y; yreg[4*t+2]=yv.z; yreg[4*t+3]=yv.w;
    }
  }
  // phase 2: gsh[i] = sum_k ga[k][i]*xs[k];  grw[k] = (sum_i ga[k][i]*sh[i]) * y[k]
  float gsh[16];
  #pragma unroll
  for (int i=0;i<16;i++) gsh[i]=0.f;
  float grw[KDIM];
  const float4* ga4 = (const float4*)(gA + (size_t)rcv*512);
  #pragma unroll
  for (int k=0;k<KDIM;k++){
    float xsk = xsbuf[(size_t)k*NEDGES + p];
    float4 g0 = ga4[k*4+0];
    float4 g1 = ga4[k*4+1];
    float4 g2_ = ga4[k*4+2];
    float4 g3_ = ga4[k*4+3];
    float gxs = g0.x*sh[0]+g0.y*sh[1]+g0.z*sh[2]+g0.w*sh[3]
              + g1.x*sh[4]+g1.y*sh[5]+g1.z*sh[6]+g1.w*sh[7]
              + g2_.x*sh[8]+g2_.y*sh[9]+g2_.z*sh[10]+g2_.w*sh[11]
              + g3_.x*sh[12]+g3_.y*sh[13]+g3_.z*sh[14]+g3_.w*sh[15];
    gsh[0]+=g0.x*xsk;  gsh[1]+=g0.y*xsk;  gsh[2]+=g0.z*xsk;  gsh[3]+=g0.w*xsk;
    gsh[4]+=g1.x*xsk;  gsh[5]+=g1.y*xsk;  gsh[6]+=g1.z*xsk;  gsh[7]+=g1.w*xsk;
    gsh[8]+=g2_.x*xsk; gsh[9]+=g2_.y*xsk; gsh[10]+=g2_.z*xsk; gsh[11]+=g2_.w*xsk;
    gsh[12]+=g3_.x*xsk;gsh[13]+=g3_.y*xsk;gsh[14]+=g3_.z*xsk; gsh[15]+=g3_.w*xsk;
    grw[k] = gxs*yreg[k];
  }
  // phase 3: grad_r = sum_m silu'(h_m) * (grw . W2[m,:]) * (db . W1[:,m])
  float grad_r = 0.f;
  #pragma unroll 4
  for (int m=0;m<NHID;m++){
    float h = b_r1[m];
    #pragma unroll
    for (int q=0;q<NB;q++) h += b[q]*W_r1[q*NHID+m];
    float sg = 1.0f/(1.0f+__expf(-h));
    float sp_ = sg*(1.0f + h*(1.0f-sg));
    float gs = 0.f;
    #pragma unroll
    for (int k=0;k<KDIM;k++) gs += grw[k]*W_r2[m*KDIM+k];
    float dbw = 0.f;
    #pragma unroll
    for (int q=0;q<NB;q++) dbw += db[q]*W_r1[q*NHID+m];
    grad_r += gs*sp_*dbw;
  }
  // angular gradient
  float x_=ux, y_=uy, z_=uz;
  float x2=x_*x_, y2=y_*y_, z2=z_*z_;
  const float* g = gsh;
  float gux = 0.48860251f*g[3]
            + 1.09254843f*(y_*g[4] + z_*g[7])
            + 1.09254844f*x_*g[8]
            + 3.54026154f*x_*y_*g[9]
            + 2.89061144f*y_*z_*g[10]
            + 0.45704579f*(5.0f*z2-1.0f)*g[13]
            + 2.89061144f*x_*z_*g[14]
            + 1.77013077f*(x2-y2)*g[15];
  float guy = 0.48860251f*g[1]
            + 1.09254843f*(x_*g[4] + z_*g[5])
            - 1.09254844f*y_*g[8]
            + 1.77013077f*(x2-y2)*g[9]
            + 2.89061144f*x_*z_*g[10]
            + 0.45704579f*(5.0f*z2-1.0f)*g[11]
            - 2.89061144f*y_*z_*g[14]
            - 3.54026154f*x_*y_*g[15];
  float guz = 0.48860251f*g[2]
            + 1.09254843f*(y_*g[5] + x_*g[7])
            + 1.89234942f*z_*g[6]
            + 2.89061144f*x_*y_*g[10]
            + 4.5704579f*y_*z_*g[11]
            + 0.37317633f*(15.0f*z2-3.0f)*g[12]
            + 4.5704579f*x_*z_*g[13]
            + 1.44530572f*(x2-y2)*g[14];
  float dotg = gux*x_ + guy*y_ + guz*z_;
  float gvx = grad_r*x_ + (gux - dotg*x_)*invr;
  float gvy = grad_r*y_ + (guy - dotg*y_)*invr;
  float gvz = grad_r*z_ + (guz - dotg*z_)*invr;
  // vec = pos[rcv]-pos[snd]; F = -dE/dp => F[snd] += gvec, F[rcv] -= gvec
  atomicAdd(&F[snd*3+0],  gvx);
  atomicAdd(&F[snd*3+1],  gvy);
  atomicAdd(&F[snd*3+2],  gvz);
  atomicAdd(&F[rcv*3+0], -gvx);
  atomicAdd(&F[rcv*3+1], -gvy);
  atomicAdd(&F[rcv*3+2], -gvz);
}

extern "C" void kernel_launch(void* const* d_in, const int* in_sizes, int n_in,
                              void* d_out, int out_size, void* d_ws, size_t ws_size,
                              hipStream_t stream){
  const float* positions       = (const float*)d_in[0];
  const float* node_attrs      = (const float*)d_in[1];
  const int*   edge_index      = (const int*)  d_in[2];
  const float* shifts          = (const float*)d_in[3];
  const int*   batch           = (const int*)  d_in[4];
  const float* atomic_energies = (const float*)d_in[6];
  const float* W_embed         = (const float*)d_in[7];
  const float* W_up            = (const float*)d_in[8];
  const float* W_r1            = (const float*)d_in[9];
  const float* b_r1            = (const float*)d_in[10];
  const float* W_r2            = (const float*)d_in[11];
  const float* U2              = (const float*)d_in[12];
  const float* U3              = (const float*)d_in[13];
  const float* Wp1             = (const float*)d_in[14];
  const float* Wp2             = (const float*)d_in[15];
  const float* Wp3             = (const float*)d_in[16];
  const float* W_read          = (const float*)d_in[17];
  float* out = (float*)d_out;

  float* Abuf  = (float*)d_ws;                        // N*512 = 64 MB (A, then gA in place)
  float* xbuf  = Abuf  + (size_t)NNODES*KDIM*NSHD;    // 4 MB
  float* ybuf  = xbuf  + (size_t)NNODES*KDIM;         // 4 MB
  float* xsbuf = ybuf  + (size_t)NNODES*KDIM;         // E*32 = 64 MB
  float* vbuf  = xsbuf + (size_t)NEDGES*KDIM;         // 6 MB
  int* sndbuf  = (int*)(vbuf + (size_t)3*NEDGES);     // 2 MB
  int* rcvbuf  = sndbuf + NEDGES;                     // 2 MB
  float* G3    = (float*)(rcvbuf + NEDGES);           // 16 KB
  float* U2s   = G3 + 4096;
  float* c123  = U2s + 256;
  int* cnt       = (int*)(c123 + 128);
  int* row_start = cnt + NNODES;
  int* woff      = row_start + NNODES + 1;
  int* elist     = woff + NNODES;                     // 2 MB

  hipMemsetAsync(d_out, 0, sizeof(float)*(NGRAPH + (size_t)NNODES*3), stream);
  hipMemsetAsync(cnt, 0, sizeof(int)*NNODES, stream);

  prep_kernel<<<1,256,0,stream>>>(U2,U3,Wp1,Wp2,Wp3,W_read,G3,U2s,c123);
  csr_count_kernel<<<NEDGES/256,256,0,stream>>>(edge_index, cnt);
  csr_scan_kernel<<<1,1024,0,stream>>>(cnt, row_start, woff);
  csr_scatter_kernel<<<NEDGES/256,256,0,stream>>>(edge_index, woff, elist);
  node_embed_kernel<<<NNODES/4,256,0,stream>>>(node_attrs,W_embed,W_up,atomic_energies,
                                               batch,xbuf,ybuf,out);
  edge_fwd_kernel<<<NEDGES/256,256,0,stream>>>(elist,edge_index,shifts,positions,ybuf,
                                               W_r1,b_r1,W_r2,xsbuf,vbuf,sndbuf,rcvbuf);
  node_accA_kernel<<<NNODES/4,256,0,stream>>>(row_start,xsbuf,vbuf,Abuf);
  node_b_kernel<<<NNODES/8,256,0,stream>>>(Abuf,xbuf,batch,G3,U2s,c123,W_read,out);
  edge_bwd_kernel<<<NEDGES/256,256,0,stream>>>(sndbuf,rcvbuf,vbuf,xsbuf,ybuf,
                                               W_r1,b_r1,W_r2,Abuf,out+NGRAPH);
}

// Round 4
// 2005.375 us; speedup vs baseline: 1.8101x; 1.3485x over previous
//
#include <hip/hip_runtime.h>
#include <math.h>

#define NNODES 32768
#define NEDGES 524288
#define KDIM 32
#define NSHD 16
#define NB 8
#define NHID 64
#define NGRAPH 16
#define NELEM 10
#define RMAXF 5.0f
#define INVR_MAX 0.2f
#define PI_F 3.14159265358979f
#define CBES 0.632455532033676f   /* sqrt(2/R_MAX) */

__device__ __forceinline__ void compute_sh(float x, float y, float z, float* sh){
  float x2=x*x, y2=y*y, z2=z*z;
  sh[0]=0.28209479f;
  sh[1]=0.48860251f*y;
  sh[2]=0.48860251f*z;
  sh[3]=0.48860251f*x;
  sh[4]=1.09254843f*x*y;
  sh[5]=1.09254843f*y*z;
  sh[6]=0.31539157f*(3.0f*z2-1.0f);
  sh[7]=1.09254843f*x*z;
  sh[8]=0.54627422f*(x2-y2);
  sh[9]=0.59004359f*y*(3.0f*x2-y2);
  sh[10]=2.89061144f*x*y*z;
  sh[11]=0.45704579f*y*(5.0f*z2-1.0f);
  sh[12]=0.37317633f*z*(5.0f*z2-3.0f);
  sh[13]=0.45704579f*x*(5.0f*z2-1.0f);
  sh[14]=1.44530572f*z*(x2-y2);
  sh[15]=0.59004359f*x*(x2-3.0f*y2);
}

// ---------------------------------------------------------------- prep
__global__ void prep_kernel(const float* __restrict__ U2, const float* __restrict__ U3,
                            const float* __restrict__ Wp1, const float* __restrict__ Wp2,
                            const float* __restrict__ Wp3, const float* __restrict__ Wread,
                            float* __restrict__ G3, float* __restrict__ U2s,
                            float* __restrict__ c123){
  int t = threadIdx.x;
  for (int v = t; v < 4096; v += 256){
    int i = v >> 8, j = (v >> 4) & 15, l = v & 15;
    G3[v] = U3[i*256 + j*16 + l] + U3[j*256 + i*16 + l] + U3[j*256 + l*16 + i];
  }
  {
    int i = t >> 4, j = t & 15;
    U2s[t] = U2[i*16+j] + U2[j*16+i];
  }
  if (t < 96){
    int which = t >> 5, k = t & 31;
    const float* Wp = (which==0)?Wp1:((which==1)?Wp2:Wp3);
    float s = 0.f;
    for (int q=0;q<KDIM;q++) s += Wp[k*KDIM+q]*Wread[q];
    c123[t] = s;
  }
}

// ---------------------------------------------------------------- CSR build
__global__ void csr_count_kernel(const int* __restrict__ eidx, int* __restrict__ cnt){
  int e = blockIdx.x*256 + threadIdx.x;
  if (e < NEDGES) atomicAdd(&cnt[eidx[NEDGES + e]], 1);
}

__global__ void csr_scan_kernel(const int* __restrict__ cnt, int* __restrict__ row_start,
                                int* __restrict__ woff){
  __shared__ int part[1024];
  int t = threadIdx.x;
  int base_idx = t*32;
  int local[32];
  int s = 0;
  #pragma unroll
  for (int j=0;j<32;j++){
    int c = cnt[base_idx+j];
    local[j] = s;
    s += c;
  }
  part[t] = s;
  __syncthreads();
  for (int off=1; off<1024; off<<=1){
    int v = (t>=off) ? part[t-off] : 0;
    __syncthreads();
    part[t] += v;
    __syncthreads();
  }
  int base = (t==0) ? 0 : part[t-1];
  #pragma unroll
  for (int j=0;j<32;j++){
    int v = base + local[j];
    row_start[base_idx+j] = v;
    woff[base_idx+j] = v;
  }
  if (t==1023) row_start[NNODES] = part[1023];
}

__global__ void csr_scatter_kernel(const int* __restrict__ eidx, int* __restrict__ woff,
                                   int* __restrict__ elist){
  int e = blockIdx.x*256 + threadIdx.x;
  if (e < NEDGES){
    int rcv = eidx[NEDGES + e];
    int p = atomicAdd(&woff[rcv], 1);
    elist[p] = e;
  }
}

// ---------------------------------------------------------------- node embed
__global__ void node_embed_kernel(const float* __restrict__ attrs,
                                  const float* __restrict__ W_embed,
                                  const float* __restrict__ W_up,
                                  const float* __restrict__ ae,
                                  const int* __restrict__ batch,
                                  float* __restrict__ xbuf, float* __restrict__ ybuf,
                                  float* __restrict__ out_e){
  int gtid = blockIdx.x*256 + threadIdx.x;
  int n = gtid >> 6;
  int lane = threadIdx.x & 63;
  int k = lane & 31;
  float xv = 0.f;
  #pragma unroll
  for (int e=0;e<NELEM;e++) xv += attrs[n*NELEM+e]*W_embed[e*KDIM+k];
  float yv = 0.f;
  #pragma unroll 8
  for (int k2=0;k2<KDIM;k2++) yv += __shfl(xv, k2, 64) * W_up[k2*KDIM+k];
  if (lane < 32){
    xbuf[n*KDIM+k]=xv;
    ybuf[n*KDIM+k]=yv;
  }
  if (lane == 0){
    float s=0.f;
    #pragma unroll
    for (int e=0;e<NELEM;e++) s += attrs[n*NELEM+e]*ae[e];
    atomicAdd(&out_e[batch[n]], s);
  }
}

// ---------------------------------------------------------------- edge forward (thread-per-edge)
__global__ void __launch_bounds__(256) edge_fwd_kernel(
    const int* __restrict__ elist, const int* __restrict__ eidx,
    const float* __restrict__ shifts, const float* __restrict__ pos,
    const float* __restrict__ ybuf,
    const float* __restrict__ W_r1, const float* __restrict__ b_r1,
    const float* __restrict__ W_r2,
    float* __restrict__ xsbuf, float* __restrict__ vbuf,
    int* __restrict__ sndbuf, int* __restrict__ rcvbuf){
  int p = blockIdx.x*256 + threadIdx.x;
  int e = elist[p];
  int snd = eidx[e], rcv = eidx[NEDGES + e];
  float vx = pos[rcv*3+0] - pos[snd*3+0] + shifts[e*3+0];
  float vy = pos[rcv*3+1] - pos[snd*3+1] + shifts[e*3+1];
  float vz = pos[rcv*3+2] - pos[snd*3+2] + shifts[e*3+2];
  float r2 = vx*vx+vy*vy+vz*vz + 1e-18f;
  float r = sqrtf(r2);
  float invr = 1.0f/r;
  float u = r*INVR_MAX;
  float u2=u*u, u3=u2*u, u6=u3*u3;
  float cutp = 1.0f - 28.0f*u6 + 48.0f*u6*u - 21.0f*u6*u2;
  float cut = (u < 1.0f) ? cutp : 0.f;
  float th = PI_F*u;
  float s1=__sinf(th), c1=__cosf(th);
  float cb = CBES*invr*cut;
  float b[NB];
  {
    float Sp=0.f, Sc=s1;
    b[0]=Sc*cb;
    #pragma unroll
    for (int q=1;q<NB;q++){ float Sn=2.f*c1*Sc-Sp; Sp=Sc; Sc=Sn; b[q]=Sc*cb; }
  }
  float Rw[KDIM];
  #pragma unroll
  for (int k=0;k<KDIM;k++) Rw[k]=0.f;
  #pragma unroll 4
  for (int m=0;m<NHID;m++){
    float h = b_r1[m];
    #pragma unroll
    for (int q=0;q<NB;q++) h += b[q]*W_r1[q*NHID+m];
    float s = h/(1.0f+__expf(-h));
    #pragma unroll
    for (int k=0;k<KDIM;k++) Rw[k] += s*W_r2[m*KDIM+k];
  }
  const float4* y4 = (const float4*)(ybuf + (size_t)snd*KDIM);
  #pragma unroll
  for (int t=0;t<8;t++){
    float4 yv = y4[t];
    xsbuf[(size_t)(4*t+0)*NEDGES + p] = yv.x*Rw[4*t+0];
    xsbuf[(size_t)(4*t+1)*NEDGES + p] = yv.y*Rw[4*t+1];
    xsbuf[(size_t)(4*t+2)*NEDGES + p] = yv.z*Rw[4*t+2];
    xsbuf[(size_t)(4*t+3)*NEDGES + p] = yv.w*Rw[4*t+3];
  }
  vbuf[p] = vx;
  vbuf[NEDGES + p] = vy;
  vbuf[2*NEDGES + p] = vz;
  sndbuf[p] = snd;
  rcvbuf[p] = rcv;
}

// ---------------------------------------------------------------- A accumulation
__global__ void __launch_bounds__(256) node_accA_kernel(
    const int* __restrict__ row_start, const float* __restrict__ xsbuf,
    const float* __restrict__ vbuf, float* __restrict__ A){
  int tid = threadIdx.x;
  int wl = tid>>6, lane = tid&63;
  int n = blockIdx.x*4 + wl;
  int k2 = lane>>1, ihalf = lane&1;
  float acc[8];
  #pragma unroll
  for (int j=0;j<8;j++) acc[j]=0.f;
  int rs=row_start[n], re=row_start[n+1];
  for (int p=rs; p<re; ++p){
    float vx=vbuf[p], vy=vbuf[NEDGES+p], vz=vbuf[2*NEDGES+p];
    float r2 = vx*vx+vy*vy+vz*vz + 1e-18f;
    float invr = 1.0f/sqrtf(r2);
    float sh[16];
    compute_sh(vx*invr, vy*invr, vz*invr, sh);
    float shh[8];
    #pragma unroll
    for (int j=0;j<8;j++) shh[j] = ihalf ? sh[8+j] : sh[j];
    float xsv = xsbuf[(size_t)k2*NEDGES + p];
    #pragma unroll
    for (int j=0;j<8;j++) acc[j] += xsv*shh[j];
  }
  float4* Ao = (float4*)(A + (size_t)n*512 + lane*8);
  Ao[0] = make_float4(acc[0],acc[1],acc[2],acc[3]);
  Ao[1] = make_float4(acc[4],acc[5],acc[6],acc[7]);
}

// ---------------------------------------------------------------- node B-ops
// thread = (node,k). Fused per-i loop: compute g2[i],g3[i], consume immediately.
// Peak live state ~24 regs (no spill). G3/U2s read via wave-uniform global
// addresses -> compiler emits s_load (SMEM pipe, overlaps VALU). gA written
// in place over A (thread owns its 64B row; a[] fully loaded before writes).
__global__ void __launch_bounds__(256) node_b_kernel(
    float* Abuf, const float* __restrict__ xbuf,
    const int* __restrict__ batch, const float* __restrict__ G3g,
    const float* __restrict__ U2sg, const float* __restrict__ c123,
    const float* __restrict__ Wread, float* __restrict__ out_e){
  int n = blockIdx.x*8 + (threadIdx.x>>5);
  int k = threadIdx.x & 31;
  const float inv_avg = 1.0f/16.0f;
  float a[16];
  float4* Arow = (float4*)(Abuf + ((size_t)n*KDIM + k)*NSHD);
  #pragma unroll
  for (int q=0;q<4;q++){
    float4 t = Arow[q];
    a[q*4+0]=t.x*inv_avg; a[q*4+1]=t.y*inv_avg;
    a[q*4+2]=t.z*inv_avg; a[q*4+3]=t.w*inv_avg;
  }
  float c1k=c123[k], c2k=c123[KDIM+k], c3k=c123[2*KDIM+k];
  float B2=0.f, B3=0.f;
  float o0=0.f,o1=0.f,o2=0.f;
  #pragma unroll
  for (int i=0;i<16;i++){
    float g2i=0.f;
    #pragma unroll
    for (int j=0;j<16;j++) g2i += U2sg[i*16+j]*a[j];
    float g3i=0.f;
    #pragma unroll
    for (int j=0;j<16;j++){
      const float* row = G3g + (i*16+j)*16;
      float d=0.f;
      #pragma unroll
      for (int l=0;l<16;l++) d += row[l]*a[l];
      g3i += a[j]*d;
    }
    B2 += a[i]*g2i;
    B3 += a[i]*g3i;
    float o = (c2k*g2i + c3k*g3i)*inv_avg;
    if (i==0) o += c1k*inv_avg;
    int ph = i&3;
    if (ph==0) o0=o;
    else if (ph==1) o1=o;
    else if (ph==2) o2=o;
    else Arow[i>>2] = make_float4(o0,o1,o2,o);
  }
  B2 *= 0.5f; B3 *= (1.0f/3.0f);
  float contrib = a[0]*c1k + B2*c2k + B3*c3k + xbuf[n*KDIM+k]*Wread[k];
  #pragma unroll
  for (int off=1; off<32; off<<=1) contrib += __shfl_xor(contrib, off, 64);
  if (k==0) atomicAdd(&out_e[batch[n]], contrib);
}

// ---------------------------------------------------------------- edge backward (thread-per-edge)
__global__ void __launch_bounds__(256) edge_bwd_kernel(
    const int* __restrict__ sndbuf, const int* __restrict__ rcvbuf,
    const float* __restrict__ vbuf, const float* __restrict__ xsbuf,
    const float* __restrict__ ybuf,
    const float* __restrict__ W_r1, const float* __restrict__ b_r1,
    const float* __restrict__ W_r2, const float* __restrict__ gA,
    float* __restrict__ F){
  int p = blockIdx.x*256 + threadIdx.x;
  int snd = sndbuf[p], rcv = rcvbuf[p];
  float vx=vbuf[p], vy=vbuf[NEDGES+p], vz=vbuf[2*NEDGES+p];
  float r2 = vx*vx+vy*vy+vz*vz + 1e-18f;
  float r = sqrtf(r2);
  float invr = 1.0f/r;
  float ux=vx*invr, uy=vy*invr, uz=vz*invr;
  float u = r*INVR_MAX;
  float u2=u*u, u3=u2*u, u6=u3*u3;
  float cutp = 1.0f - 28.0f*u6 + 48.0f*u6*u - 21.0f*u6*u2;
  float cut = (u<1.0f) ? cutp : 0.f;
  float u4=u2*u2, om=1.0f-u;
  float dcdrp = -168.0f*u4*u*om*om*INVR_MAX;
  float dcdr = (u<1.0f) ? dcdrp : 0.f;
  float th = PI_F*u;
  float s1=__sinf(th), c1=__cosf(th);
  float cb = CBES*invr*cut;
  float b[NB], db[NB];
  {
    float Sp=0.f, Sc=s1, Cp=1.0f, Cc=c1;
    b[0]=Sc*cb;
    db[0]=CBES*invr*((PI_F*INVR_MAX)*Cc - Sc*invr)*cut + CBES*Sc*invr*dcdr;
    #pragma unroll
    for (int q=1;q<NB;q++){
      float Sn=2.f*c1*Sc-Sp; Sp=Sc; Sc=Sn;
      float Cn=2.f*c1*Cc-Cp; Cp=Cc; Cc=Cn;
      b[q]=Sc*cb;
      db[q]=CBES*invr*((PI_F*(float)(q+1)*INVR_MAX)*Cc - Sc*invr)*cut + CBES*Sc*invr*dcdr;
    }
  }
  float sh[16];
  compute_sh(ux,uy,uz,sh);
  float yreg[KDIM];
  {
    const float4* y4 = (const float4*)(ybuf + (size_t)snd*KDIM);
    #pragma unroll
    for (int t=0;t<8;t++){
      float4 yv = y4[t];
      yreg[4*t+0]=yv.x; yreg[4*t+1]=yv.y; yreg[4*t+2]=yv.z; yreg[4*t+3]=yv.w;
    }
  }
  float gsh[16];
  #pragma unroll
  for (int i=0;i<16;i++) gsh[i]=0.f;
  float grw[KDIM];
  const float4* ga4 = (const float4*)(gA + (size_t)rcv*512);
  #pragma unroll
  for (int k=0;k<KDIM;k++){
    float xsk = xsbuf[(size_t)k*NEDGES + p];
    float4 g0 = ga4[k*4+0];
    float4 g1 = ga4[k*4+1];
    float4 g2_ = ga4[k*4+2];
    float4 g3_ = ga4[k*4+3];
    float gxs = g0.x*sh[0]+g0.y*sh[1]+g0.z*sh[2]+g0.w*sh[3]
              + g1.x*sh[4]+g1.y*sh[5]+g1.z*sh[6]+g1.w*sh[7]
              + g2_.x*sh[8]+g2_.y*sh[9]+g2_.z*sh[10]+g2_.w*sh[11]
              + g3_.x*sh[12]+g3_.y*sh[13]+g3_.z*sh[14]+g3_.w*sh[15];
    gsh[0]+=g0.x*xsk;  gsh[1]+=g0.y*xsk;  gsh[2]+=g0.z*xsk;  gsh[3]+=g0.w*xsk;
    gsh[4]+=g1.x*xsk;  gsh[5]+=g1.y*xsk;  gsh[6]+=g1.z*xsk;  gsh[7]+=g1.w*xsk;
    gsh[8]+=g2_.x*xsk; gsh[9]+=g2_.y*xsk; gsh[10]+=g2_.z*xsk; gsh[11]+=g2_.w*xsk;
    gsh[12]+=g3_.x*xsk;gsh[13]+=g3_.y*xsk;gsh[14]+=g3_.z*xsk; gsh[15]+=g3_.w*xsk;
    grw[k] = gxs*yreg[k];
  }
  float grad_r = 0.f;
  #pragma unroll 4
  for (int m=0;m<NHID;m++){
    float h = b_r1[m];
    #pragma unroll
    for (int q=0;q<NB;q++) h += b[q]*W_r1[q*NHID+m];
    float sg = 1.0f/(1.0f+__expf(-h));
    float sp_ = sg*(1.0f + h*(1.0f-sg));
    float gs = 0.f;
    #pragma unroll
    for (int k=0;k<KDIM;k++) gs += grw[k]*W_r2[m*KDIM+k];
    float dbw = 0.f;
    #pragma unroll
    for (int q=0;q<NB;q++) dbw += db[q]*W_r1[q*NHID+m];
    grad_r += gs*sp_*dbw;
  }
  float x_=ux, y_=uy, z_=uz;
  float x2=x_*x_, y2=y_*y_, z2=z_*z_;
  const float* g = gsh;
  float gux = 0.48860251f*g[3]
            + 1.09254843f*(y_*g[4] + z_*g[7])
            + 1.09254844f*x_*g[8]
            + 3.54026154f*x_*y_*g[9]
            + 2.89061144f*y_*z_*g[10]
            + 0.45704579f*(5.0f*z2-1.0f)*g[13]
            + 2.89061144f*x_*z_*g[14]
            + 1.77013077f*(x2-y2)*g[15];
  float guy = 0.48860251f*g[1]
            + 1.09254843f*(x_*g[4] + z_*g[5])
            - 1.09254844f*y_*g[8]
            + 1.77013077f*(x2-y2)*g[9]
            + 2.89061144f*x_*z_*g[10]
            + 0.45704579f*(5.0f*z2-1.0f)*g[11]
            - 2.89061144f*y_*z_*g[14]
            - 3.54026154f*x_*y_*g[15];
  float guz = 0.48860251f*g[2]
            + 1.09254843f*(y_*g[5] + x_*g[7])
            + 1.89234942f*z_*g[6]
            + 2.89061144f*x_*y_*g[10]
            + 4.5704579f*y_*z_*g[11]
            + 0.37317633f*(15.0f*z2-3.0f)*g[12]
            + 4.5704579f*x_*z_*g[13]
            + 1.44530572f*(x2-y2)*g[14];
  float dotg = gux*x_ + guy*y_ + guz*z_;
  float gvx = grad_r*x_ + (gux - dotg*x_)*invr;
  float gvy = grad_r*y_ + (guy - dotg*y_)*invr;
  float gvz = grad_r*z_ + (guz - dotg*z_)*invr;
  atomicAdd(&F[snd*3+0],  gvx);
  atomicAdd(&F[snd*3+1],  gvy);
  atomicAdd(&F[snd*3+2],  gvz);
  atomicAdd(&F[rcv*3+0], -gvx);
  atomicAdd(&F[rcv*3+1], -gvy);
  atomicAdd(&F[rcv*3+2], -gvz);
}

extern "C" void kernel_launch(void* const* d_in, const int* in_sizes, int n_in,
                              void* d_out, int out_size, void* d_ws, size_t ws_size,
                              hipStream_t stream){
  const float* positions       = (const float*)d_in[0];
  const float* node_attrs      = (const float*)d_in[1];
  const int*   edge_index      = (const int*)  d_in[2];
  const float* shifts          = (const float*)d_in[3];
  const int*   batch           = (const int*)  d_in[4];
  const float* atomic_energies = (const float*)d_in[6];
  const float* W_embed         = (const float*)d_in[7];
  const float* W_up            = (const float*)d_in[8];
  const float* W_r1            = (const float*)d_in[9];
  const float* b_r1            = (const float*)d_in[10];
  const float* W_r2            = (const float*)d_in[11];
  const float* U2              = (const float*)d_in[12];
  const float* U3              = (const float*)d_in[13];
  const float* Wp1             = (const float*)d_in[14];
  const float* Wp2             = (const float*)d_in[15];
  const float* Wp3             = (const float*)d_in[16];
  const float* W_read          = (const float*)d_in[17];
  float* out = (float*)d_out;

  float* Abuf  = (float*)d_ws;                        // N*512 = 64 MB (A, then gA in place)
  float* xbuf  = Abuf  + (size_t)NNODES*KDIM*NSHD;    // 4 MB
  float* ybuf  = xbuf  + (size_t)NNODES*KDIM;         // 4 MB
  float* xsbuf = ybuf  + (size_t)NNODES*KDIM;         // E*32 = 64 MB
  float* vbuf  = xsbuf + (size_t)NEDGES*KDIM;         // 6 MB
  int* sndbuf  = (int*)(vbuf + (size_t)3*NEDGES);     // 2 MB
  int* rcvbuf  = sndbuf + NEDGES;                     // 2 MB
  float* G3    = (float*)(rcvbuf + NEDGES);           // 16 KB
  float* U2s   = G3 + 4096;
  float* c123  = U2s + 256;
  int* cnt       = (int*)(c123 + 128);
  int* row_start = cnt + NNODES;
  int* woff      = row_start + NNODES + 1;
  int* elist     = woff + NNODES;                     // 2 MB

  hipMemsetAsync(d_out, 0, sizeof(float)*(NGRAPH + (size_t)NNODES*3), stream);
  hipMemsetAsync(cnt, 0, sizeof(int)*NNODES, stream);

  prep_kernel<<<1,256,0,stream>>>(U2,U3,Wp1,Wp2,Wp3,W_read,G3,U2s,c123);
  csr_count_kernel<<<NEDGES/256,256,0,stream>>>(edge_index, cnt);
  csr_scan_kernel<<<1,1024,0,stream>>>(cnt, row_start, woff);
  csr_scatter_kernel<<<NEDGES/256,256,0,stream>>>(edge_index, woff, elist);
  node_embed_kernel<<<NNODES/4,256,0,stream>>>(node_attrs,W_embed,W_up,atomic_energies,
                                               batch,xbuf,ybuf,out);
  edge_fwd_kernel<<<NEDGES/256,256,0,stream>>>(elist,edge_index,shifts,positions,ybuf,
                                               W_r1,b_r1,W_r2,xsbuf,vbuf,sndbuf,rcvbuf);
  node_accA_kernel<<<NNODES/4,256,0,stream>>>(row_start,xsbuf,vbuf,Abuf);
  node_b_kernel<<<NNODES/8,256,0,stream>>>(Abuf,xbuf,batch,G3,U2s,c123,W_read,out);
  edge_bwd_kernel<<<NEDGES/256,256,0,stream>>>(sndbuf,rcvbuf,vbuf,xsbuf,ybuf,
                                               W_r1,b_r1,W_r2,Abuf,out+NGRAPH);
}

// Round 5
// 1775.384 us; speedup vs baseline: 2.0446x; 1.1295x over previous
//
#include <hip/hip_runtime.h>
#include <math.h>

#define NNODES 32768
#define NEDGES 524288
#define KDIM 32
#define NSHD 16
#define NB 8
#define NHID 64
#define NGRAPH 16
#define NELEM 10
#define RMAXF 5.0f
#define INVR_MAX 0.2f
#define PI_F 3.14159265358979f
#define CBES 0.632455532033676f   /* sqrt(2/R_MAX) */
#define LUTN 2048                 /* intervals; rows 0..LUTN (row LUTN = beyond-cutoff const) */

__device__ __forceinline__ void compute_sh(float x, float y, float z, float* sh){
  float x2=x*x, y2=y*y, z2=z*z;
  sh[0]=0.28209479f;
  sh[1]=0.48860251f*y;
  sh[2]=0.48860251f*z;
  sh[3]=0.48860251f*x;
  sh[4]=1.09254843f*x*y;
  sh[5]=1.09254843f*y*z;
  sh[6]=0.31539157f*(3.0f*z2-1.0f);
  sh[7]=1.09254843f*x*z;
  sh[8]=0.54627422f*(x2-y2);
  sh[9]=0.59004359f*y*(3.0f*x2-y2);
  sh[10]=2.89061144f*x*y*z;
  sh[11]=0.45704579f*y*(5.0f*z2-1.0f);
  sh[12]=0.37317633f*z*(5.0f*z2-3.0f);
  sh[13]=0.45704579f*x*(5.0f*z2-1.0f);
  sh[14]=1.44530572f*z*(x2-y2);
  sh[15]=0.59004359f*x*(x2-3.0f*y2);
}

// ---------------------------------------------------------------- prep
// S3[pid][i] for pairs (j<=l): g3_i = sum_{j<=l} S3*a_j*a_l, where
// G3[i][j][l] = U3[ijl]+U3[jil]+U3[jli] and S3 = G3[i][j][l]+G3[i][l][j] (j<l), G3[i][j][j] (j==l).
__global__ void prep_kernel(const float* __restrict__ U2, const float* __restrict__ U3,
                            const float* __restrict__ Wp1, const float* __restrict__ Wp2,
                            const float* __restrict__ Wp3, const float* __restrict__ Wread,
                            float* __restrict__ S3, float* __restrict__ U2s,
                            float* __restrict__ c123){
  int t = threadIdx.x;
  for (int v = t; v < 136*16; v += 256){
    int pid = v >> 4, i = v & 15;
    int j = 0, rem = pid;
    while (rem >= 16 - j){ rem -= 16 - j; j++; }
    int l = j + rem;
    float s;
    if (j == l){
      s = U3[i*256 + j*16 + j] + U3[j*256 + i*16 + j] + U3[j*256 + j*16 + i];
    } else {
      s = U3[i*256 + j*16 + l] + U3[j*256 + i*16 + l] + U3[j*256 + l*16 + i]
        + U3[i*256 + l*16 + j] + U3[l*256 + i*16 + j] + U3[l*256 + j*16 + i];
    }
    S3[v] = s;
  }
  {
    int i = t >> 4, j = t & 15;
    U2s[t] = U2[i*16+j] + U2[j*16+i];   // symmetric: row j contiguous in i
  }
  if (t < 96){
    int which = t >> 5, k = t & 31;
    const float* Wp = (which==0)?Wp1:((which==1)?Wp2:Wp3);
    float s = 0.f;
    for (int q=0;q<KDIM;q++) s += Wp[k*KDIM+q]*Wread[q];
    c123[t] = s;
  }
}

// ---------------------------------------------------------------- radial LUT
// lut[g*64 + k]    = Rw_k(r_g),  lut[g*64+32+k] = dRw_k/dr(r_g),  r_g = max(5*g/LUTN, 1e-9)
__global__ void lut_kernel(const float* __restrict__ W_r1, const float* __restrict__ b_r1,
                           const float* __restrict__ W_r2, float* __restrict__ lut){
  int g = blockIdx.x*256 + threadIdx.x;
  if (g > LUTN) return;
  float r = fmaxf(5.0f*(float)g/(float)LUTN, 1e-9f);
  float invr = 1.0f/r;
  float u = r*INVR_MAX;
  float cut = 0.f, dcdr = 0.f;
  if (u < 1.0f){
    float u2=u*u, u3=u2*u, u6=u3*u3;
    cut = 1.0f - 28.0f*u6 + 48.0f*u6*u - 21.0f*u6*u2;
    float u4=u2*u2, om=1.0f-u;
    dcdr = -168.0f*u4*u*om*om*INVR_MAX;
  }
  float b[NB], db[NB];
  #pragma unroll
  for (int q=0;q<NB;q++){
    float nn = (float)(q+1);
    float ang = PI_F*nn*u;
    float S = sinf(ang), C = cosf(ang);
    b[q]  = CBES*S*invr*cut;
    db[q] = CBES*invr*((PI_F*nn*INVR_MAX)*C - S*invr)*cut + CBES*S*invr*dcdr;
  }
  float Rw[KDIM], dRw[KDIM];
  #pragma unroll
  for (int k=0;k<KDIM;k++){ Rw[k]=0.f; dRw[k]=0.f; }
  for (int m=0;m<NHID;m++){
    float h = b_r1[m], dh = 0.f;
    #pragma unroll
    for (int q=0;q<NB;q++){ h += b[q]*W_r1[q*NHID+m]; dh += db[q]*W_r1[q*NHID+m]; }
    float sg = 1.0f/(1.0f+expf(-h));
    float s  = h*sg;
    float sp = sg*(1.0f + h*(1.0f-sg));
    float f  = sp*dh;
    #pragma unroll
    for (int k=0;k<KDIM;k++){
      Rw[k]  += s*W_r2[m*KDIM+k];
      dRw[k] += f*W_r2[m*KDIM+k];
    }
  }
  #pragma unroll
  for (int k=0;k<KDIM;k++){
    lut[(size_t)g*64 + k]      = Rw[k];
    lut[(size_t)g*64 + 32 + k] = dRw[k];
  }
}

// ---------------------------------------------------------------- CSR build
__global__ void csr_count_kernel(const int* __restrict__ eidx, int* __restrict__ cnt){
  int e = blockIdx.x*256 + threadIdx.x;
  if (e < NEDGES) atomicAdd(&cnt[eidx[NEDGES + e]], 1);
}

__global__ void csr_scan_kernel(const int* __restrict__ cnt, int* __restrict__ row_start,
                                int* __restrict__ woff){
  __shared__ int part[1024];
  int t = threadIdx.x;
  int base_idx = t*32;
  int local[32];
  int s = 0;
  #pragma unroll
  for (int j=0;j<32;j++){
    int c = cnt[base_idx+j];
    local[j] = s;
    s += c;
  }
  part[t] = s;
  __syncthreads();
  for (int off=1; off<1024; off<<=1){
    int v = (t>=off) ? part[t-off] : 0;
    __syncthreads();
    part[t] += v;
    __syncthreads();
  }
  int base = (t==0) ? 0 : part[t-1];
  #pragma unroll
  for (int j=0;j<32;j++){
    int v = base + local[j];
    row_start[base_idx+j] = v;
    woff[base_idx+j] = v;
  }
  if (t==1023) row_start[NNODES] = part[1023];
}

__global__ void csr_scatter_kernel(const int* __restrict__ eidx, int* __restrict__ woff,
                                   int* __restrict__ elist){
  int e = blockIdx.x*256 + threadIdx.x;
  if (e < NEDGES){
    int rcv = eidx[NEDGES + e];
    int p = atomicAdd(&woff[rcv], 1);
    elist[p] = e;
  }
}

// ---------------------------------------------------------------- node embed
__global__ void node_embed_kernel(const float* __restrict__ attrs,
                                  const float* __restrict__ W_embed,
                                  const float* __restrict__ W_up,
                                  const float* __restrict__ ae,
                                  const int* __restrict__ batch,
                                  float* __restrict__ xbuf, float* __restrict__ ybuf,
                                  float* __restrict__ out_e){
  int gtid = blockIdx.x*256 + threadIdx.x;
  int n = gtid >> 6;
  int lane = threadIdx.x & 63;
  int k = lane & 31;
  float xv = 0.f;
  #pragma unroll
  for (int e=0;e<NELEM;e++) xv += attrs[n*NELEM+e]*W_embed[e*KDIM+k];
  float yv = 0.f;
  #pragma unroll 8
  for (int k2=0;k2<KDIM;k2++) yv += __shfl(xv, k2, 64) * W_up[k2*KDIM+k];
  if (lane < 32){
    xbuf[n*KDIM+k]=xv;
    ybuf[n*KDIM+k]=yv;
  }
  if (lane == 0){
    float s=0.f;
    #pragma unroll
    for (int e=0;e<NELEM;e++) s += attrs[n*NELEM+e]*ae[e];
    atomicAdd(&out_e[batch[n]], s);
  }
}

// ---------------------------------------------------------------- A accumulation (fused radial LUT)
// wave per node; all per-edge loads wave-uniform (broadcast) except LUT/y (32-float rows).
// Also emits vbuf4/snd/rcv for the backward pass.
__global__ void __launch_bounds__(256) node_accA_kernel(
    const int* __restrict__ row_start, const int* __restrict__ elist,
    const int* __restrict__ eidx, const float* __restrict__ shifts,
    const float* __restrict__ pos, const float* __restrict__ ybuf,
    const float* __restrict__ lut,
    float4* __restrict__ vbuf4, int* __restrict__ sndbuf, int* __restrict__ rcvbuf,
    float* __restrict__ A){
  int tid = threadIdx.x;
  int wl = tid>>6, lane = tid&63;
  int n = blockIdx.x*4 + wl;
  int k2 = lane>>1, ihalf = lane&1;
  float acc[8];
  #pragma unroll
  for (int j=0;j<8;j++) acc[j]=0.f;
  float px=pos[n*3+0], py=pos[n*3+1], pz=pos[n*3+2];
  int rs=row_start[n], re=row_start[n+1];
  for (int p=rs; p<re; ++p){
    int e = elist[p];
    int snd = eidx[e];
    float vx = px - pos[snd*3+0] + shifts[(size_t)e*3+0];
    float vy = py - pos[snd*3+1] + shifts[(size_t)e*3+1];
    float vz = pz - pos[snd*3+2] + shifts[(size_t)e*3+2];
    float r = sqrtf(vx*vx+vy*vy+vz*vz + 1e-18f);
    float invr = 1.0f/r;
    float u = r*INVR_MAX;
    float t = fminf(u,1.0f)*(float)LUTN;
    int gg = min((int)t, LUTN-1);
    float w = t - (float)gg;
    const float* rowA = lut + (size_t)gg*64;
    float rw0 = rowA[k2], rw1 = rowA[64+k2];
    float rw = rw0 + (rw1-rw0)*w;
    float y = ybuf[(size_t)snd*KDIM + k2];
    float xs = y*rw;
    float sh[16];
    compute_sh(vx*invr, vy*invr, vz*invr, sh);
    #pragma unroll
    for (int j=0;j<8;j++) acc[j] = fmaf(xs, ihalf ? sh[8+j] : sh[j], acc[j]);
    if (lane == 0){
      vbuf4[p] = make_float4(vx,vy,vz,r);
      sndbuf[p] = snd;
      rcvbuf[p] = n;
    }
  }
  float4* Ao = (float4*)(A + (size_t)n*512 + lane*8);
  Ao[0] = make_float4(acc[0],acc[1],acc[2],acc[3]);
  Ao[1] = make_float4(acc[4],acc[5],acc[6],acc[7]);
}

// ---------------------------------------------------------------- node B-ops
// thread = (node,k). Pair-symmetric g3 (136 pairs), g2 matvec; coefficients
// streamed via wave-uniform s_load. gA written in place over A.
__global__ void __launch_bounds__(256) node_b_kernel(
    float* Abuf, const float* __restrict__ xbuf,
    const int* __restrict__ batch, const float* __restrict__ S3,
    const float* __restrict__ U2s, const float* __restrict__ c123,
    const float* __restrict__ Wread, float* __restrict__ out_e){
  int n = blockIdx.x*8 + (threadIdx.x>>5);
  int k = threadIdx.x & 31;
  const float inv_avg = 1.0f/16.0f;
  float a[16];
  float4* Arow = (float4*)(Abuf + ((size_t)n*KDIM + k)*NSHD);
  #pragma unroll
  for (int q=0;q<4;q++){
    float4 t = Arow[q];
    a[q*4+0]=t.x*inv_avg; a[q*4+1]=t.y*inv_avg;
    a[q*4+2]=t.z*inv_avg; a[q*4+3]=t.w*inv_avg;
  }
  float g3[16];
  #pragma unroll
  for (int i=0;i<16;i++) g3[i]=0.f;
  int pid = 0;
  #pragma unroll
  for (int j=0;j<16;j++){
    #pragma unroll
    for (int l=j;l<16;l++){
      float pa = a[j]*a[l];
      const float* s3r = S3 + pid*16;
      #pragma unroll
      for (int i=0;i<16;i++) g3[i] = fmaf(s3r[i], pa, g3[i]);
      pid++;
    }
  }
  float g2[16];
  #pragma unroll
  for (int i=0;i<16;i++) g2[i]=0.f;
  #pragma unroll
  for (int j=0;j<16;j++){
    float aj = a[j];
    const float* u2r = U2s + j*16;
    #pragma unroll
    for (int i=0;i<16;i++) g2[i] = fmaf(u2r[i], aj, g2[i]);
  }
  float B2=0.f, B3=0.f;
  #pragma unroll
  for (int i=0;i<16;i++){ B2 += a[i]*g2[i]; B3 += a[i]*g3[i]; }
  B2 *= 0.5f; B3 *= (1.0f/3.0f);
  float c1k=c123[k], c2k=c123[KDIM+k], c3k=c123[2*KDIM+k];
  float contrib = a[0]*c1k + B2*c2k + B3*c3k + xbuf[n*KDIM+k]*Wread[k];
  #pragma unroll
  for (int q=0;q<4;q++){
    float4 t;
    t.x = (c2k*g2[q*4+0]+c3k*g3[q*4+0])*inv_avg;
    t.y = (c2k*g2[q*4+1]+c3k*g3[q*4+1])*inv_avg;
    t.z = (c2k*g2[q*4+2]+c3k*g3[q*4+2])*inv_avg;
    t.w = (c2k*g2[q*4+3]+c3k*g3[q*4+3])*inv_avg;
    if (q==0) t.x += c1k*inv_avg;
    Arow[q]=t;
  }
  #pragma unroll
  for (int off=1; off<32; off<<=1) contrib += __shfl_xor(contrib, off, 64);
  if (k==0) atomicAdd(&out_e[batch[n]], contrib);
}

// ---------------------------------------------------------------- edge backward (thread-per-edge, LUT)
__global__ void __launch_bounds__(256) edge_bwd_kernel(
    const int* __restrict__ sndbuf, const int* __restrict__ rcvbuf,
    const float4* __restrict__ vbuf4, const float* __restrict__ ybuf,
    const float* __restrict__ lut, const float* __restrict__ gA,
    float* __restrict__ F){
  int p = blockIdx.x*256 + threadIdx.x;
  int snd = sndbuf[p], rcv = rcvbuf[p];
  float4 v4 = vbuf4[p];
  float vx=v4.x, vy=v4.y, vz=v4.z, r=v4.w;
  float invr = 1.0f/r;
  float ux=vx*invr, uy=vy*invr, uz=vz*invr;
  float u = r*INVR_MAX;
  float t = fminf(u,1.0f)*(float)LUTN;
  int gg = min((int)t, LUTN-1);
  float w = t - (float)gg;
  const float* rowA = lut + (size_t)gg*64;
  float sh[16];
  compute_sh(ux,uy,uz,sh);
  const float4* ga4 = (const float4*)(gA + (size_t)rcv*512);
  const float4* y4  = (const float4*)(ybuf + (size_t)snd*KDIM);
  float gsh[16];
  #pragma unroll
  for (int i=0;i<16;i++) gsh[i]=0.f;
  float grad_r = 0.f;
  #pragma unroll
  for (int k4=0;k4<8;k4++){
    float4 r0 = *(const float4*)(rowA + k4*4);
    float4 r1 = *(const float4*)(rowA + 64 + k4*4);
    float4 d0 = *(const float4*)(rowA + 32 + k4*4);
    float4 d1 = *(const float4*)(rowA + 96 + k4*4);
    float rwv[4]  = { r0.x+(r1.x-r0.x)*w, r0.y+(r1.y-r0.y)*w,
                      r0.z+(r1.z-r0.z)*w, r0.w+(r1.w-r0.w)*w };
    float drwv[4] = { d0.x+(d1.x-d0.x)*w, d0.y+(d1.y-d0.y)*w,
                      d0.z+(d1.z-d0.z)*w, d0.w+(d1.w-d0.w)*w };
    float4 yv = y4[k4];
    float yk[4] = { yv.x, yv.y, yv.z, yv.w };
    #pragma unroll
    for (int q=0;q<4;q++){
      int k = k4*4+q;
      float xsk = yk[q]*rwv[q];
      float4 g0 = ga4[k*4+0];
      float4 g1 = ga4[k*4+1];
      float4 g2_ = ga4[k*4+2];
      float4 g3_ = ga4[k*4+3];
      float gxs = g0.x*sh[0]+g0.y*sh[1]+g0.z*sh[2]+g0.w*sh[3]
                + g1.x*sh[4]+g1.y*sh[5]+g1.z*sh[6]+g1.w*sh[7]
                + g2_.x*sh[8]+g2_.y*sh[9]+g2_.z*sh[10]+g2_.w*sh[11]
                + g3_.x*sh[12]+g3_.y*sh[13]+g3_.z*sh[14]+g3_.w*sh[15];
      gsh[0]+=g0.x*xsk;  gsh[1]+=g0.y*xsk;  gsh[2]+=g0.z*xsk;  gsh[3]+=g0.w*xsk;
      gsh[4]+=g1.x*xsk;  gsh[5]+=g1.y*xsk;  gsh[6]+=g1.z*xsk;  gsh[7]+=g1.w*xsk;
      gsh[8]+=g2_.x*xsk; gsh[9]+=g2_.y*xsk; gsh[10]+=g2_.z*xsk; gsh[11]+=g2_.w*xsk;
      gsh[12]+=g3_.x*xsk;gsh[13]+=g3_.y*xsk;gsh[14]+=g3_.z*xsk; gsh[15]+=g3_.w*xsk;
      grad_r += gxs*yk[q]*drwv[q];
    }
  }
  float x_=ux, y_=uy, z_=uz;
  float x2=x_*x_, y2=y_*y_, z2=z_*z_;
  const float* g = gsh;
  float gux = 0.48860251f*g[3]
            + 1.09254843f*(y_*g[4] + z_*g[7])
            + 1.09254844f*x_*g[8]
            + 3.54026154f*x_*y_*g[9]
            + 2.89061144f*y_*z_*g[10]
            + 0.45704579f*(5.0f*z2-1.0f)*g[13]
            + 2.89061144f*x_*z_*g[14]
            + 1.77013077f*(x2-y2)*g[15];
  float guy = 0.48860251f*g[1]
            + 1.09254843f*(x_*g[4] + z_*g[5])
            - 1.09254844f*y_*g[8]
            + 1.77013077f*(x2-y2)*g[9]
            + 2.89061144f*x_*z_*g[10]
            + 0.45704579f*(5.0f*z2-1.0f)*g[11]
            - 2.89061144f*y_*z_*g[14]
            - 3.54026154f*x_*y_*g[15];
  float guz = 0.48860251f*g[2]
            + 1.09254843f*(y_*g[5] + x_*g[7])
            + 1.89234942f*z_*g[6]
            + 2.89061144f*x_*y_*g[10]
            + 4.5704579f*y_*z_*g[11]
            + 0.37317633f*(15.0f*z2-3.0f)*g[12]
            + 4.5704579f*x_*z_*g[13]
            + 1.44530572f*(x2-y2)*g[14];
  float dotg = gux*x_ + guy*y_ + guz*z_;
  float gvx = grad_r*x_ + (gux - dotg*x_)*invr;
  float gvy = grad_r*y_ + (guy - dotg*y_)*invr;
  float gvz = grad_r*z_ + (guz - dotg*z_)*invr;
  atomicAdd(&F[snd*3+0],  gvx);
  atomicAdd(&F[snd*3+1],  gvy);
  atomicAdd(&F[snd*3+2],  gvz);
  atomicAdd(&F[rcv*3+0], -gvx);
  atomicAdd(&F[rcv*3+1], -gvy);
  atomicAdd(&F[rcv*3+2], -gvz);
}

extern "C" void kernel_launch(void* const* d_in, const int* in_sizes, int n_in,
                              void* d_out, int out_size, void* d_ws, size_t ws_size,
                              hipStream_t stream){
  const float* positions       = (const float*)d_in[0];
  const float* node_attrs      = (const float*)d_in[1];
  const int*   edge_index      = (const int*)  d_in[2];
  const float* shifts          = (const float*)d_in[3];
  const int*   batch           = (const int*)  d_in[4];
  const float* atomic_energies = (const float*)d_in[6];
  const float* W_embed         = (const float*)d_in[7];
  const float* W_up            = (const float*)d_in[8];
  const float* W_r1            = (const float*)d_in[9];
  const float* b_r1            = (const float*)d_in[10];
  const float* W_r2            = (const float*)d_in[11];
  const float* U2              = (const float*)d_in[12];
  const float* U3              = (const float*)d_in[13];
  const float* Wp1             = (const float*)d_in[14];
  const float* Wp2             = (const float*)d_in[15];
  const float* Wp3             = (const float*)d_in[16];
  const float* W_read          = (const float*)d_in[17];
  float* out = (float*)d_out;

  float* Abuf  = (float*)d_ws;                        // N*512 (A, then gA in place)
  float* xbuf  = Abuf  + (size_t)NNODES*KDIM*NSHD;    // N*32
  float* ybuf  = xbuf  + (size_t)NNODES*KDIM;         // N*32
  float* lut   = ybuf  + (size_t)NNODES*KDIM;         // 2050*64
  float* S3    = lut   + (size_t)2050*64;             // 136*16 -> pad 2304
  float* U2s   = S3    + 2304;                        // 256
  float* c123  = U2s   + 256;                         // 96 -> pad 128
  float4* vbuf4 = (float4*)(c123 + 128);              // E float4
  int* sndbuf  = (int*)(vbuf4 + (size_t)NEDGES);      // E
  int* rcvbuf  = sndbuf + NEDGES;                     // E
  int* cnt       = rcvbuf + NEDGES;                   // N
  int* row_start = cnt + NNODES;                      // N+1 (pad 64)
  int* woff      = row_start + NNODES + 64;           // N
  int* elist     = woff + NNODES;                     // E

  hipMemsetAsync(d_out, 0, sizeof(float)*(NGRAPH + (size_t)NNODES*3), stream);
  hipMemsetAsync(cnt, 0, sizeof(int)*NNODES, stream);

  prep_kernel<<<1,256,0,stream>>>(U2,U3,Wp1,Wp2,Wp3,W_read,S3,U2s,c123);
  lut_kernel<<<(LUTN+1+255)/256,256,0,stream>>>(W_r1,b_r1,W_r2,lut);
  csr_count_kernel<<<NEDGES/256,256,0,stream>>>(edge_index, cnt);
  csr_scan_kernel<<<1,1024,0,stream>>>(cnt, row_start, woff);
  csr_scatter_kernel<<<NEDGES/256,256,0,stream>>>(edge_index, woff, elist);
  node_embed_kernel<<<NNODES/4,256,0,stream>>>(node_attrs,W_embed,W_up,atomic_energies,
                                               batch,xbuf,ybuf,out);
  node_accA_kernel<<<NNODES/4,256,0,stream>>>(row_start,elist,edge_index,shifts,
                                              positions,ybuf,lut,vbuf4,sndbuf,rcvbuf,Abuf);
  node_b_kernel<<<NNODES/8,256,0,stream>>>(Abuf,xbuf,batch,S3,U2s,c123,W_read,out);
  edge_bwd_kernel<<<NEDGES/256,256,0,stream>>>(sndbuf,rcvbuf,vbuf4,ybuf,lut,Abuf,out+NGRAPH);
}

// Round 6
// 1456.908 us; speedup vs baseline: 2.4916x; 1.2186x over previous
//
#include <hip/hip_runtime.h>
#include <math.h>

#define NNODES 32768
#define NEDGES 524288
#define KDIM 32
#define NSHD 16
#define NB 8
#define NHID 64
#define NGRAPH 16
#define NELEM 10
#define RMAXF 5.0f
#define INVR_MAX 0.2f
#define PI_F 3.14159265358979f
#define CBES 0.632455532033676f   /* sqrt(2/R_MAX) */
#define LUTN 2048                 /* intervals; rows 0..LUTN (row LUTN = beyond-cutoff const) */

// 16 named outputs: keeps the SH values in VGPRs (array form triggered
// PromoteAlloca -> LDS with 32-way bank conflicts, R5 post-mortem).
__device__ __forceinline__ void compute_sh16(float x, float y, float z,
    float& s0, float& s1, float& s2, float& s3,
    float& s4, float& s5, float& s6, float& s7,
    float& s8, float& s9, float& s10, float& s11,
    float& s12, float& s13, float& s14, float& s15){
  float x2=x*x, y2=y*y, z2=z*z;
  s0=0.28209479f;
  s1=0.48860251f*y;
  s2=0.48860251f*z;
  s3=0.48860251f*x;
  s4=1.09254843f*x*y;
  s5=1.09254843f*y*z;
  s6=0.31539157f*(3.0f*z2-1.0f);
  s7=1.09254843f*x*z;
  s8=0.54627422f*(x2-y2);
  s9=0.59004359f*y*(3.0f*x2-y2);
  s10=2.89061144f*x*y*z;
  s11=0.45704579f*y*(5.0f*z2-1.0f);
  s12=0.37317633f*z*(5.0f*z2-3.0f);
  s13=0.45704579f*x*(5.0f*z2-1.0f);
  s14=1.44530572f*z*(x2-y2);
  s15=0.59004359f*x*(x2-3.0f*y2);
}

// ---------------------------------------------------------------- prep
__global__ void prep_kernel(const float* __restrict__ U2, const float* __restrict__ U3,
                            const float* __restrict__ Wp1, const float* __restrict__ Wp2,
                            const float* __restrict__ Wp3, const float* __restrict__ Wread,
                            float* __restrict__ S3, float* __restrict__ U2s,
                            float* __restrict__ c123){
  int t = threadIdx.x;
  for (int v = t; v < 136*16; v += 256){
    int pid = v >> 4, i = v & 15;
    int j = 0, rem = pid;
    while (rem >= 16 - j){ rem -= 16 - j; j++; }
    int l = j + rem;
    float s;
    if (j == l){
      s = U3[i*256 + j*16 + j] + U3[j*256 + i*16 + j] + U3[j*256 + j*16 + i];
    } else {
      s = U3[i*256 + j*16 + l] + U3[j*256 + i*16 + l] + U3[j*256 + l*16 + i]
        + U3[i*256 + l*16 + j] + U3[l*256 + i*16 + j] + U3[l*256 + j*16 + i];
    }
    S3[v] = s;
  }
  {
    int i = t >> 4, j = t & 15;
    U2s[t] = U2[i*16+j] + U2[j*16+i];
  }
  if (t < 96){
    int which = t >> 5, k = t & 31;
    const float* Wp = (which==0)?Wp1:((which==1)?Wp2:Wp3);
    float s = 0.f;
    for (int q=0;q<KDIM;q++) s += Wp[k*KDIM+q]*Wread[q];
    c123[t] = s;
  }
}

// ---------------------------------------------------------------- radial LUT
__global__ void lut_kernel(const float* __restrict__ W_r1, const float* __restrict__ b_r1,
                           const float* __restrict__ W_r2, float* __restrict__ lut){
  int g = blockIdx.x*256 + threadIdx.x;
  if (g > LUTN) return;
  float r = fmaxf(5.0f*(float)g/(float)LUTN, 1e-9f);
  float invr = 1.0f/r;
  float u = r*INVR_MAX;
  float cut = 0.f, dcdr = 0.f;
  if (u < 1.0f){
    float u2=u*u, u3=u2*u, u6=u3*u3;
    cut = 1.0f - 28.0f*u6 + 48.0f*u6*u - 21.0f*u6*u2;
    float u4=u2*u2, om=1.0f-u;
    dcdr = -168.0f*u4*u*om*om*INVR_MAX;
  }
  float b[NB], db[NB];
  #pragma unroll
  for (int q=0;q<NB;q++){
    float nn = (float)(q+1);
    float ang = PI_F*nn*u;
    float S = sinf(ang), C = cosf(ang);
    b[q]  = CBES*S*invr*cut;
    db[q] = CBES*invr*((PI_F*nn*INVR_MAX)*C - S*invr)*cut + CBES*S*invr*dcdr;
  }
  float Rw[KDIM], dRw[KDIM];
  #pragma unroll
  for (int k=0;k<KDIM;k++){ Rw[k]=0.f; dRw[k]=0.f; }
  for (int m=0;m<NHID;m++){
    float h = b_r1[m], dh = 0.f;
    #pragma unroll
    for (int q=0;q<NB;q++){ h += b[q]*W_r1[q*NHID+m]; dh += db[q]*W_r1[q*NHID+m]; }
    float sg = 1.0f/(1.0f+expf(-h));
    float s  = h*sg;
    float sp = sg*(1.0f + h*(1.0f-sg));
    float f  = sp*dh;
    #pragma unroll
    for (int k=0;k<KDIM;k++){
      Rw[k]  += s*W_r2[m*KDIM+k];
      dRw[k] += f*W_r2[m*KDIM+k];
    }
  }
  #pragma unroll
  for (int k=0;k<KDIM;k++){
    lut[(size_t)g*64 + k]      = Rw[k];
    lut[(size_t)g*64 + 32 + k] = dRw[k];
  }
}

// ---------------------------------------------------------------- CSR build
__global__ void csr_count_kernel(const int* __restrict__ eidx, int* __restrict__ cnt){
  int e = blockIdx.x*256 + threadIdx.x;
  if (e < NEDGES) atomicAdd(&cnt[eidx[NEDGES + e]], 1);
}

__global__ void csr_scan_kernel(const int* __restrict__ cnt, int* __restrict__ row_start,
                                int* __restrict__ woff){
  __shared__ int part[1024];
  int t = threadIdx.x;
  int base_idx = t*32;
  int local[32];
  int s = 0;
  #pragma unroll
  for (int j=0;j<32;j++){
    int c = cnt[base_idx+j];
    local[j] = s;
    s += c;
  }
  part[t] = s;
  __syncthreads();
  for (int off=1; off<1024; off<<=1){
    int v = (t>=off) ? part[t-off] : 0;
    __syncthreads();
    part[t] += v;
    __syncthreads();
  }
  int base = (t==0) ? 0 : part[t-1];
  #pragma unroll
  for (int j=0;j<32;j++){
    int v = base + local[j];
    row_start[base_idx+j] = v;
    woff[base_idx+j] = v;
  }
  if (t==1023) row_start[NNODES] = part[1023];
}

__global__ void csr_scatter_kernel(const int* __restrict__ eidx, int* __restrict__ woff,
                                   int* __restrict__ elist){
  int e = blockIdx.x*256 + threadIdx.x;
  if (e < NEDGES){
    int rcv = eidx[NEDGES + e];
    int p = atomicAdd(&woff[rcv], 1);
    elist[p] = e;
  }
}

// ---------------------------------------------------------------- node embed
__global__ void node_embed_kernel(const float* __restrict__ attrs,
                                  const float* __restrict__ W_embed,
                                  const float* __restrict__ W_up,
                                  const float* __restrict__ ae,
                                  const int* __restrict__ batch,
                                  float* __restrict__ xbuf, float* __restrict__ ybuf,
                                  float* __restrict__ out_e){
  int gtid = blockIdx.x*256 + threadIdx.x;
  int n = gtid >> 6;
  int lane = threadIdx.x & 63;
  int k = lane & 31;
  float xv = 0.f;
  #pragma unroll
  for (int e=0;e<NELEM;e++) xv += attrs[n*NELEM+e]*W_embed[e*KDIM+k];
  float yv = 0.f;
  #pragma unroll 8
  for (int k2=0;k2<KDIM;k2++) yv += __shfl(xv, k2, 64) * W_up[k2*KDIM+k];
  if (lane < 32){
    xbuf[n*KDIM+k]=xv;
    ybuf[n*KDIM+k]=yv;
  }
  if (lane == 0){
    float s=0.f;
    #pragma unroll
    for (int e=0;e<NELEM;e++) s += attrs[n*NELEM+e]*ae[e];
    atomicAdd(&out_e[batch[n]], s);
  }
}

// ---------------------------------------------------------------- A accumulation (fused radial LUT)
__global__ void __launch_bounds__(256) node_accA_kernel(
    const int* __restrict__ row_start, const int* __restrict__ elist,
    const int* __restrict__ eidx, const float* __restrict__ shifts,
    const float* __restrict__ pos, const float* __restrict__ ybuf,
    const float* __restrict__ lut,
    float4* __restrict__ vbuf4, int* __restrict__ sndbuf, int* __restrict__ rcvbuf,
    float* __restrict__ A){
  int tid = threadIdx.x;
  int wl = tid>>6, lane = tid&63;
  int n = blockIdx.x*4 + wl;
  int k2 = lane>>1, ihalf = lane&1;
  float a0=0.f,a1=0.f,a2=0.f,a3=0.f,a4=0.f,a5=0.f,a6=0.f,a7=0.f;
  float px=pos[n*3+0], py=pos[n*3+1], pz=pos[n*3+2];
  int rs=row_start[n], re=row_start[n+1];
  for (int p=rs; p<re; ++p){
    int e = elist[p];
    int snd = eidx[e];
    float vx = px - pos[snd*3+0] + shifts[(size_t)e*3+0];
    float vy = py - pos[snd*3+1] + shifts[(size_t)e*3+1];
    float vz = pz - pos[snd*3+2] + shifts[(size_t)e*3+2];
    float r = sqrtf(vx*vx+vy*vy+vz*vz + 1e-18f);
    float invr = 1.0f/r;
    float u = r*INVR_MAX;
    float t = fminf(u,1.0f)*(float)LUTN;
    int gg = min((int)t, LUTN-1);
    float w = t - (float)gg;
    const float* rowA = lut + (size_t)gg*64;
    float rw0 = rowA[k2], rw1 = rowA[64+k2];
    float rw = rw0 + (rw1-rw0)*w;
    float y = ybuf[(size_t)snd*KDIM + k2];
    float xs = y*rw;
    float s0,s1,s2,s3,s4,s5,s6,s7,s8,s9,s10,s11,s12,s13,s14,s15;
    compute_sh16(vx*invr, vy*invr, vz*invr,
                 s0,s1,s2,s3,s4,s5,s6,s7,s8,s9,s10,s11,s12,s13,s14,s15);
    float e0 = ihalf ? s8  : s0;
    float e1 = ihalf ? s9  : s1;
    float e2 = ihalf ? s10 : s2;
    float e3 = ihalf ? s11 : s3;
    float e4 = ihalf ? s12 : s4;
    float e5 = ihalf ? s13 : s5;
    float e6 = ihalf ? s14 : s6;
    float e7 = ihalf ? s15 : s7;
    a0 = fmaf(xs, e0, a0);
    a1 = fmaf(xs, e1, a1);
    a2 = fmaf(xs, e2, a2);
    a3 = fmaf(xs, e3, a3);
    a4 = fmaf(xs, e4, a4);
    a5 = fmaf(xs, e5, a5);
    a6 = fmaf(xs, e6, a6);
    a7 = fmaf(xs, e7, a7);
    if (lane == 0){
      vbuf4[p] = make_float4(vx,vy,vz,r);
      sndbuf[p] = snd;
      rcvbuf[p] = n;
    }
  }
  float4* Ao = (float4*)(A + (size_t)n*512 + lane*8);
  Ao[0] = make_float4(a0,a1,a2,a3);
  Ao[1] = make_float4(a4,a5,a6,a7);
}

// ---------------------------------------------------------------- node B-ops
__global__ void __launch_bounds__(256) node_b_kernel(
    float* Abuf, const float* __restrict__ xbuf,
    const int* __restrict__ batch, const float* __restrict__ S3,
    const float* __restrict__ U2s, const float* __restrict__ c123,
    const float* __restrict__ Wread, float* __restrict__ out_e){
  int n = blockIdx.x*8 + (threadIdx.x>>5);
  int k = threadIdx.x & 31;
  const float inv_avg = 1.0f/16.0f;
  float a[16];
  float4* Arow = (float4*)(Abuf + ((size_t)n*KDIM + k)*NSHD);
  #pragma unroll
  for (int q=0;q<4;q++){
    float4 t = Arow[q];
    a[q*4+0]=t.x*inv_avg; a[q*4+1]=t.y*inv_avg;
    a[q*4+2]=t.z*inv_avg; a[q*4+3]=t.w*inv_avg;
  }
  float g3[16];
  #pragma unroll
  for (int i=0;i<16;i++) g3[i]=0.f;
  int pid = 0;
  #pragma unroll
  for (int j=0;j<16;j++){
    #pragma unroll
    for (int l=j;l<16;l++){
      float pa = a[j]*a[l];
      const float* s3r = S3 + pid*16;
      #pragma unroll
      for (int i=0;i<16;i++) g3[i] = fmaf(s3r[i], pa, g3[i]);
      pid++;
    }
  }
  float g2[16];
  #pragma unroll
  for (int i=0;i<16;i++) g2[i]=0.f;
  #pragma unroll
  for (int j=0;j<16;j++){
    float aj = a[j];
    const float* u2r = U2s + j*16;
    #pragma unroll
    for (int i=0;i<16;i++) g2[i] = fmaf(u2r[i], aj, g2[i]);
  }
  float B2=0.f, B3=0.f;
  #pragma unroll
  for (int i=0;i<16;i++){ B2 += a[i]*g2[i]; B3 += a[i]*g3[i]; }
  B2 *= 0.5f; B3 *= (1.0f/3.0f);
  float c1k=c123[k], c2k=c123[KDIM+k], c3k=c123[2*KDIM+k];
  float contrib = a[0]*c1k + B2*c2k + B3*c3k + xbuf[n*KDIM+k]*Wread[k];
  #pragma unroll
  for (int q=0;q<4;q++){
    float4 t;
    t.x = (c2k*g2[q*4+0]+c3k*g3[q*4+0])*inv_avg;
    t.y = (c2k*g2[q*4+1]+c3k*g3[q*4+1])*inv_avg;
    t.z = (c2k*g2[q*4+2]+c3k*g3[q*4+2])*inv_avg;
    t.w = (c2k*g2[q*4+3]+c3k*g3[q*4+3])*inv_avg;
    if (q==0) t.x += c1k*inv_avg;
    Arow[q]=t;
  }
  #pragma unroll
  for (int off=1; off<32; off<<=1) contrib += __shfl_xor(contrib, off, 64);
  if (k==0) atomicAdd(&out_e[batch[n]], contrib);
}

// ---------------------------------------------------------------- edge backward (thread-per-edge, LUT)
__global__ void __launch_bounds__(256) edge_bwd_kernel(
    const int* __restrict__ sndbuf, const int* __restrict__ rcvbuf,
    const float4* __restrict__ vbuf4, const float* __restrict__ ybuf,
    const float* __restrict__ lut, const float* __restrict__ gA,
    float* __restrict__ F){
  int p = blockIdx.x*256 + threadIdx.x;
  int snd = sndbuf[p], rcv = rcvbuf[p];
  float4 v4 = vbuf4[p];
  float vx=v4.x, vy=v4.y, vz=v4.z, r=v4.w;
  float invr = 1.0f/r;
  float ux=vx*invr, uy=vy*invr, uz=vz*invr;
  float u = r*INVR_MAX;
  float t = fminf(u,1.0f)*(float)LUTN;
  int gg = min((int)t, LUTN-1);
  float w = t - (float)gg;
  const float* rowA = lut + (size_t)gg*64;
  float s0,s1,s2,s3,s4,s5,s6,s7,s8,s9,s10,s11,s12,s13,s14,s15;
  compute_sh16(ux,uy,uz,
               s0,s1,s2,s3,s4,s5,s6,s7,s8,s9,s10,s11,s12,s13,s14,s15);
  const float4* ga4 = (const float4*)(gA + (size_t)rcv*512);
  const float4* y4  = (const float4*)(ybuf + (size_t)snd*KDIM);
  float G0=0.f,G1=0.f,G2=0.f,G3v=0.f,G4=0.f,G5=0.f,G6=0.f,G7=0.f;
  float G8=0.f,G9=0.f,G10=0.f,G11=0.f,G12=0.f,G13=0.f,G14=0.f,G15=0.f;
  float grad_r = 0.f;
  #pragma unroll
  for (int k4=0;k4<8;k4++){
    float4 r0 = *(const float4*)(rowA + k4*4);
    float4 r1 = *(const float4*)(rowA + 64 + k4*4);
    float4 d0 = *(const float4*)(rowA + 32 + k4*4);
    float4 d1 = *(const float4*)(rowA + 96 + k4*4);
    float rwv0 = r0.x+(r1.x-r0.x)*w, rwv1 = r0.y+(r1.y-r0.y)*w;
    float rwv2 = r0.z+(r1.z-r0.z)*w, rwv3 = r0.w+(r1.w-r0.w)*w;
    float dr0 = d0.x+(d1.x-d0.x)*w, dr1 = d0.y+(d1.y-d0.y)*w;
    float dr2 = d0.z+(d1.z-d0.z)*w, dr3 = d0.w+(d1.w-d0.w)*w;
    float4 yv = y4[k4];
    #pragma unroll
    for (int q=0;q<4;q++){
      int k = k4*4+q;
      float yk  = (q==0)?yv.x:((q==1)?yv.y:((q==2)?yv.z:yv.w));
      float rwq = (q==0)?rwv0:((q==1)?rwv1:((q==2)?rwv2:rwv3));
      float drq = (q==0)?dr0:((q==1)?dr1:((q==2)?dr2:dr3));
      float xsk = yk*rwq;
      float4 t0 = ga4[k*4+0];
      float4 t1 = ga4[k*4+1];
      float4 t2 = ga4[k*4+2];
      float4 t3 = ga4[k*4+3];
      float gxs = t0.x*s0+t0.y*s1+t0.z*s2+t0.w*s3
                + t1.x*s4+t1.y*s5+t1.z*s6+t1.w*s7
                + t2.x*s8+t2.y*s9+t2.z*s10+t2.w*s11
                + t3.x*s12+t3.y*s13+t3.z*s14+t3.w*s15;
      G0  = fmaf(t0.x,xsk,G0);  G1  = fmaf(t0.y,xsk,G1);
      G2  = fmaf(t0.z,xsk,G2);  G3v = fmaf(t0.w,xsk,G3v);
      G4  = fmaf(t1.x,xsk,G4);  G5  = fmaf(t1.y,xsk,G5);
      G6  = fmaf(t1.z,xsk,G6);  G7  = fmaf(t1.w,xsk,G7);
      G8  = fmaf(t2.x,xsk,G8);  G9  = fmaf(t2.y,xsk,G9);
      G10 = fmaf(t2.z,xsk,G10); G11 = fmaf(t2.w,xsk,G11);
      G12 = fmaf(t3.x,xsk,G12); G13 = fmaf(t3.y,xsk,G13);
      G14 = fmaf(t3.z,xsk,G14); G15 = fmaf(t3.w,xsk,G15);
      grad_r += gxs*yk*drq;
    }
  }
  float x_=ux, y_=uy, z_=uz;
  float x2=x_*x_, y2=y_*y_, z2=z_*z_;
  float gux = 0.48860251f*G3v
            + 1.09254843f*(y_*G4 + z_*G7)
            + 1.09254844f*x_*G8
            + 3.54026154f*x_*y_*G9
            + 2.89061144f*y_*z_*G10
            + 0.45704579f*(5.0f*z2-1.0f)*G13
            + 2.89061144f*x_*z_*G14
            + 1.77013077f*(x2-y2)*G15;
  float guy = 0.48860251f*G1
            + 1.09254843f*(x_*G4 + z_*G5)
            - 1.09254844f*y_*G8
            + 1.77013077f*(x2-y2)*G9
            + 2.89061144f*x_*z_*G10
            + 0.45704579f*(5.0f*z2-1.0f)*G11
            - 2.89061144f*y_*z_*G14
            - 3.54026154f*x_*y_*G15;
  float guz = 0.48860251f*G2
            + 1.09254843f*(y_*G5 + x_*G7)
            + 1.89234942f*z_*G6
            + 2.89061144f*x_*y_*G10
            + 4.5704579f*y_*z_*G11
            + 0.37317633f*(15.0f*z2-3.0f)*G12
            + 4.5704579f*x_*z_*G13
            + 1.44530572f*(x2-y2)*G14;
  float dotg = gux*x_ + guy*y_ + guz*z_;
  float gvx = grad_r*x_ + (gux - dotg*x_)*invr;
  float gvy = grad_r*y_ + (guy - dotg*y_)*invr;
  float gvz = grad_r*z_ + (guz - dotg*z_)*invr;
  atomicAdd(&F[snd*3+0],  gvx);
  atomicAdd(&F[snd*3+1],  gvy);
  atomicAdd(&F[snd*3+2],  gvz);
  atomicAdd(&F[rcv*3+0], -gvx);
  atomicAdd(&F[rcv*3+1], -gvy);
  atomicAdd(&F[rcv*3+2], -gvz);
}

extern "C" void kernel_launch(void* const* d_in, const int* in_sizes, int n_in,
                              void* d_out, int out_size, void* d_ws, size_t ws_size,
                              hipStream_t stream){
  const float* positions       = (const float*)d_in[0];
  const float* node_attrs      = (const float*)d_in[1];
  const int*   edge_index      = (const int*)  d_in[2];
  const float* shifts          = (const float*)d_in[3];
  const int*   batch           = (const int*)  d_in[4];
  const float* atomic_energies = (const float*)d_in[6];
  const float* W_embed         = (const float*)d_in[7];
  const float* W_up            = (const float*)d_in[8];
  const float* W_r1            = (const float*)d_in[9];
  const float* b_r1            = (const float*)d_in[10];
  const float* W_r2            = (const float*)d_in[11];
  const float* U2              = (const float*)d_in[12];
  const float* U3              = (const float*)d_in[13];
  const float* Wp1             = (const float*)d_in[14];
  const float* Wp2             = (const float*)d_in[15];
  const float* Wp3             = (const float*)d_in[16];
  const float* W_read          = (const float*)d_in[17];
  float* out = (float*)d_out;

  float* Abuf  = (float*)d_ws;                        // N*512 (A, then gA in place)
  float* xbuf  = Abuf  + (size_t)NNODES*KDIM*NSHD;    // N*32
  float* ybuf  = xbuf  + (size_t)NNODES*KDIM;         // N*32
  float* lut   = ybuf  + (size_t)NNODES*KDIM;         // 2050*64
  float* S3    = lut   + (size_t)2050*64;             // 136*16 -> pad 2304
  float* U2s   = S3    + 2304;                        // 256
  float* c123  = U2s   + 256;                         // 96 -> pad 128
  float4* vbuf4 = (float4*)(c123 + 128);              // E float4
  int* sndbuf  = (int*)(vbuf4 + (size_t)NEDGES);      // E
  int* rcvbuf  = sndbuf + NEDGES;                     // E
  int* cnt       = rcvbuf + NEDGES;                   // N
  int* row_start = cnt + NNODES;                      // N+1 (pad 64)
  int* woff      = row_start + NNODES + 64;           // N
  int* elist     = woff + NNODES;                     // E

  hipMemsetAsync(d_out, 0, sizeof(float)*(NGRAPH + (size_t)NNODES*3), stream);
  hipMemsetAsync(cnt, 0, sizeof(int)*NNODES, stream);

  prep_kernel<<<1,256,0,stream>>>(U2,U3,Wp1,Wp2,Wp3,W_read,S3,U2s,c123);
  lut_kernel<<<(LUTN+1+255)/256,256,0,stream>>>(W_r1,b_r1,W_r2,lut);
  csr_count_kernel<<<NEDGES/256,256,0,stream>>>(edge_index, cnt);
  csr_scan_kernel<<<1,1024,0,stream>>>(cnt, row_start, woff);
  csr_scatter_kernel<<<NEDGES/256,256,0,stream>>>(edge_index, woff, elist);
  node_embed_kernel<<<NNODES/4,256,0,stream>>>(node_attrs,W_embed,W_up,atomic_energies,
                                               batch,xbuf,ybuf,out);
  node_accA_kernel<<<NNODES/4,256,0,stream>>>(row_start,elist,edge_index,shifts,
                                              positions,ybuf,lut,vbuf4,sndbuf,rcvbuf,Abuf);
  node_b_kernel<<<NNODES/8,256,0,stream>>>(Abuf,xbuf,batch,S3,U2s,c123,W_read,out);
  edge_bwd_kernel<<<NEDGES/256,256,0,stream>>>(sndbuf,rcvbuf,vbuf4,ybuf,lut,Abuf,out+NGRAPH);
}

// Round 7
// 1049.199 us; speedup vs baseline: 3.4598x; 1.3886x over previous
//
#include <hip/hip_runtime.h>
#include <math.h>

#define NNODES 32768
#define NEDGES 524288
#define KDIM 32
#define NSHD 16
#define NB 8
#define NHID 64
#define NGRAPH 16
#define NELEM 10
#define RMAXF 5.0f
#define INVR_MAX 0.2f
#define PI_F 3.14159265358979f
#define CBES 0.632455532033676f   /* sqrt(2/R_MAX) */
#define LUTN 2048
#define NPAIR 136                 /* 16*17/2 symmetric (j<=l) pairs */

// 16 named outputs: keeps SH values in VGPRs (array form triggered
// PromoteAlloca -> LDS with 32-way bank conflicts, R5 post-mortem).
__device__ __forceinline__ void compute_sh16(float x, float y, float z,
    float& s0, float& s1, float& s2, float& s3,
    float& s4, float& s5, float& s6, float& s7,
    float& s8, float& s9, float& s10, float& s11,
    float& s12, float& s13, float& s14, float& s15){
  float x2=x*x, y2=y*y, z2=z*z;
  s0=0.28209479f;
  s1=0.48860251f*y;
  s2=0.48860251f*z;
  s3=0.48860251f*x;
  s4=1.09254843f*x*y;
  s5=1.09254843f*y*z;
  s6=0.31539157f*(3.0f*z2-1.0f);
  s7=1.09254843f*x*z;
  s8=0.54627422f*(x2-y2);
  s9=0.59004359f*y*(3.0f*x2-y2);
  s10=2.89061144f*x*y*z;
  s11=0.45704579f*y*(5.0f*z2-1.0f);
  s12=0.37317633f*z*(5.0f*z2-3.0f);
  s13=0.45704579f*x*(5.0f*z2-1.0f);
  s14=1.44530572f*z*(x2-y2);
  s15=0.59004359f*x*(x2-3.0f*y2);
}

// ---------------------------------------------------------------- prep
__global__ void prep_kernel(const float* __restrict__ U2, const float* __restrict__ U3,
                            const float* __restrict__ Wp1, const float* __restrict__ Wp2,
                            const float* __restrict__ Wp3, const float* __restrict__ Wread,
                            float* __restrict__ S3, float* __restrict__ U2s,
                            float* __restrict__ c123){
  int t = threadIdx.x;
  for (int v = t; v < NPAIR*16; v += 256){
    int pid = v >> 4, i = v & 15;
    int j = 0, rem = pid;
    while (rem >= 16 - j){ rem -= 16 - j; j++; }
    int l = j + rem;
    float s;
    if (j == l){
      s = U3[i*256 + j*16 + j] + U3[j*256 + i*16 + j] + U3[j*256 + j*16 + i];
    } else {
      s = U3[i*256 + j*16 + l] + U3[j*256 + i*16 + l] + U3[j*256 + l*16 + i]
        + U3[i*256 + l*16 + j] + U3[l*256 + i*16 + j] + U3[l*256 + j*16 + i];
    }
    S3[v] = s;
  }
  {
    int i = t >> 4, j = t & 15;
    U2s[t] = U2[i*16+j] + U2[j*16+i];
  }
  if (t < 96){
    int which = t >> 5, k = t & 31;
    const float* Wp = (which==0)?Wp1:((which==1)?Wp2:Wp3);
    float s = 0.f;
    for (int q=0;q<KDIM;q++) s += Wp[k*KDIM+q]*Wread[q];
    c123[t] = s;
  }
}

// ---------------------------------------------------------------- radial LUT
__global__ void lut_kernel(const float* __restrict__ W_r1, const float* __restrict__ b_r1,
                           const float* __restrict__ W_r2, float* __restrict__ lut){
  int g = blockIdx.x*256 + threadIdx.x;
  if (g > LUTN) return;
  float r = fmaxf(5.0f*(float)g/(float)LUTN, 1e-9f);
  float invr = 1.0f/r;
  float u = r*INVR_MAX;
  float cut = 0.f, dcdr = 0.f;
  if (u < 1.0f){
    float u2=u*u, u3=u2*u, u6=u3*u3;
    cut = 1.0f - 28.0f*u6 + 48.0f*u6*u - 21.0f*u6*u2;
    float u4=u2*u2, om=1.0f-u;
    dcdr = -168.0f*u4*u*om*om*INVR_MAX;
  }
  float b[NB], db[NB];
  #pragma unroll
  for (int q=0;q<NB;q++){
    float nn = (float)(q+1);
    float ang = PI_F*nn*u;
    float S = sinf(ang), C = cosf(ang);
    b[q]  = CBES*S*invr*cut;
    db[q] = CBES*invr*((PI_F*nn*INVR_MAX)*C - S*invr)*cut + CBES*S*invr*dcdr;
  }
  float Rw[KDIM], dRw[KDIM];
  #pragma unroll
  for (int k=0;k<KDIM;k++){ Rw[k]=0.f; dRw[k]=0.f; }
  for (int m=0;m<NHID;m++){
    float h = b_r1[m], dh = 0.f;
    #pragma unroll
    for (int q=0;q<NB;q++){ h += b[q]*W_r1[q*NHID+m]; dh += db[q]*W_r1[q*NHID+m]; }
    float sg = 1.0f/(1.0f+expf(-h));
    float s  = h*sg;
    float sp = sg*(1.0f + h*(1.0f-sg));
    float f  = sp*dh;
    #pragma unroll
    for (int k=0;k<KDIM;k++){
      Rw[k]  += s*W_r2[m*KDIM+k];
      dRw[k] += f*W_r2[m*KDIM+k];
    }
  }
  #pragma unroll
  for (int k=0;k<KDIM;k++){
    lut[(size_t)g*64 + k]      = Rw[k];
    lut[(size_t)g*64 + 32 + k] = dRw[k];
  }
}

// ---------------------------------------------------------------- CSR build
__global__ void csr_count_kernel(const int* __restrict__ eidx, int* __restrict__ cnt){
  int e = blockIdx.x*256 + threadIdx.x;
  if (e < NEDGES) atomicAdd(&cnt[eidx[NEDGES + e]], 1);
}

__global__ void csr_scan_kernel(const int* __restrict__ cnt, int* __restrict__ row_start,
                                int* __restrict__ woff){
  __shared__ int part[1024];
  int t = threadIdx.x;
  int base_idx = t*32;
  int local[32];
  int s = 0;
  #pragma unroll
  for (int j=0;j<32;j++){
    int c = cnt[base_idx+j];
    local[j] = s;
    s += c;
  }
  part[t] = s;
  __syncthreads();
  for (int off=1; off<1024; off<<=1){
    int v = (t>=off) ? part[t-off] : 0;
    __syncthreads();
    part[t] += v;
    __syncthreads();
  }
  int base = (t==0) ? 0 : part[t-1];
  #pragma unroll
  for (int j=0;j<32;j++){
    int v = base + local[j];
    row_start[base_idx+j] = v;
    woff[base_idx+j] = v;
  }
  if (t==1023) row_start[NNODES] = part[1023];
}

__global__ void csr_scatter_kernel(const int* __restrict__ eidx, int* __restrict__ woff,
                                   int* __restrict__ elist){
  int e = blockIdx.x*256 + threadIdx.x;
  if (e < NEDGES){
    int rcv = eidx[NEDGES + e];
    int p = atomicAdd(&woff[rcv], 1);
    elist[p] = e;
  }
}

// ---------------------------------------------------------------- node embed
// e0 written per node (no 16-address atomic hotspot; reduced in reduce_e).
__global__ void node_embed_kernel(const float* __restrict__ attrs,
                                  const float* __restrict__ W_embed,
                                  const float* __restrict__ W_up,
                                  const float* __restrict__ ae,
                                  float* __restrict__ xbuf, float* __restrict__ ybuf,
                                  float* __restrict__ e0con){
  int gtid = blockIdx.x*256 + threadIdx.x;
  int n = gtid >> 6;
  int lane = threadIdx.x & 63;
  int k = lane & 31;
  float xv = 0.f;
  #pragma unroll
  for (int e=0;e<NELEM;e++) xv += attrs[n*NELEM+e]*W_embed[e*KDIM+k];
  float yv = 0.f;
  #pragma unroll 8
  for (int k2=0;k2<KDIM;k2++) yv += __shfl(xv, k2, 64) * W_up[k2*KDIM+k];
  if (lane < 32){
    xbuf[n*KDIM+k]=xv;
    ybuf[n*KDIM+k]=yv;
  }
  if (lane == 0){
    float s=0.f;
    #pragma unroll
    for (int e=0;e<NELEM;e++) s += attrs[n*NELEM+e]*ae[e];
    e0con[n] = s;
  }
}

// ---------------------------------------------------------------- A accumulation (fused radial LUT)
__global__ void __launch_bounds__(256) node_accA_kernel(
    const int* __restrict__ row_start, const int* __restrict__ elist,
    const int* __restrict__ eidx, const float* __restrict__ shifts,
    const float* __restrict__ pos, const float* __restrict__ ybuf,
    const float* __restrict__ lut,
    float4* __restrict__ vbuf4, int* __restrict__ sndbuf, int* __restrict__ rcvbuf,
    float* __restrict__ A){
  int tid = threadIdx.x;
  int wl = tid>>6, lane = tid&63;
  int n = blockIdx.x*4 + wl;
  int k2 = lane>>1, ihalf = lane&1;
  float a0=0.f,a1=0.f,a2=0.f,a3=0.f,a4=0.f,a5=0.f,a6=0.f,a7=0.f;
  float px=pos[n*3+0], py=pos[n*3+1], pz=pos[n*3+2];
  int rs=row_start[n], re=row_start[n+1];
  for (int p=rs; p<re; ++p){
    int e = elist[p];
    int snd = eidx[e];
    float vx = px - pos[snd*3+0] + shifts[(size_t)e*3+0];
    float vy = py - pos[snd*3+1] + shifts[(size_t)e*3+1];
    float vz = pz - pos[snd*3+2] + shifts[(size_t)e*3+2];
    float r = sqrtf(vx*vx+vy*vy+vz*vz + 1e-18f);
    float invr = 1.0f/r;
    float u = r*INVR_MAX;
    float t = fminf(u,1.0f)*(float)LUTN;
    int gg = min((int)t, LUTN-1);
    float w = t - (float)gg;
    const float* rowA = lut + (size_t)gg*64;
    float rw0 = rowA[k2], rw1 = rowA[64+k2];
    float rw = rw0 + (rw1-rw0)*w;
    float y = ybuf[(size_t)snd*KDIM + k2];
    float xs = y*rw;
    float s0,s1,s2,s3,s4,s5,s6,s7,s8,s9,s10,s11,s12,s13,s14,s15;
    compute_sh16(vx*invr, vy*invr, vz*invr,
                 s0,s1,s2,s3,s4,s5,s6,s7,s8,s9,s10,s11,s12,s13,s14,s15);
    float e0 = ihalf ? s8  : s0;
    float e1 = ihalf ? s9  : s1;
    float e2 = ihalf ? s10 : s2;
    float e3 = ihalf ? s11 : s3;
    float e4 = ihalf ? s12 : s4;
    float e5 = ihalf ? s13 : s5;
    float e6 = ihalf ? s14 : s6;
    float e7 = ihalf ? s15 : s7;
    a0 = fmaf(xs, e0, a0);
    a1 = fmaf(xs, e1, a1);
    a2 = fmaf(xs, e2, a2);
    a3 = fmaf(xs, e3, a3);
    a4 = fmaf(xs, e4, a4);
    a5 = fmaf(xs, e5, a5);
    a6 = fmaf(xs, e6, a6);
    a7 = fmaf(xs, e7, a7);
    if (lane == 0){
      vbuf4[p] = make_float4(vx,vy,vz,r);
      sndbuf[p] = snd;
      rcvbuf[p] = n;
    }
  }
  float4* Ao = (float4*)(A + (size_t)n*512 + lane*8);
  Ao[0] = make_float4(a0,a1,a2,a3);
  Ao[1] = make_float4(a4,a5,a6,a7);
}

// ---------------------------------------------------------------- node B-ops
// thread = (k, node-pair): 2 nodes per thread. Coefficients staged in LDS,
// read as same-address broadcast ds_read_b128 (conflict-free). Pair-symmetric
// g3 (136 pairs); g2 fused per-i (no g2 array). Energy contrib -> econ[n]
// (no global atomic). gA written in place over A.
__global__ void __launch_bounds__(256) node_b_kernel(
    float* Abuf, const float* __restrict__ xbuf,
    const float* __restrict__ S3, const float* __restrict__ U2s,
    const float* __restrict__ c123, const float* __restrict__ Wread,
    float* __restrict__ econ){
  __shared__ float sS3[NPAIR*16];
  __shared__ float sU2[256];
  int tid = threadIdx.x;
  for (int v=tid; v<NPAIR*16; v+=256) sS3[v]=S3[v];
  if (tid < 256) sU2[tid]=U2s[tid];
  __syncthreads();
  int k = tid & 31, grp = tid >> 5;
  int n0 = blockIdx.x*16 + grp;
  int n1 = n0 + 8;
  const float inv_avg = 1.0f/16.0f;
  float aA[16], aB[16];
  float4* ArowA = (float4*)(Abuf + ((size_t)n0*KDIM + k)*NSHD);
  float4* ArowB = (float4*)(Abuf + ((size_t)n1*KDIM + k)*NSHD);
  #pragma unroll
  for (int q=0;q<4;q++){
    float4 tA = ArowA[q];
    aA[q*4+0]=tA.x*inv_avg; aA[q*4+1]=tA.y*inv_avg;
    aA[q*4+2]=tA.z*inv_avg; aA[q*4+3]=tA.w*inv_avg;
    float4 tB = ArowB[q];
    aB[q*4+0]=tB.x*inv_avg; aB[q*4+1]=tB.y*inv_avg;
    aB[q*4+2]=tB.z*inv_avg; aB[q*4+3]=tB.w*inv_avg;
  }
  float g3A[16], g3B[16];
  #pragma unroll
  for (int i=0;i<16;i++){ g3A[i]=0.f; g3B[i]=0.f; }
  int pid = 0;
  #pragma unroll
  for (int j=0;j<16;j++){
    #pragma unroll
    for (int l=j;l<16;l++){
      float paA = aA[j]*aA[l];
      float paB = aB[j]*aB[l];
      const float4* s3r = (const float4*)(sS3 + pid*16);
      #pragma unroll
      for (int q=0;q<4;q++){
        float4 c = s3r[q];
        g3A[q*4+0]=fmaf(c.x,paA,g3A[q*4+0]); g3B[q*4+0]=fmaf(c.x,paB,g3B[q*4+0]);
        g3A[q*4+1]=fmaf(c.y,paA,g3A[q*4+1]); g3B[q*4+1]=fmaf(c.y,paB,g3B[q*4+1]);
        g3A[q*4+2]=fmaf(c.z,paA,g3A[q*4+2]); g3B[q*4+2]=fmaf(c.z,paB,g3B[q*4+2]);
        g3A[q*4+3]=fmaf(c.w,paA,g3A[q*4+3]); g3B[q*4+3]=fmaf(c.w,paB,g3B[q*4+3]);
      }
      pid++;
    }
  }
  float c1k=c123[k], c2k=c123[KDIM+k], c3k=c123[2*KDIM+k];
  float B2A=0.f, B3A=0.f, B2B=0.f, B3B=0.f;
  float oA0=0.f,oA1=0.f,oA2=0.f, oB0=0.f,oB1=0.f,oB2=0.f;
  #pragma unroll
  for (int i=0;i<16;i++){
    // g2_i = sum_j U2s[j][i] a_j  (U2s symmetric; sU2 row j contiguous in i)
    float g2iA=0.f, g2iB=0.f;
    #pragma unroll
    for (int j=0;j<16;j++){
      float c = sU2[j*16+i];
      g2iA = fmaf(c, aA[j], g2iA);
      g2iB = fmaf(c, aB[j], g2iB);
    }
    B2A += aA[i]*g2iA;  B3A += aA[i]*g3A[i];
    B2B += aB[i]*g2iB;  B3B += aB[i]*g3B[i];
    float oA = (c2k*g2iA + c3k*g3A[i])*inv_avg;
    float oB = (c2k*g2iB + c3k*g3B[i])*inv_avg;
    if (i==0){ oA += c1k*inv_avg; oB += c1k*inv_avg; }
    int ph = i&3;
    if (ph==0){ oA0=oA; oB0=oB; }
    else if (ph==1){ oA1=oA; oB1=oB; }
    else if (ph==2){ oA2=oA; oB2=oB; }
    else {
      ArowA[i>>2] = make_float4(oA0,oA1,oA2,oA);
      ArowB[i>>2] = make_float4(oB0,oB1,oB2,oB);
    }
  }
  B2A *= 0.5f; B3A *= (1.0f/3.0f);
  B2B *= 0.5f; B3B *= (1.0f/3.0f);
  float wrk = Wread[k];
  float cA = aA[0]*c1k + B2A*c2k + B3A*c3k + xbuf[(size_t)n0*KDIM+k]*wrk;
  float cB = aB[0]*c1k + B2B*c2k + B3B*c3k + xbuf[(size_t)n1*KDIM+k]*wrk;
  #pragma unroll
  for (int off=1; off<32; off<<=1){
    cA += __shfl_xor(cA, off, 64);
    cB += __shfl_xor(cB, off, 64);
  }
  if (k==0){
    econ[n0] = cA;
    econ[n1] = cB;
  }
}

// ---------------------------------------------------------------- energy reduce
// out_e[g] += sum_n (econ[n] + e0con[n]) over batch[n]==g. LDS-binned.
__global__ void reduce_e_kernel(const float* __restrict__ econ,
                                const float* __restrict__ e0con,
                                const int* __restrict__ batch,
                                float* __restrict__ out_e){
  __shared__ float part[NGRAPH];
  int tid = threadIdx.x;
  if (tid < NGRAPH) part[tid]=0.f;
  __syncthreads();
  int n = blockIdx.x*256 + tid;
  float v = econ[n] + e0con[n];
  atomicAdd(&part[batch[n]], v);
  __syncthreads();
  if (tid < NGRAPH) atomicAdd(&out_e[tid], part[tid]);
}

// ---------------------------------------------------------------- edge backward (thread-per-edge, LUT)
__global__ void __launch_bounds__(256) edge_bwd_kernel(
    const int* __restrict__ sndbuf, const int* __restrict__ rcvbuf,
    const float4* __restrict__ vbuf4, const float* __restrict__ ybuf,
    const float* __restrict__ lut, const float* __restrict__ gA,
    float* __restrict__ F){
  int p = blockIdx.x*256 + threadIdx.x;
  int snd = sndbuf[p], rcv = rcvbuf[p];
  float4 v4 = vbuf4[p];
  float vx=v4.x, vy=v4.y, vz=v4.z, r=v4.w;
  float invr = 1.0f/r;
  float ux=vx*invr, uy=vy*invr, uz=vz*invr;
  float u = r*INVR_MAX;
  float t = fminf(u,1.0f)*(float)LUTN;
  int gg = min((int)t, LUTN-1);
  float w = t - (float)gg;
  const float* rowA = lut + (size_t)gg*64;
  float s0,s1,s2,s3,s4,s5,s6,s7,s8,s9,s10,s11,s12,s13,s14,s15;
  compute_sh16(ux,uy,uz,
               s0,s1,s2,s3,s4,s5,s6,s7,s8,s9,s10,s11,s12,s13,s14,s15);
  const float4* ga4 = (const float4*)(gA + (size_t)rcv*512);
  const float4* y4  = (const float4*)(ybuf + (size_t)snd*KDIM);
  float G0=0.f,G1=0.f,G2=0.f,G3v=0.f,G4=0.f,G5=0.f,G6=0.f,G7=0.f;
  float G8=0.f,G9=0.f,G10=0.f,G11=0.f,G12=0.f,G13=0.f,G14=0.f,G15=0.f;
  float grad_r = 0.f;
  #pragma unroll
  for (int k4=0;k4<8;k4++){
    float4 r0 = *(const float4*)(rowA + k4*4);
    float4 r1 = *(const float4*)(rowA + 64 + k4*4);
    float4 d0 = *(const float4*)(rowA + 32 + k4*4);
    float4 d1 = *(const float4*)(rowA + 96 + k4*4);
    float rwv0 = r0.x+(r1.x-r0.x)*w, rwv1 = r0.y+(r1.y-r0.y)*w;
    float rwv2 = r0.z+(r1.z-r0.z)*w, rwv3 = r0.w+(r1.w-r0.w)*w;
    float dr0 = d0.x+(d1.x-d0.x)*w, dr1 = d0.y+(d1.y-d0.y)*w;
    float dr2 = d0.z+(d1.z-d0.z)*w, dr3 = d0.w+(d1.w-d0.w)*w;
    float4 yv = y4[k4];
    #pragma unroll
    for (int q=0;q<4;q++){
      int k = k4*4+q;
      float yk  = (q==0)?yv.x:((q==1)?yv.y:((q==2)?yv.z:yv.w));
      float rwq = (q==0)?rwv0:((q==1)?rwv1:((q==2)?rwv2:rwv3));
      float drq = (q==0)?dr0:((q==1)?dr1:((q==2)?dr2:dr3));
      float xsk = yk*rwq;
      float4 t0 = ga4[k*4+0];
      float4 t1 = ga4[k*4+1];
      float4 t2 = ga4[k*4+2];
      float4 t3 = ga4[k*4+3];
      float gxs = t0.x*s0+t0.y*s1+t0.z*s2+t0.w*s3
                + t1.x*s4+t1.y*s5+t1.z*s6+t1.w*s7
                + t2.x*s8+t2.y*s9+t2.z*s10+t2.w*s11
                + t3.x*s12+t3.y*s13+t3.z*s14+t3.w*s15;
      G0  = fmaf(t0.x,xsk,G0);  G1  = fmaf(t0.y,xsk,G1);
      G2  = fmaf(t0.z,xsk,G2);  G3v = fmaf(t0.w,xsk,G3v);
      G4  = fmaf(t1.x,xsk,G4);  G5  = fmaf(t1.y,xsk,G5);
      G6  = fmaf(t1.z,xsk,G6);  G7  = fmaf(t1.w,xsk,G7);
      G8  = fmaf(t2.x,xsk,G8);  G9  = fmaf(t2.y,xsk,G9);
      G10 = fmaf(t2.z,xsk,G10); G11 = fmaf(t2.w,xsk,G11);
      G12 = fmaf(t3.x,xsk,G12); G13 = fmaf(t3.y,xsk,G13);
      G14 = fmaf(t3.z,xsk,G14); G15 = fmaf(t3.w,xsk,G15);
      grad_r += gxs*yk*drq;
    }
  }
  float x_=ux, y_=uy, z_=uz;
  float x2=x_*x_, y2=y_*y_, z2=z_*z_;
  float gux = 0.48860251f*G3v
            + 1.09254843f*(y_*G4 + z_*G7)
            + 1.09254844f*x_*G8
            + 3.54026154f*x_*y_*G9
            + 2.89061144f*y_*z_*G10
            + 0.45704579f*(5.0f*z2-1.0f)*G13
            + 2.89061144f*x_*z_*G14
            + 1.77013077f*(x2-y2)*G15;
  float guy = 0.48860251f*G1
            + 1.09254843f*(x_*G4 + z_*G5)
            - 1.09254844f*y_*G8
            + 1.77013077f*(x2-y2)*G9
            + 2.89061144f*x_*z_*G10
            + 0.45704579f*(5.0f*z2-1.0f)*G11
            - 2.89061144f*y_*z_*G14
            - 3.54026154f*x_*y_*G15;
  float guz = 0.48860251f*G2
            + 1.09254843f*(y_*G5 + x_*G7)
            + 1.89234942f*z_*G6
            + 2.89061144f*x_*y_*G10
            + 4.5704579f*y_*z_*G11
            + 0.37317633f*(15.0f*z2-3.0f)*G12
            + 4.5704579f*x_*z_*G13
            + 1.44530572f*(x2-y2)*G14;
  float dotg = gux*x_ + guy*y_ + guz*z_;
  float gvx = grad_r*x_ + (gux - dotg*x_)*invr;
  float gvy = grad_r*y_ + (guy - dotg*y_)*invr;
  float gvz = grad_r*z_ + (guz - dotg*z_)*invr;
  atomicAdd(&F[snd*3+0],  gvx);
  atomicAdd(&F[snd*3+1],  gvy);
  atomicAdd(&F[snd*3+2],  gvz);
  atomicAdd(&F[rcv*3+0], -gvx);
  atomicAdd(&F[rcv*3+1], -gvy);
  atomicAdd(&F[rcv*3+2], -gvz);
}

extern "C" void kernel_launch(void* const* d_in, const int* in_sizes, int n_in,
                              void* d_out, int out_size, void* d_ws, size_t ws_size,
                              hipStream_t stream){
  const float* positions       = (const float*)d_in[0];
  const float* node_attrs      = (const float*)d_in[1];
  const int*   edge_index      = (const int*)  d_in[2];
  const float* shifts          = (const float*)d_in[3];
  const int*   batch           = (const int*)  d_in[4];
  const float* atomic_energies = (const float*)d_in[6];
  const float* W_embed         = (const float*)d_in[7];
  const float* W_up            = (const float*)d_in[8];
  const float* W_r1            = (const float*)d_in[9];
  const float* b_r1            = (const float*)d_in[10];
  const float* W_r2            = (const float*)d_in[11];
  const float* U2              = (const float*)d_in[12];
  const float* U3              = (const float*)d_in[13];
  const float* Wp1             = (const float*)d_in[14];
  const float* Wp2             = (const float*)d_in[15];
  const float* Wp3             = (const float*)d_in[16];
  const float* W_read          = (const float*)d_in[17];
  float* out = (float*)d_out;

  float* Abuf  = (float*)d_ws;                        // N*512 (A, then gA in place)
  float* xbuf  = Abuf  + (size_t)NNODES*KDIM*NSHD;    // N*32
  float* ybuf  = xbuf  + (size_t)NNODES*KDIM;         // N*32
  float* lut   = ybuf  + (size_t)NNODES*KDIM;         // 2050*64
  float* S3    = lut   + (size_t)2050*64;             // 136*16 -> pad 2304
  float* U2s   = S3    + 2304;                        // 256
  float* c123  = U2s   + 256;                         // 96 -> pad 128
  float* econ  = c123  + 128;                         // N
  float* e0con = econ  + NNODES;                      // N
  float4* vbuf4 = (float4*)(e0con + NNODES);          // E float4
  int* sndbuf  = (int*)(vbuf4 + (size_t)NEDGES);      // E
  int* rcvbuf  = sndbuf + NEDGES;                     // E
  int* cnt       = rcvbuf + NEDGES;                   // N
  int* row_start = cnt + NNODES;                      // N+1 (pad 64)
  int* woff      = row_start + NNODES + 64;           // N
  int* elist     = woff + NNODES;                     // E

  hipMemsetAsync(d_out, 0, sizeof(float)*(NGRAPH + (size_t)NNODES*3), stream);
  hipMemsetAsync(cnt, 0, sizeof(int)*NNODES, stream);

  prep_kernel<<<1,256,0,stream>>>(U2,U3,Wp1,Wp2,Wp3,W_read,S3,U2s,c123);
  lut_kernel<<<(LUTN+1+255)/256,256,0,stream>>>(W_r1,b_r1,W_r2,lut);
  csr_count_kernel<<<NEDGES/256,256,0,stream>>>(edge_index, cnt);
  csr_scan_kernel<<<1,1024,0,stream>>>(cnt, row_start, woff);
  csr_scatter_kernel<<<NEDGES/256,256,0,stream>>>(edge_index, woff, elist);
  node_embed_kernel<<<NNODES/4,256,0,stream>>>(node_attrs,W_embed,W_up,atomic_energies,
                                               xbuf,ybuf,e0con);
  node_accA_kernel<<<NNODES/4,256,0,stream>>>(row_start,elist,edge_index,shifts,
                                              positions,ybuf,lut,vbuf4,sndbuf,rcvbuf,Abuf);
  node_b_kernel<<<NNODES/16,256,0,stream>>>(Abuf,xbuf,S3,U2s,c123,W_read,econ);
  reduce_e_kernel<<<NNODES/256,256,0,stream>>>(econ,e0con,batch,out);
  edge_bwd_kernel<<<NEDGES/256,256,0,stream>>>(sndbuf,rcvbuf,vbuf4,ybuf,lut,Abuf,out+NGRAPH);
}

// Round 8
// 845.643 us; speedup vs baseline: 4.2926x; 1.2407x over previous
//
#include <hip/hip_runtime.h>
#include <math.h>

#define NNODES 32768
#define NEDGES 524288
#define KDIM 32
#define NSHD 16
#define NB 8
#define NHID 64
#define NGRAPH 16
#define NELEM 10
#define RMAXF 5.0f
#define INVR_MAX 0.2f
#define PI_F 3.14159265358979f
#define CBES 0.632455532033676f   /* sqrt(2/R_MAX) */
#define LUTN 2048
#define NPAIR 136                 /* 16*17/2 symmetric (j<=l) pairs */

// 16 named outputs: keeps SH values in VGPRs (array form triggered
// PromoteAlloca -> LDS with 32-way bank conflicts, R5 post-mortem).
__device__ __forceinline__ void compute_sh16(float x, float y, float z,
    float& s0, float& s1, float& s2, float& s3,
    float& s4, float& s5, float& s6, float& s7,
    float& s8, float& s9, float& s10, float& s11,
    float& s12, float& s13, float& s14, float& s15){
  float x2=x*x, y2=y*y, z2=z*z;
  s0=0.28209479f;
  s1=0.48860251f*y;
  s2=0.48860251f*z;
  s3=0.48860251f*x;
  s4=1.09254843f*x*y;
  s5=1.09254843f*y*z;
  s6=0.31539157f*(3.0f*z2-1.0f);
  s7=1.09254843f*x*z;
  s8=0.54627422f*(x2-y2);
  s9=0.59004359f*y*(3.0f*x2-y2);
  s10=2.89061144f*x*y*z;
  s11=0.45704579f*y*(5.0f*z2-1.0f);
  s12=0.37317633f*z*(5.0f*z2-3.0f);
  s13=0.45704579f*x*(5.0f*z2-1.0f);
  s14=1.44530572f*z*(x2-y2);
  s15=0.59004359f*x*(x2-3.0f*y2);
}

// ---------------------------------------------------------------- prep
__global__ void prep_kernel(const float* __restrict__ U2, const float* __restrict__ U3,
                            const float* __restrict__ Wp1, const float* __restrict__ Wp2,
                            const float* __restrict__ Wp3, const float* __restrict__ Wread,
                            float* __restrict__ S3, float* __restrict__ U2s,
                            float* __restrict__ c123){
  int t = threadIdx.x;
  for (int v = t; v < NPAIR*16; v += 256){
    int pid = v >> 4, i = v & 15;
    int j = 0, rem = pid;
    while (rem >= 16 - j){ rem -= 16 - j; j++; }
    int l = j + rem;
    float s;
    if (j == l){
      s = U3[i*256 + j*16 + j] + U3[j*256 + i*16 + j] + U3[j*256 + j*16 + i];
    } else {
      s = U3[i*256 + j*16 + l] + U3[j*256 + i*16 + l] + U3[j*256 + l*16 + i]
        + U3[i*256 + l*16 + j] + U3[l*256 + i*16 + j] + U3[l*256 + j*16 + i];
    }
    S3[v] = s;
  }
  {
    int i = t >> 4, j = t & 15;
    U2s[t] = U2[i*16+j] + U2[j*16+i];
  }
  if (t < 96){
    int which = t >> 5, k = t & 31;
    const float* Wp = (which==0)?Wp1:((which==1)?Wp2:Wp3);
    float s = 0.f;
    for (int q=0;q<KDIM;q++) s += Wp[k*KDIM+q]*Wread[q];
    c123[t] = s;
  }
}

// ---------------------------------------------------------------- radial LUT
__global__ void lut_kernel(const float* __restrict__ W_r1, const float* __restrict__ b_r1,
                           const float* __restrict__ W_r2, float* __restrict__ lut){
  int g = blockIdx.x*256 + threadIdx.x;
  if (g > LUTN) return;
  float r = fmaxf(5.0f*(float)g/(float)LUTN, 1e-9f);
  float invr = 1.0f/r;
  float u = r*INVR_MAX;
  float cut = 0.f, dcdr = 0.f;
  if (u < 1.0f){
    float u2=u*u, u3=u2*u, u6=u3*u3;
    cut = 1.0f - 28.0f*u6 + 48.0f*u6*u - 21.0f*u6*u2;
    float u4=u2*u2, om=1.0f-u;
    dcdr = -168.0f*u4*u*om*om*INVR_MAX;
  }
  float b[NB], db[NB];
  #pragma unroll
  for (int q=0;q<NB;q++){
    float nn = (float)(q+1);
    float ang = PI_F*nn*u;
    float S = sinf(ang), C = cosf(ang);
    b[q]  = CBES*S*invr*cut;
    db[q] = CBES*invr*((PI_F*nn*INVR_MAX)*C - S*invr)*cut + CBES*S*invr*dcdr;
  }
  float Rw[KDIM], dRw[KDIM];
  #pragma unroll
  for (int k=0;k<KDIM;k++){ Rw[k]=0.f; dRw[k]=0.f; }
  for (int m=0;m<NHID;m++){
    float h = b_r1[m], dh = 0.f;
    #pragma unroll
    for (int q=0;q<NB;q++){ h += b[q]*W_r1[q*NHID+m]; dh += db[q]*W_r1[q*NHID+m]; }
    float sg = 1.0f/(1.0f+expf(-h));
    float s  = h*sg;
    float sp = sg*(1.0f + h*(1.0f-sg));
    float f  = sp*dh;
    #pragma unroll
    for (int k=0;k<KDIM;k++){
      Rw[k]  += s*W_r2[m*KDIM+k];
      dRw[k] += f*W_r2[m*KDIM+k];
    }
  }
  #pragma unroll
  for (int k=0;k<KDIM;k++){
    lut[(size_t)g*64 + k]      = Rw[k];
    lut[(size_t)g*64 + 32 + k] = dRw[k];
  }
}

// ---------------------------------------------------------------- CSR build
__global__ void csr_count_kernel(const int* __restrict__ eidx, int* __restrict__ cnt){
  int e = blockIdx.x*256 + threadIdx.x;
  if (e < NEDGES) atomicAdd(&cnt[eidx[NEDGES + e]], 1);
}

__global__ void csr_scan_kernel(const int* __restrict__ cnt, int* __restrict__ row_start,
                                int* __restrict__ woff){
  __shared__ int part[1024];
  int t = threadIdx.x;
  int base_idx = t*32;
  int local[32];
  int s = 0;
  #pragma unroll
  for (int j=0;j<32;j++){
    int c = cnt[base_idx+j];
    local[j] = s;
    s += c;
  }
  part[t] = s;
  __syncthreads();
  for (int off=1; off<1024; off<<=1){
    int v = (t>=off) ? part[t-off] : 0;
    __syncthreads();
    part[t] += v;
    __syncthreads();
  }
  int base = (t==0) ? 0 : part[t-1];
  #pragma unroll
  for (int j=0;j<32;j++){
    int v = base + local[j];
    row_start[base_idx+j] = v;
    woff[base_idx+j] = v;
  }
  if (t==1023) row_start[NNODES] = part[1023];
}

__global__ void csr_scatter_kernel(const int* __restrict__ eidx, int* __restrict__ woff,
                                   int* __restrict__ elist){
  int e = blockIdx.x*256 + threadIdx.x;
  if (e < NEDGES){
    int rcv = eidx[NEDGES + e];
    int p = atomicAdd(&woff[rcv], 1);
    elist[p] = e;
  }
}

// ---------------------------------------------------------------- node embed
__global__ void node_embed_kernel(const float* __restrict__ attrs,
                                  const float* __restrict__ W_embed,
                                  const float* __restrict__ W_up,
                                  const float* __restrict__ ae,
                                  float* __restrict__ xbuf, float* __restrict__ ybuf,
                                  float* __restrict__ e0con){
  int gtid = blockIdx.x*256 + threadIdx.x;
  int n = gtid >> 6;
  int lane = threadIdx.x & 63;
  int k = lane & 31;
  float xv = 0.f;
  #pragma unroll
  for (int e=0;e<NELEM;e++) xv += attrs[n*NELEM+e]*W_embed[e*KDIM+k];
  float yv = 0.f;
  #pragma unroll 8
  for (int k2=0;k2<KDIM;k2++) yv += __shfl(xv, k2, 64) * W_up[k2*KDIM+k];
  if (lane < 32){
    xbuf[n*KDIM+k]=xv;
    ybuf[n*KDIM+k]=yv;
  }
  if (lane == 0){
    float s=0.f;
    #pragma unroll
    for (int e=0;e<NELEM;e++) s += attrs[n*NELEM+e]*ae[e];
    e0con[n] = s;
  }
}

// ---------------------------------------------------------------- A accumulation (fused radial LUT)
__global__ void __launch_bounds__(256) node_accA_kernel(
    const int* __restrict__ row_start, const int* __restrict__ elist,
    const int* __restrict__ eidx, const float* __restrict__ shifts,
    const float* __restrict__ pos, const float* __restrict__ ybuf,
    const float* __restrict__ lut,
    float4* __restrict__ vbuf4, int* __restrict__ sndbuf, int* __restrict__ rcvbuf,
    float* __restrict__ A){
  int tid = threadIdx.x;
  int wl = tid>>6, lane = tid&63;
  int n = blockIdx.x*4 + wl;
  int k2 = lane>>1, ihalf = lane&1;
  float a0=0.f,a1=0.f,a2=0.f,a3=0.f,a4=0.f,a5=0.f,a6=0.f,a7=0.f;
  float px=pos[n*3+0], py=pos[n*3+1], pz=pos[n*3+2];
  int rs=row_start[n], re=row_start[n+1];
  for (int p=rs; p<re; ++p){
    int e = elist[p];
    int snd = eidx[e];
    float vx = px - pos[snd*3+0] + shifts[(size_t)e*3+0];
    float vy = py - pos[snd*3+1] + shifts[(size_t)e*3+1];
    float vz = pz - pos[snd*3+2] + shifts[(size_t)e*3+2];
    float r = sqrtf(vx*vx+vy*vy+vz*vz + 1e-18f);
    float invr = 1.0f/r;
    float u = r*INVR_MAX;
    float t = fminf(u,1.0f)*(float)LUTN;
    int gg = min((int)t, LUTN-1);
    float w = t - (float)gg;
    const float* rowA = lut + (size_t)gg*64;
    float rw0 = rowA[k2], rw1 = rowA[64+k2];
    float rw = rw0 + (rw1-rw0)*w;
    float y = ybuf[(size_t)snd*KDIM + k2];
    float xs = y*rw;
    float s0,s1,s2,s3,s4,s5,s6,s7,s8,s9,s10,s11,s12,s13,s14,s15;
    compute_sh16(vx*invr, vy*invr, vz*invr,
                 s0,s1,s2,s3,s4,s5,s6,s7,s8,s9,s10,s11,s12,s13,s14,s15);
    float e0 = ihalf ? s8  : s0;
    float e1 = ihalf ? s9  : s1;
    float e2 = ihalf ? s10 : s2;
    float e3 = ihalf ? s11 : s3;
    float e4 = ihalf ? s12 : s4;
    float e5 = ihalf ? s13 : s5;
    float e6 = ihalf ? s14 : s6;
    float e7 = ihalf ? s15 : s7;
    a0 = fmaf(xs, e0, a0);
    a1 = fmaf(xs, e1, a1);
    a2 = fmaf(xs, e2, a2);
    a3 = fmaf(xs, e3, a3);
    a4 = fmaf(xs, e4, a4);
    a5 = fmaf(xs, e5, a5);
    a6 = fmaf(xs, e6, a6);
    a7 = fmaf(xs, e7, a7);
    if (lane == 0){
      vbuf4[p] = make_float4(vx,vy,vz,r);
      sndbuf[p] = snd;
      rcvbuf[p] = n;
    }
  }
  float4* Ao = (float4*)(A + (size_t)n*512 + lane*8);
  Ao[0] = make_float4(a0,a1,a2,a3);
  Ao[1] = make_float4(a4,a5,a6,a7);
}

// ---------------------------------------------------------------- node B-ops
// thread = (node,k), ONE node per thread (R7's 2-node variant spilled:
// 256 VGPR + 950 MB scratch traffic). Coefficients staged in LDS, read as
// same-address broadcast ds_read_b128 (conflict-free; one read serves the
// wave's 2 nodes). Pair-symmetric g3 (136 pairs); g2 fused per-i.
// Energy contrib -> econ[n]; gA written in place over A.
__global__ void __launch_bounds__(256) node_b_kernel(
    float* Abuf, const float* __restrict__ xbuf,
    const float* __restrict__ S3, const float* __restrict__ U2s,
    const float* __restrict__ c123, const float* __restrict__ Wread,
    float* __restrict__ econ){
  __shared__ float sS3[NPAIR*16];
  __shared__ float sU2[256];
  int tid = threadIdx.x;
  for (int v=tid; v<NPAIR*16; v+=256) sS3[v]=S3[v];
  if (tid < 256) sU2[tid]=U2s[tid];
  __syncthreads();
  int k = tid & 31, grp = tid >> 5;
  int n = blockIdx.x*8 + grp;
  const float inv_avg = 1.0f/16.0f;
  float a[16];
  float4* Arow = (float4*)(Abuf + ((size_t)n*KDIM + k)*NSHD);
  #pragma unroll
  for (int q=0;q<4;q++){
    float4 t = Arow[q];
    a[q*4+0]=t.x*inv_avg; a[q*4+1]=t.y*inv_avg;
    a[q*4+2]=t.z*inv_avg; a[q*4+3]=t.w*inv_avg;
  }
  float g3[16];
  #pragma unroll
  for (int i=0;i<16;i++) g3[i]=0.f;
  int pid = 0;
  #pragma unroll
  for (int j=0;j<16;j++){
    #pragma unroll
    for (int l=j;l<16;l++){
      float pa = a[j]*a[l];
      const float4* s3r = (const float4*)(sS3 + pid*16);
      float4 c0 = s3r[0], c1 = s3r[1], c2 = s3r[2], c3 = s3r[3];
      g3[0] =fmaf(c0.x,pa,g3[0]);  g3[1] =fmaf(c0.y,pa,g3[1]);
      g3[2] =fmaf(c0.z,pa,g3[2]);  g3[3] =fmaf(c0.w,pa,g3[3]);
      g3[4] =fmaf(c1.x,pa,g3[4]);  g3[5] =fmaf(c1.y,pa,g3[5]);
      g3[6] =fmaf(c1.z,pa,g3[6]);  g3[7] =fmaf(c1.w,pa,g3[7]);
      g3[8] =fmaf(c2.x,pa,g3[8]);  g3[9] =fmaf(c2.y,pa,g3[9]);
      g3[10]=fmaf(c2.z,pa,g3[10]); g3[11]=fmaf(c2.w,pa,g3[11]);
      g3[12]=fmaf(c3.x,pa,g3[12]); g3[13]=fmaf(c3.y,pa,g3[13]);
      g3[14]=fmaf(c3.z,pa,g3[14]); g3[15]=fmaf(c3.w,pa,g3[15]);
      pid++;
    }
  }
  float c1k=c123[k], c2k=c123[KDIM+k], c3k=c123[2*KDIM+k];
  float B2=0.f, B3=0.f;
  float o0=0.f,o1=0.f,o2=0.f;
  #pragma unroll
  for (int i=0;i<16;i++){
    // g2_i = sum_j U2s[j][i] a_j  (U2s symmetric; sU2 row j contiguous in i)
    float g2i=0.f;
    #pragma unroll
    for (int j=0;j<16;j++) g2i = fmaf(sU2[j*16+i], a[j], g2i);
    B2 += a[i]*g2i;
    B3 += a[i]*g3[i];
    float o = (c2k*g2i + c3k*g3[i])*inv_avg;
    if (i==0) o += c1k*inv_avg;
    int ph = i&3;
    if (ph==0) o0=o;
    else if (ph==1) o1=o;
    else if (ph==2) o2=o;
    else Arow[i>>2] = make_float4(o0,o1,o2,o);
  }
  B2 *= 0.5f; B3 *= (1.0f/3.0f);
  float contrib = a[0]*c1k + B2*c2k + B3*c3k + xbuf[(size_t)n*KDIM+k]*Wread[k];
  #pragma unroll
  for (int off=1; off<32; off<<=1) contrib += __shfl_xor(contrib, off, 64);
  if (k==0) econ[n] = contrib;
}

// ---------------------------------------------------------------- energy reduce
__global__ void reduce_e_kernel(const float* __restrict__ econ,
                                const float* __restrict__ e0con,
                                const int* __restrict__ batch,
                                float* __restrict__ out_e){
  __shared__ float part[NGRAPH];
  int tid = threadIdx.x;
  if (tid < NGRAPH) part[tid]=0.f;
  __syncthreads();
  int n = blockIdx.x*256 + tid;
  float v = econ[n] + e0con[n];
  atomicAdd(&part[batch[n]], v);
  __syncthreads();
  if (tid < NGRAPH) atomicAdd(&out_e[tid], part[tid]);
}

// ---------------------------------------------------------------- edge backward (thread-per-edge, LUT)
__global__ void __launch_bounds__(256) edge_bwd_kernel(
    const int* __restrict__ sndbuf, const int* __restrict__ rcvbuf,
    const float4* __restrict__ vbuf4, const float* __restrict__ ybuf,
    const float* __restrict__ lut, const float* __restrict__ gA,
    float* __restrict__ F){
  int p = blockIdx.x*256 + threadIdx.x;
  int snd = sndbuf[p], rcv = rcvbuf[p];
  float4 v4 = vbuf4[p];
  float vx=v4.x, vy=v4.y, vz=v4.z, r=v4.w;
  float invr = 1.0f/r;
  float ux=vx*invr, uy=vy*invr, uz=vz*invr;
  float u = r*INVR_MAX;
  float t = fminf(u,1.0f)*(float)LUTN;
  int gg = min((int)t, LUTN-1);
  float w = t - (float)gg;
  const float* rowA = lut + (size_t)gg*64;
  float s0,s1,s2,s3,s4,s5,s6,s7,s8,s9,s10,s11,s12,s13,s14,s15;
  compute_sh16(ux,uy,uz,
               s0,s1,s2,s3,s4,s5,s6,s7,s8,s9,s10,s11,s12,s13,s14,s15);
  const float4* ga4 = (const float4*)(gA + (size_t)rcv*512);
  const float4* y4  = (const float4*)(ybuf + (size_t)snd*KDIM);
  float G0=0.f,G1=0.f,G2=0.f,G3v=0.f,G4=0.f,G5=0.f,G6=0.f,G7=0.f;
  float G8=0.f,G9=0.f,G10=0.f,G11=0.f,G12=0.f,G13=0.f,G14=0.f,G15=0.f;
  float grad_r = 0.f;
  #pragma unroll
  for (int k4=0;k4<8;k4++){
    float4 r0 = *(const float4*)(rowA + k4*4);
    float4 r1 = *(const float4*)(rowA + 64 + k4*4);
    float4 d0 = *(const float4*)(rowA + 32 + k4*4);
    float4 d1 = *(const float4*)(rowA + 96 + k4*4);
    float rwv0 = r0.x+(r1.x-r0.x)*w, rwv1 = r0.y+(r1.y-r0.y)*w;
    float rwv2 = r0.z+(r1.z-r0.z)*w, rwv3 = r0.w+(r1.w-r0.w)*w;
    float dr0 = d0.x+(d1.x-d0.x)*w, dr1 = d0.y+(d1.y-d0.y)*w;
    float dr2 = d0.z+(d1.z-d0.z)*w, dr3 = d0.w+(d1.w-d0.w)*w;
    float4 yv = y4[k4];
    #pragma unroll
    for (int q=0;q<4;q++){
      int k = k4*4+q;
      float yk  = (q==0)?yv.x:((q==1)?yv.y:((q==2)?yv.z:yv.w));
      float rwq = (q==0)?rwv0:((q==1)?rwv1:((q==2)?rwv2:rwv3));
      float drq = (q==0)?dr0:((q==1)?dr1:((q==2)?dr2:dr3));
      float xsk = yk*rwq;
      float4 t0 = ga4[k*4+0];
      float4 t1 = ga4[k*4+1];
      float4 t2 = ga4[k*4+2];
      float4 t3 = ga4[k*4+3];
      float gxs = t0.x*s0+t0.y*s1+t0.z*s2+t0.w*s3
                + t1.x*s4+t1.y*s5+t1.z*s6+t1.w*s7
                + t2.x*s8+t2.y*s9+t2.z*s10+t2.w*s11
                + t3.x*s12+t3.y*s13+t3.z*s14+t3.w*s15;
      G0  = fmaf(t0.x,xsk,G0);  G1  = fmaf(t0.y,xsk,G1);
      G2  = fmaf(t0.z,xsk,G2);  G3v = fmaf(t0.w,xsk,G3v);
      G4  = fmaf(t1.x,xsk,G4);  G5  = fmaf(t1.y,xsk,G5);
      G6  = fmaf(t1.z,xsk,G6);  G7  = fmaf(t1.w,xsk,G7);
      G8  = fmaf(t2.x,xsk,G8);  G9  = fmaf(t2.y,xsk,G9);
      G10 = fmaf(t2.z,xsk,G10); G11 = fmaf(t2.w,xsk,G11);
      G12 = fmaf(t3.x,xsk,G12); G13 = fmaf(t3.y,xsk,G13);
      G14 = fmaf(t3.z,xsk,G14); G15 = fmaf(t3.w,xsk,G15);
      grad_r += gxs*yk*drq;
    }
  }
  float x_=ux, y_=uy, z_=uz;
  float x2=x_*x_, y2=y_*y_, z2=z_*z_;
  float gux = 0.48860251f*G3v
            + 1.09254843f*(y_*G4 + z_*G7)
            + 1.09254844f*x_*G8
            + 3.54026154f*x_*y_*G9
            + 2.89061144f*y_*z_*G10
            + 0.45704579f*(5.0f*z2-1.0f)*G13
            + 2.89061144f*x_*z_*G14
            + 1.77013077f*(x2-y2)*G15;
  float guy = 0.48860251f*G1
            + 1.09254843f*(x_*G4 + z_*G5)
            - 1.09254844f*y_*G8
            + 1.77013077f*(x2-y2)*G9
            + 2.89061144f*x_*z_*G10
            + 0.45704579f*(5.0f*z2-1.0f)*G11
            - 2.89061144f*y_*z_*G14
            - 3.54026154f*x_*y_*G15;
  float guz = 0.48860251f*G2
            + 1.09254843f*(y_*G5 + x_*G7)
            + 1.89234942f*z_*G6
            + 2.89061144f*x_*y_*G10
            + 4.5704579f*y_*z_*G11
            + 0.37317633f*(15.0f*z2-3.0f)*G12
            + 4.5704579f*x_*z_*G13
            + 1.44530572f*(x2-y2)*G14;
  float dotg = gux*x_ + guy*y_ + guz*z_;
  float gvx = grad_r*x_ + (gux - dotg*x_)*invr;
  float gvy = grad_r*y_ + (guy - dotg*y_)*invr;
  float gvz = grad_r*z_ + (guz - dotg*z_)*invr;
  atomicAdd(&F[snd*3+0],  gvx);
  atomicAdd(&F[snd*3+1],  gvy);
  atomicAdd(&F[snd*3+2],  gvz);
  atomicAdd(&F[rcv*3+0], -gvx);
  atomicAdd(&F[rcv*3+1], -gvy);
  atomicAdd(&F[rcv*3+2], -gvz);
}

extern "C" void kernel_launch(void* const* d_in, const int* in_sizes, int n_in,
                              void* d_out, int out_size, void* d_ws, size_t ws_size,
                              hipStream_t stream){
  const float* positions       = (const float*)d_in[0];
  const float* node_attrs      = (const float*)d_in[1];
  const int*   edge_index      = (const int*)  d_in[2];
  const float* shifts          = (const float*)d_in[3];
  const int*   batch           = (const int*)  d_in[4];
  const float* atomic_energies = (const float*)d_in[6];
  const float* W_embed         = (const float*)d_in[7];
  const float* W_up            = (const float*)d_in[8];
  const float* W_r1            = (const float*)d_in[9];
  const float* b_r1            = (const float*)d_in[10];
  const float* W_r2            = (const float*)d_in[11];
  const float* U2              = (const float*)d_in[12];
  const float* U3              = (const float*)d_in[13];
  const float* Wp1             = (const float*)d_in[14];
  const float* Wp2             = (const float*)d_in[15];
  const float* Wp3             = (const float*)d_in[16];
  const float* W_read          = (const float*)d_in[17];
  float* out = (float*)d_out;

  float* Abuf  = (float*)d_ws;                        // N*512 (A, then gA in place)
  float* xbuf  = Abuf  + (size_t)NNODES*KDIM*NSHD;    // N*32
  float* ybuf  = xbuf  + (size_t)NNODES*KDIM;         // N*32
  float* lut   = ybuf  + (size_t)NNODES*KDIM;         // 2050*64
  float* S3    = lut   + (size_t)2050*64;             // 136*16 -> pad 2304
  float* U2s   = S3    + 2304;                        // 256
  float* c123  = U2s   + 256;                         // 96 -> pad 128
  float* econ  = c123  + 128;                         // N
  float* e0con = econ  + NNODES;                      // N
  float4* vbuf4 = (float4*)(e0con + NNODES);          // E float4
  int* sndbuf  = (int*)(vbuf4 + (size_t)NEDGES);      // E
  int* rcvbuf  = sndbuf + NEDGES;                     // E
  int* cnt       = rcvbuf + NEDGES;                   // N
  int* row_start = cnt + NNODES;                      // N+1 (pad 64)
  int* woff      = row_start + NNODES + 64;           // N
  int* elist     = woff + NNODES;                     // E

  hipMemsetAsync(d_out, 0, sizeof(float)*(NGRAPH + (size_t)NNODES*3), stream);
  hipMemsetAsync(cnt, 0, sizeof(int)*NNODES, stream);

  prep_kernel<<<1,256,0,stream>>>(U2,U3,Wp1,Wp2,Wp3,W_read,S3,U2s,c123);
  lut_kernel<<<(LUTN+1+255)/256,256,0,stream>>>(W_r1,b_r1,W_r2,lut);
  csr_count_kernel<<<NEDGES/256,256,0,stream>>>(edge_index, cnt);
  csr_scan_kernel<<<1,1024,0,stream>>>(cnt, row_start, woff);
  csr_scatter_kernel<<<NEDGES/256,256,0,stream>>>(edge_index, woff, elist);
  node_embed_kernel<<<NNODES/4,256,0,stream>>>(node_attrs,W_embed,W_up,atomic_energies,
                                               xbuf,ybuf,e0con);
  node_accA_kernel<<<NNODES/4,256,0,stream>>>(row_start,elist,edge_index,shifts,
                                              positions,ybuf,lut,vbuf4,sndbuf,rcvbuf,Abuf);
  node_b_kernel<<<NNODES/8,256,0,stream>>>(Abuf,xbuf,S3,U2s,c123,W_read,econ);
  reduce_e_kernel<<<NNODES/256,256,0,stream>>>(econ,e0con,batch,out);
  edge_bwd_kernel<<<NEDGES/256,256,0,stream>>>(sndbuf,rcvbuf,vbuf4,ybuf,lut,Abuf,out+NGRAPH);
}

// Round 9
// 797.153 us; speedup vs baseline: 4.5537x; 1.0608x over previous
//
#include <hip/hip_runtime.h>
#include <math.h>

#define NNODES 32768
#define NEDGES 524288
#define KDIM 32
#define NSHD 16
#define NB 8
#define NHID 64
#define NGRAPH 16
#define NELEM 10
#define RMAXF 5.0f
#define INVR_MAX 0.2f
#define PI_F 3.14159265358979f
#define CBES 0.632455532033676f   /* sqrt(2/R_MAX) */
#define LUTN 2048
#define NPAIR 136                 /* 16*17/2 symmetric (j<=l) pairs */

// 16 named outputs: keeps SH values in VGPRs (array form triggered
// PromoteAlloca -> LDS with 32-way bank conflicts, R5 post-mortem).
__device__ __forceinline__ void compute_sh16(float x, float y, float z,
    float& s0, float& s1, float& s2, float& s3,
    float& s4, float& s5, float& s6, float& s7,
    float& s8, float& s9, float& s10, float& s11,
    float& s12, float& s13, float& s14, float& s15){
  float x2=x*x, y2=y*y, z2=z*z;
  s0=0.28209479f;
  s1=0.48860251f*y;
  s2=0.48860251f*z;
  s3=0.48860251f*x;
  s4=1.09254843f*x*y;
  s5=1.09254843f*y*z;
  s6=0.31539157f*(3.0f*z2-1.0f);
  s7=1.09254843f*x*z;
  s8=0.54627422f*(x2-y2);
  s9=0.59004359f*y*(3.0f*x2-y2);
  s10=2.89061144f*x*y*z;
  s11=0.45704579f*y*(5.0f*z2-1.0f);
  s12=0.37317633f*z*(5.0f*z2-3.0f);
  s13=0.45704579f*x*(5.0f*z2-1.0f);
  s14=1.44530572f*z*(x2-y2);
  s15=0.59004359f*x*(x2-3.0f*y2);
}

// ---------------------------------------------------------------- prep
__global__ void prep_kernel(const float* __restrict__ U2, const float* __restrict__ U3,
                            const float* __restrict__ Wp1, const float* __restrict__ Wp2,
                            const float* __restrict__ Wp3, const float* __restrict__ Wread,
                            float* __restrict__ S3, float* __restrict__ U2s,
                            float* __restrict__ c123){
  int t = threadIdx.x;
  for (int v = t; v < NPAIR*16; v += 256){
    int pid = v >> 4, i = v & 15;
    int j = 0, rem = pid;
    while (rem >= 16 - j){ rem -= 16 - j; j++; }
    int l = j + rem;
    float s;
    if (j == l){
      s = U3[i*256 + j*16 + j] + U3[j*256 + i*16 + j] + U3[j*256 + j*16 + i];
    } else {
      s = U3[i*256 + j*16 + l] + U3[j*256 + i*16 + l] + U3[j*256 + l*16 + i]
        + U3[i*256 + l*16 + j] + U3[l*256 + i*16 + j] + U3[l*256 + j*16 + i];
    }
    S3[v] = s;
  }
  {
    int i = t >> 4, j = t & 15;
    U2s[t] = U2[i*16+j] + U2[j*16+i];
  }
  if (t < 96){
    int which = t >> 5, k = t & 31;
    const float* Wp = (which==0)?Wp1:((which==1)?Wp2:Wp3);
    float s = 0.f;
    for (int q=0;q<KDIM;q++) s += Wp[k*KDIM+q]*Wread[q];
    c123[t] = s;
  }
}

// ---------------------------------------------------------------- radial LUT
__global__ void lut_kernel(const float* __restrict__ W_r1, const float* __restrict__ b_r1,
                           const float* __restrict__ W_r2, float* __restrict__ lut){
  int g = blockIdx.x*256 + threadIdx.x;
  if (g > LUTN) return;
  float r = fmaxf(5.0f*(float)g/(float)LUTN, 1e-9f);
  float invr = 1.0f/r;
  float u = r*INVR_MAX;
  float cut = 0.f, dcdr = 0.f;
  if (u < 1.0f){
    float u2=u*u, u3=u2*u, u6=u3*u3;
    cut = 1.0f - 28.0f*u6 + 48.0f*u6*u - 21.0f*u6*u2;
    float u4=u2*u2, om=1.0f-u;
    dcdr = -168.0f*u4*u*om*om*INVR_MAX;
  }
  float b[NB], db[NB];
  #pragma unroll
  for (int q=0;q<NB;q++){
    float nn = (float)(q+1);
    float ang = PI_F*nn*u;
    float S = sinf(ang), C = cosf(ang);
    b[q]  = CBES*S*invr*cut;
    db[q] = CBES*invr*((PI_F*nn*INVR_MAX)*C - S*invr)*cut + CBES*S*invr*dcdr;
  }
  float Rw[KDIM], dRw[KDIM];
  #pragma unroll
  for (int k=0;k<KDIM;k++){ Rw[k]=0.f; dRw[k]=0.f; }
  for (int m=0;m<NHID;m++){
    float h = b_r1[m], dh = 0.f;
    #pragma unroll
    for (int q=0;q<NB;q++){ h += b[q]*W_r1[q*NHID+m]; dh += db[q]*W_r1[q*NHID+m]; }
    float sg = 1.0f/(1.0f+expf(-h));
    float s  = h*sg;
    float sp = sg*(1.0f + h*(1.0f-sg));
    float f  = sp*dh;
    #pragma unroll
    for (int k=0;k<KDIM;k++){
      Rw[k]  += s*W_r2[m*KDIM+k];
      dRw[k] += f*W_r2[m*KDIM+k];
    }
  }
  #pragma unroll
  for (int k=0;k<KDIM;k++){
    lut[(size_t)g*64 + k]      = Rw[k];
    lut[(size_t)g*64 + 32 + k] = dRw[k];
  }
}

// ---------------------------------------------------------------- CSR build (receiver)
__global__ void csr_count_kernel(const int* __restrict__ eidx, int* __restrict__ cnt){
  int e = blockIdx.x*256 + threadIdx.x;
  if (e < NEDGES) atomicAdd(&cnt[eidx[NEDGES + e]], 1);
}

// generic exclusive scan over NNODES counts -> row_start (N+1) + woff copy
__global__ void csr_scan_kernel(const int* __restrict__ cnt, int* __restrict__ row_start,
                                int* __restrict__ woff){
  __shared__ int part[1024];
  int t = threadIdx.x;
  int base_idx = t*32;
  int local[32];
  int s = 0;
  #pragma unroll
  for (int j=0;j<32;j++){
    int c = cnt[base_idx+j];
    local[j] = s;
    s += c;
  }
  part[t] = s;
  __syncthreads();
  for (int off=1; off<1024; off<<=1){
    int v = (t>=off) ? part[t-off] : 0;
    __syncthreads();
    part[t] += v;
    __syncthreads();
  }
  int base = (t==0) ? 0 : part[t-1];
  #pragma unroll
  for (int j=0;j<32;j++){
    int v = base + local[j];
    row_start[base_idx+j] = v;
    woff[base_idx+j] = v;
  }
  if (t==1023) row_start[NNODES] = part[1023];
}

__global__ void csr_scatter_kernel(const int* __restrict__ eidx, int* __restrict__ woff,
                                   int* __restrict__ elist){
  int e = blockIdx.x*256 + threadIdx.x;
  if (e < NEDGES){
    int rcv = eidx[NEDGES + e];
    int p = atomicAdd(&woff[rcv], 1);
    elist[p] = e;
  }
}

// ---------------------------------------------------------------- CSR build (sender, over CSR positions)
__global__ void csr2_count_kernel(const int* __restrict__ sndbuf, int* __restrict__ cnt2){
  int p = blockIdx.x*256 + threadIdx.x;
  if (p < NEDGES) atomicAdd(&cnt2[sndbuf[p]], 1);
}

__global__ void csr2_scatter_kernel(const int* __restrict__ sndbuf, int* __restrict__ woff2,
                                    int* __restrict__ elist2){
  int p = blockIdx.x*256 + threadIdx.x;
  if (p < NEDGES){
    int s = sndbuf[p];
    int slot = atomicAdd(&woff2[s], 1);
    elist2[slot] = p;
  }
}

// ---------------------------------------------------------------- node embed
__global__ void node_embed_kernel(const float* __restrict__ attrs,
                                  const float* __restrict__ W_embed,
                                  const float* __restrict__ W_up,
                                  const float* __restrict__ ae,
                                  float* __restrict__ xbuf, float* __restrict__ ybuf,
                                  float* __restrict__ e0con){
  int gtid = blockIdx.x*256 + threadIdx.x;
  int n = gtid >> 6;
  int lane = threadIdx.x & 63;
  int k = lane & 31;
  float xv = 0.f;
  #pragma unroll
  for (int e=0;e<NELEM;e++) xv += attrs[n*NELEM+e]*W_embed[e*KDIM+k];
  float yv = 0.f;
  #pragma unroll 8
  for (int k2=0;k2<KDIM;k2++) yv += __shfl(xv, k2, 64) * W_up[k2*KDIM+k];
  if (lane < 32){
    xbuf[n*KDIM+k]=xv;
    ybuf[n*KDIM+k]=yv;
  }
  if (lane == 0){
    float s=0.f;
    #pragma unroll
    for (int e=0;e<NELEM;e++) s += attrs[n*NELEM+e]*ae[e];
    e0con[n] = s;
  }
}

// ---------------------------------------------------------------- A accumulation (fused radial LUT)
__global__ void __launch_bounds__(256) node_accA_kernel(
    const int* __restrict__ row_start, const int* __restrict__ elist,
    const int* __restrict__ eidx, const float* __restrict__ shifts,
    const float* __restrict__ pos, const float* __restrict__ ybuf,
    const float* __restrict__ lut,
    float4* __restrict__ vbuf4, int* __restrict__ sndbuf, int* __restrict__ rcvbuf,
    float* __restrict__ A){
  int tid = threadIdx.x;
  int wl = tid>>6, lane = tid&63;
  int n = blockIdx.x*4 + wl;
  int k2 = lane>>1, ihalf = lane&1;
  float a0=0.f,a1=0.f,a2=0.f,a3=0.f,a4=0.f,a5=0.f,a6=0.f,a7=0.f;
  float px=pos[n*3+0], py=pos[n*3+1], pz=pos[n*3+2];
  int rs=row_start[n], re=row_start[n+1];
  for (int p=rs; p<re; ++p){
    int e = elist[p];
    int snd = eidx[e];
    float vx = px - pos[snd*3+0] + shifts[(size_t)e*3+0];
    float vy = py - pos[snd*3+1] + shifts[(size_t)e*3+1];
    float vz = pz - pos[snd*3+2] + shifts[(size_t)e*3+2];
    float r = sqrtf(vx*vx+vy*vy+vz*vz + 1e-18f);
    float invr = 1.0f/r;
    float u = r*INVR_MAX;
    float t = fminf(u,1.0f)*(float)LUTN;
    int gg = min((int)t, LUTN-1);
    float w = t - (float)gg;
    const float* rowA = lut + (size_t)gg*64;
    float rw0 = rowA[k2], rw1 = rowA[64+k2];
    float rw = rw0 + (rw1-rw0)*w;
    float y = ybuf[(size_t)snd*KDIM + k2];
    float xs = y*rw;
    float s0,s1,s2,s3,s4,s5,s6,s7,s8,s9,s10,s11,s12,s13,s14,s15;
    compute_sh16(vx*invr, vy*invr, vz*invr,
                 s0,s1,s2,s3,s4,s5,s6,s7,s8,s9,s10,s11,s12,s13,s14,s15);
    float e0 = ihalf ? s8  : s0;
    float e1 = ihalf ? s9  : s1;
    float e2 = ihalf ? s10 : s2;
    float e3 = ihalf ? s11 : s3;
    float e4 = ihalf ? s12 : s4;
    float e5 = ihalf ? s13 : s5;
    float e6 = ihalf ? s14 : s6;
    float e7 = ihalf ? s15 : s7;
    a0 = fmaf(xs, e0, a0);
    a1 = fmaf(xs, e1, a1);
    a2 = fmaf(xs, e2, a2);
    a3 = fmaf(xs, e3, a3);
    a4 = fmaf(xs, e4, a4);
    a5 = fmaf(xs, e5, a5);
    a6 = fmaf(xs, e6, a6);
    a7 = fmaf(xs, e7, a7);
    if (lane == 0){
      vbuf4[p] = make_float4(vx,vy,vz,r);
      sndbuf[p] = snd;
      rcvbuf[p] = n;
    }
  }
  float4* Ao = (float4*)(A + (size_t)n*512 + lane*8);
  Ao[0] = make_float4(a0,a1,a2,a3);
  Ao[1] = make_float4(a4,a5,a6,a7);
}

// ---------------------------------------------------------------- node B-ops
// thread = (node,k), one node per thread (2-node variant spilled, R7).
// LDS-staged coefficients, same-address broadcast reads.
__global__ void __launch_bounds__(256) node_b_kernel(
    float* Abuf, const float* __restrict__ xbuf,
    const float* __restrict__ S3, const float* __restrict__ U2s,
    const float* __restrict__ c123, const float* __restrict__ Wread,
    float* __restrict__ econ){
  __shared__ float sS3[NPAIR*16];
  __shared__ float sU2[256];
  int tid = threadIdx.x;
  for (int v=tid; v<NPAIR*16; v+=256) sS3[v]=S3[v];
  if (tid < 256) sU2[tid]=U2s[tid];
  __syncthreads();
  int k = tid & 31, grp = tid >> 5;
  int n = blockIdx.x*8 + grp;
  const float inv_avg = 1.0f/16.0f;
  float a[16];
  float4* Arow = (float4*)(Abuf + ((size_t)n*KDIM + k)*NSHD);
  #pragma unroll
  for (int q=0;q<4;q++){
    float4 t = Arow[q];
    a[q*4+0]=t.x*inv_avg; a[q*4+1]=t.y*inv_avg;
    a[q*4+2]=t.z*inv_avg; a[q*4+3]=t.w*inv_avg;
  }
  float g3[16];
  #pragma unroll
  for (int i=0;i<16;i++) g3[i]=0.f;
  int pid = 0;
  #pragma unroll
  for (int j=0;j<16;j++){
    #pragma unroll
    for (int l=j;l<16;l++){
      float pa = a[j]*a[l];
      const float4* s3r = (const float4*)(sS3 + pid*16);
      float4 c0 = s3r[0], c1 = s3r[1], c2 = s3r[2], c3 = s3r[3];
      g3[0] =fmaf(c0.x,pa,g3[0]);  g3[1] =fmaf(c0.y,pa,g3[1]);
      g3[2] =fmaf(c0.z,pa,g3[2]);  g3[3] =fmaf(c0.w,pa,g3[3]);
      g3[4] =fmaf(c1.x,pa,g3[4]);  g3[5] =fmaf(c1.y,pa,g3[5]);
      g3[6] =fmaf(c1.z,pa,g3[6]);  g3[7] =fmaf(c1.w,pa,g3[7]);
      g3[8] =fmaf(c2.x,pa,g3[8]);  g3[9] =fmaf(c2.y,pa,g3[9]);
      g3[10]=fmaf(c2.z,pa,g3[10]); g3[11]=fmaf(c2.w,pa,g3[11]);
      g3[12]=fmaf(c3.x,pa,g3[12]); g3[13]=fmaf(c3.y,pa,g3[13]);
      g3[14]=fmaf(c3.z,pa,g3[14]); g3[15]=fmaf(c3.w,pa,g3[15]);
      pid++;
    }
  }
  float c1k=c123[k], c2k=c123[KDIM+k], c3k=c123[2*KDIM+k];
  float B2=0.f, B3=0.f;
  float o0=0.f,o1=0.f,o2=0.f;
  #pragma unroll
  for (int i=0;i<16;i++){
    float g2i=0.f;
    #pragma unroll
    for (int j=0;j<16;j++) g2i = fmaf(sU2[j*16+i], a[j], g2i);
    B2 += a[i]*g2i;
    B3 += a[i]*g3[i];
    float o = (c2k*g2i + c3k*g3[i])*inv_avg;
    if (i==0) o += c1k*inv_avg;
    int ph = i&3;
    if (ph==0) o0=o;
    else if (ph==1) o1=o;
    else if (ph==2) o2=o;
    else Arow[i>>2] = make_float4(o0,o1,o2,o);
  }
  B2 *= 0.5f; B3 *= (1.0f/3.0f);
  float contrib = a[0]*c1k + B2*c2k + B3*c3k + xbuf[(size_t)n*KDIM+k]*Wread[k];
  #pragma unroll
  for (int off=1; off<32; off<<=1) contrib += __shfl_xor(contrib, off, 64);
  if (k==0) econ[n] = contrib;
}

// ---------------------------------------------------------------- energy reduce
__global__ void reduce_e_kernel(const float* __restrict__ econ,
                                const float* __restrict__ e0con,
                                const int* __restrict__ batch,
                                float* __restrict__ out_e){
  __shared__ float part[NGRAPH];
  int tid = threadIdx.x;
  if (tid < NGRAPH) part[tid]=0.f;
  __syncthreads();
  int n = blockIdx.x*256 + tid;
  float v = econ[n] + e0con[n];
  atomicAdd(&part[batch[n]], v);
  __syncthreads();
  if (tid < NGRAPH) atomicAdd(&out_e[tid], part[tid]);
}

// ---------------------------------------------------------------- edge backward (thread-per-edge, LUT)
// NO atomics: stores per-edge gradient vector to SoA buffers (coalesced).
__global__ void __launch_bounds__(256) edge_bwd_kernel(
    const int* __restrict__ sndbuf, const int* __restrict__ rcvbuf,
    const float4* __restrict__ vbuf4, const float* __restrict__ ybuf,
    const float* __restrict__ lut, const float* __restrict__ gA,
    float* __restrict__ gvx_o, float* __restrict__ gvy_o, float* __restrict__ gvz_o){
  int p = blockIdx.x*256 + threadIdx.x;
  int snd = sndbuf[p], rcv = rcvbuf[p];
  float4 v4 = vbuf4[p];
  float vx=v4.x, vy=v4.y, vz=v4.z, r=v4.w;
  float invr = 1.0f/r;
  float ux=vx*invr, uy=vy*invr, uz=vz*invr;
  float u = r*INVR_MAX;
  float t = fminf(u,1.0f)*(float)LUTN;
  int gg = min((int)t, LUTN-1);
  float w = t - (float)gg;
  const float* rowA = lut + (size_t)gg*64;
  float s0,s1,s2,s3,s4,s5,s6,s7,s8,s9,s10,s11,s12,s13,s14,s15;
  compute_sh16(ux,uy,uz,
               s0,s1,s2,s3,s4,s5,s6,s7,s8,s9,s10,s11,s12,s13,s14,s15);
  const float4* ga4 = (const float4*)(gA + (size_t)rcv*512);
  const float4* y4  = (const float4*)(ybuf + (size_t)snd*KDIM);
  float G0=0.f,G1=0.f,G2=0.f,G3v=0.f,G4=0.f,G5=0.f,G6=0.f,G7=0.f;
  float G8=0.f,G9=0.f,G10=0.f,G11=0.f,G12=0.f,G13=0.f,G14=0.f,G15=0.f;
  float grad_r = 0.f;
  #pragma unroll
  for (int k4=0;k4<8;k4++){
    float4 r0 = *(const float4*)(rowA + k4*4);
    float4 r1 = *(const float4*)(rowA + 64 + k4*4);
    float4 d0 = *(const float4*)(rowA + 32 + k4*4);
    float4 d1 = *(const float4*)(rowA + 96 + k4*4);
    float rwv0 = r0.x+(r1.x-r0.x)*w, rwv1 = r0.y+(r1.y-r0.y)*w;
    float rwv2 = r0.z+(r1.z-r0.z)*w, rwv3 = r0.w+(r1.w-r0.w)*w;
    float dr0 = d0.x+(d1.x-d0.x)*w, dr1 = d0.y+(d1.y-d0.y)*w;
    float dr2 = d0.z+(d1.z-d0.z)*w, dr3 = d0.w+(d1.w-d0.w)*w;
    float4 yv = y4[k4];
    #pragma unroll
    for (int q=0;q<4;q++){
      int k = k4*4+q;
      float yk  = (q==0)?yv.x:((q==1)?yv.y:((q==2)?yv.z:yv.w));
      float rwq = (q==0)?rwv0:((q==1)?rwv1:((q==2)?rwv2:rwv3));
      float drq = (q==0)?dr0:((q==1)?dr1:((q==2)?dr2:dr3));
      float xsk = yk*rwq;
      float4 t0 = ga4[k*4+0];
      float4 t1 = ga4[k*4+1];
      float4 t2 = ga4[k*4+2];
      float4 t3 = ga4[k*4+3];
      float gxs = t0.x*s0+t0.y*s1+t0.z*s2+t0.w*s3
                + t1.x*s4+t1.y*s5+t1.z*s6+t1.w*s7
                + t2.x*s8+t2.y*s9+t2.z*s10+t2.w*s11
                + t3.x*s12+t3.y*s13+t3.z*s14+t3.w*s15;
      G0  = fmaf(t0.x,xsk,G0);  G1  = fmaf(t0.y,xsk,G1);
      G2  = fmaf(t0.z,xsk,G2);  G3v = fmaf(t0.w,xsk,G3v);
      G4  = fmaf(t1.x,xsk,G4);  G5  = fmaf(t1.y,xsk,G5);
      G6  = fmaf(t1.z,xsk,G6);  G7  = fmaf(t1.w,xsk,G7);
      G8  = fmaf(t2.x,xsk,G8);  G9  = fmaf(t2.y,xsk,G9);
      G10 = fmaf(t2.z,xsk,G10); G11 = fmaf(t2.w,xsk,G11);
      G12 = fmaf(t3.x,xsk,G12); G13 = fmaf(t3.y,xsk,G13);
      G14 = fmaf(t3.z,xsk,G14); G15 = fmaf(t3.w,xsk,G15);
      grad_r += gxs*yk*drq;
    }
  }
  float x_=ux, y_=uy, z_=uz;
  float x2=x_*x_, y2=y_*y_, z2=z_*z_;
  float gux = 0.48860251f*G3v
            + 1.09254843f*(y_*G4 + z_*G7)
            + 1.09254844f*x_*G8
            + 3.54026154f*x_*y_*G9
            + 2.89061144f*y_*z_*G10
            + 0.45704579f*(5.0f*z2-1.0f)*G13
            + 2.89061144f*x_*z_*G14
            + 1.77013077f*(x2-y2)*G15;
  float guy = 0.48860251f*G1
            + 1.09254843f*(x_*G4 + z_*G5)
            - 1.09254844f*y_*G8
            + 1.77013077f*(x2-y2)*G9
            + 2.89061144f*x_*z_*G10
            + 0.45704579f*(5.0f*z2-1.0f)*G11
            - 2.89061144f*y_*z_*G14
            - 3.54026154f*x_*y_*G15;
  float guz = 0.48860251f*G2
            + 1.09254843f*(y_*G5 + x_*G7)
            + 1.89234942f*z_*G6
            + 2.89061144f*x_*y_*G10
            + 4.5704579f*y_*z_*G11
            + 0.37317633f*(15.0f*z2-3.0f)*G12
            + 4.5704579f*x_*z_*G13
            + 1.44530572f*(x2-y2)*G14;
  float dotg = gux*x_ + guy*y_ + guz*z_;
  gvx_o[p] = grad_r*x_ + (gux - dotg*x_)*invr;
  gvy_o[p] = grad_r*y_ + (guy - dotg*y_)*invr;
  gvz_o[p] = grad_r*z_ + (guz - dotg*z_)*invr;
}

// ---------------------------------------------------------------- force assembly
// F[n] = -sum_{p in rcv-row(n)} gv[p] + sum_{q in snd-row(n)} gv[elist2[q]].
// Plain stores; zero atomics.
__global__ void force_kernel(const int* __restrict__ row_start,
                             const int* __restrict__ row2_start,
                             const int* __restrict__ elist2,
                             const float* __restrict__ gvx, const float* __restrict__ gvy,
                             const float* __restrict__ gvz, float* __restrict__ F){
  int n = blockIdx.x*256 + threadIdx.x;
  float fx=0.f, fy=0.f, fz=0.f;
  int rs=row_start[n], re=row_start[n+1];
  for (int p=rs; p<re; ++p){
    fx -= gvx[p]; fy -= gvy[p]; fz -= gvz[p];
  }
  int s2=row2_start[n], e2=row2_start[n+1];
  for (int q=s2; q<e2; ++q){
    int p = elist2[q];
    fx += gvx[p]; fy += gvy[p]; fz += gvz[p];
  }
  F[n*3+0]=fx; F[n*3+1]=fy; F[n*3+2]=fz;
}

extern "C" void kernel_launch(void* const* d_in, const int* in_sizes, int n_in,
                              void* d_out, int out_size, void* d_ws, size_t ws_size,
                              hipStream_t stream){
  const float* positions       = (const float*)d_in[0];
  const float* node_attrs      = (const float*)d_in[1];
  const int*   edge_index      = (const int*)  d_in[2];
  const float* shifts          = (const float*)d_in[3];
  const int*   batch           = (const int*)  d_in[4];
  const float* atomic_energies = (const float*)d_in[6];
  const float* W_embed         = (const float*)d_in[7];
  const float* W_up            = (const float*)d_in[8];
  const float* W_r1            = (const float*)d_in[9];
  const float* b_r1            = (const float*)d_in[10];
  const float* W_r2            = (const float*)d_in[11];
  const float* U2              = (const float*)d_in[12];
  const float* U3              = (const float*)d_in[13];
  const float* Wp1             = (const float*)d_in[14];
  const float* Wp2             = (const float*)d_in[15];
  const float* Wp3             = (const float*)d_in[16];
  const float* W_read          = (const float*)d_in[17];
  float* out = (float*)d_out;

  float* Abuf  = (float*)d_ws;                        // N*512 (A, then gA in place)
  float* xbuf  = Abuf  + (size_t)NNODES*KDIM*NSHD;    // N*32
  float* ybuf  = xbuf  + (size_t)NNODES*KDIM;         // N*32
  float* lut   = ybuf  + (size_t)NNODES*KDIM;         // 2050*64
  float* S3    = lut   + (size_t)2050*64;             // 136*16 -> pad 2304
  float* U2s   = S3    + 2304;                        // 256
  float* c123  = U2s   + 256;                         // 96 -> pad 128
  float* econ  = c123  + 128;                         // N
  float* e0con = econ  + NNODES;                      // N
  float4* vbuf4 = (float4*)(e0con + NNODES);          // E float4
  float* gvx   = (float*)(vbuf4 + (size_t)NEDGES);    // E
  float* gvy   = gvx + NEDGES;                        // E
  float* gvz   = gvy + NEDGES;                        // E
  int* sndbuf  = (int*)(gvz + NEDGES);                // E
  int* rcvbuf  = sndbuf + NEDGES;                     // E
  int* cnt       = rcvbuf + NEDGES;                   // N
  int* row_start = cnt + NNODES;                      // N+1 (pad 64)
  int* woff      = row_start + NNODES + 64;           // N
  int* elist     = woff + NNODES;                     // E
  int* cnt2      = elist + NEDGES;                    // N
  int* row2      = cnt2 + NNODES;                     // N+1 (pad 64)
  int* woff2     = row2 + NNODES + 64;                // N
  int* elist2    = woff2 + NNODES;                    // E

  hipMemsetAsync(out, 0, sizeof(float)*NGRAPH, stream);
  hipMemsetAsync(cnt, 0, sizeof(int)*NNODES, stream);
  hipMemsetAsync(cnt2, 0, sizeof(int)*NNODES, stream);

  prep_kernel<<<1,256,0,stream>>>(U2,U3,Wp1,Wp2,Wp3,W_read,S3,U2s,c123);
  lut_kernel<<<(LUTN+1+255)/256,256,0,stream>>>(W_r1,b_r1,W_r2,lut);
  csr_count_kernel<<<NEDGES/256,256,0,stream>>>(edge_index, cnt);
  csr_scan_kernel<<<1,1024,0,stream>>>(cnt, row_start, woff);
  csr_scatter_kernel<<<NEDGES/256,256,0,stream>>>(edge_index, woff, elist);
  node_embed_kernel<<<NNODES/4,256,0,stream>>>(node_attrs,W_embed,W_up,atomic_energies,
                                               xbuf,ybuf,e0con);
  node_accA_kernel<<<NNODES/4,256,0,stream>>>(row_start,elist,edge_index,shifts,
                                              positions,ybuf,lut,vbuf4,sndbuf,rcvbuf,Abuf);
  // sender-CSR over CSR positions (needs sndbuf from node_accA)
  csr2_count_kernel<<<NEDGES/256,256,0,stream>>>(sndbuf, cnt2);
  csr_scan_kernel<<<1,1024,0,stream>>>(cnt2, row2, woff2);
  csr2_scatter_kernel<<<NEDGES/256,256,0,stream>>>(sndbuf, woff2, elist2);
  node_b_kernel<<<NNODES/8,256,0,stream>>>(Abuf,xbuf,S3,U2s,c123,W_read,econ);
  reduce_e_kernel<<<NNODES/256,256,0,stream>>>(econ,e0con,batch,out);
  edge_bwd_kernel<<<NEDGES/256,256,0,stream>>>(sndbuf,rcvbuf,vbuf4,ybuf,lut,Abuf,
                                               gvx,gvy,gvz);
  force_kernel<<<NNODES/256,256,0,stream>>>(row_start,row2,elist2,gvx,gvy,gvz,out+NGRAPH);
}